// Round 10
// baseline (652.939 us; speedup 1.0000x reference)
//
#include <hip/hip_runtime.h>
#include <math.h>

typedef unsigned short u16;
typedef unsigned int   u32;
typedef float f32x4 __attribute__((ext_vector_type(4)));
typedef __bf16 bf16x8 __attribute__((ext_vector_type(8)));

#define T_LEN  1024
#define DMODEL 1024
#define NTOK   2048
#define NHEAD  16
#define HDIM   64
#define NEXP   8
#define FFDIM  4096

#define VMW(n)   asm volatile("s_waitcnt vmcnt(" #n ")" ::: "memory")
#define SBAR()   __builtin_amdgcn_s_barrier()
#define SCHED0() __builtin_amdgcn_sched_barrier(0)

__device__ __forceinline__ u16 f2bf(float f) {          // RNE
  union { float f; u32 u; } v; v.f = f;
  u32 r = v.u + 0x7FFFu + ((v.u >> 16) & 1u);
  return (u16)(r >> 16);
}
__device__ __forceinline__ float bf2f(u16 h) {
  union { u32 u; float f; } v; v.u = ((u32)h) << 16; return v.f;
}

// async 16B global->LDS (wave-uniform LDS base; HW adds lane*16)
__device__ __forceinline__ void g2l16(const u16* src, u16* ldsbase) {
  __builtin_amdgcn_global_load_lds(
      (const __attribute__((address_space(1))) void*)src,
      (__attribute__((address_space(3))) void*)ldsbase, 16, 0, 0);
}

// split 16 f32 -> 8 packed u32 hi + 8 packed u32 lo
__device__ __forceinline__ void split16(const float* src, u32* H, u32* L) {
  #pragma unroll
  for (int j = 0; j < 8; ++j) {
    float a = src[2*j], b = src[2*j+1];
    u16 ha = f2bf(a), hb = f2bf(b);
    u16 la = f2bf(a - bf2f(ha)), lb = f2bf(b - bf2f(hb));
    H[j] = (u32)ha | ((u32)hb << 16);
    L[j] = (u32)la | ((u32)lb << 16);
  }
}

// ---------------- RMSNorm -> hi/lo bf16 split (for GEMM A-operand) ---------
__global__ __launch_bounds__(256) void tb_rms_hl(const float* __restrict__ x,
    const float* __restrict__ scale, u16* __restrict__ oh, u16* __restrict__ ol) {
  int t = blockIdx.x, tid = threadIdx.x;
  const float* xr = x + (size_t)t * DMODEL;
  float4 v = *(const float4*)(xr + tid * 4);
  double ss = (double)v.x*v.x + (double)v.y*v.y + (double)v.z*v.z + (double)v.w*v.w;
  #pragma unroll
  for (int off = 32; off; off >>= 1) ss += __shfl_xor(ss, off);
  __shared__ double red[4];
  if ((tid & 63) == 0) red[tid >> 6] = ss;
  __syncthreads();
  double denom = sqrt((red[0]+red[1]+red[2]+red[3]) / (double)DMODEL) + 1e-5;
  float4 sc = *(const float4*)(scale + tid * 4);
  float y[4];
  y[0] = (float)((double)v.x / denom * (double)sc.x);
  y[1] = (float)((double)v.y / denom * (double)sc.y);
  y[2] = (float)((double)v.z / denom * (double)sc.z);
  y[3] = (float)((double)v.w / denom * (double)sc.w);
  u16* ph = oh + (size_t)t*DMODEL + tid*4;
  u16* pl = ol + (size_t)t*DMODEL + tid*4;
  #pragma unroll
  for (int j = 0; j < 4; ++j) {
    u16 h = f2bf(y[j]);
    ph[j] = h;
    pl[j] = f2bf(y[j] - bf2f(h));
  }
}

// ---------------- RMSNorm (f64 accumulate; f32 + bf16 outputs) -------------
__global__ __launch_bounds__(256) void tb_rms(const float* __restrict__ x,
    const float* __restrict__ scale, float* __restrict__ out_f, u16* __restrict__ out_b) {
  int t = blockIdx.x, tid = threadIdx.x;
  const float* xr = x + (size_t)t * DMODEL;
  float4 v = *(const float4*)(xr + tid * 4);
  double ss = (double)v.x*v.x + (double)v.y*v.y + (double)v.z*v.z + (double)v.w*v.w;
  #pragma unroll
  for (int off = 32; off; off >>= 1) ss += __shfl_xor(ss, off);
  __shared__ double red[4];
  if ((tid & 63) == 0) red[tid >> 6] = ss;
  __syncthreads();
  double denom = sqrt((red[0]+red[1]+red[2]+red[3]) / (double)DMODEL) + 1e-5;
  float4 sc = *(const float4*)(scale + tid * 4);
  float y0 = (float)((double)v.x / denom * (double)sc.x);
  float y1 = (float)((double)v.y / denom * (double)sc.y);
  float y2 = (float)((double)v.z / denom * (double)sc.z);
  float y3 = (float)((double)v.w / denom * (double)sc.w);
  *(float4*)(out_f + (size_t)t*DMODEL + tid*4) = make_float4(y0,y1,y2,y3);
  u16* ob = out_b + (size_t)t*DMODEL + tid*4;
  ob[0]=f2bf(y0); ob[1]=f2bf(y1); ob[2]=f2bf(y2); ob[3]=f2bf(y3);
}

// ------- weight pre-split+transpose: W[k][n] f32 -> Wt[n][k] bf16 (hi[,lo]) -
template<int HILO>
__global__ __launch_bounds__(256) void tb_wsplit(const float* __restrict__ W,
    u16* __restrict__ Wh, u16* __restrict__ Wl, int K, int N) {
  __shared__ float Tf[64*68];
  size_t eo = (size_t)blockIdx.z * (size_t)K * N;
  const float* Wb = W + eo;
  int n0 = blockIdx.x*64, k0 = blockIdx.y*64;
  int tid = threadIdx.x;
  int r = tid >> 2, c = tid & 3;
  const float* wp = Wb + (size_t)(k0+r)*N + n0 + c*16;
  float vv[16];
  *(float4*)&vv[0]  = ((const float4*)wp)[0];
  *(float4*)&vv[4]  = ((const float4*)wp)[1];
  *(float4*)&vv[8]  = ((const float4*)wp)[2];
  *(float4*)&vv[12] = ((const float4*)wp)[3];
  #pragma unroll
  for (int j = 0; j < 16; ++j) Tf[(c*16+j)*68 + r] = vv[j];
  __syncthreads();
  int n = tid >> 2, kc = tid & 3;
  float tv[16];
  #pragma unroll
  for (int j = 0; j < 16; ++j) tv[j] = Tf[n*68 + kc*16 + j];
  u32 H[8], L[8];
  split16(tv, H, L);
  u16* oh = Wh + eo + (size_t)(n0+n)*K + k0 + kc*16;
  *(uint4*)oh       = make_uint4(H[0],H[1],H[2],H[3]);
  *(uint4*)(oh + 8) = make_uint4(H[4],H[5],H[6],H[7]);
  if (HILO) {
    u16* ol = Wl + eo + (size_t)(n0+n)*K + k0 + kc*16;
    *(uint4*)ol       = make_uint4(L[0],L[1],L[2],L[3]);
    *(uint4*)(ol + 8) = make_uint4(L[4],L[5],L[6],L[7]);
  }
}

// --- split-bf16 MFMA GEMM, all operands via global_load_lds ----------------
// Depth-3 early-issue pipeline: stage(t+2) issues BEFORE compute(t), so the
// steady-state period is max(C, L/2) instead of depth-2's L+C.
template<int RESID>
__global__ __launch_bounds__(256) void tb_gemm_sp2(const u16* __restrict__ Ahg,
    const u16* __restrict__ Alg, const u16* __restrict__ Bhg,
    const u16* __restrict__ Blg, const float* __restrict__ bias,
    const float* __restrict__ resid, float* __restrict__ C,
    int M, int N, int K) {
  __shared__ __align__(16) u16 Ah[3][128*32], Al[3][128*32];
  __shared__ __align__(16) u16 Bh[3][128*32], Bl[3][128*32];   // 96KB total
  int tid = threadIdx.x;
  int row0 = blockIdx.y * 128, col0 = blockIdx.x * 128;
  int lane = tid & 63, wave = tid >> 6;
  int wm = wave >> 1, wn = wave & 1;
  int l15 = lane & 15, l4 = lane >> 4;
  int sw = (l15 >> 1) & 3;
  int ci0 = ((wave*2+0)<<6)+lane, ci1 = ((wave*2+1)<<6)+lane;
  int r0 = ci0 >> 2, c0 = ((ci0 & 3) ^ ((r0 >> 1) & 3)) << 3;
  int r1 = ci1 >> 2, c1 = ((ci1 & 3) ^ ((r1 >> 1) & 3)) << 3;
  int lo0 = (wave*2+0) << 9, lo1 = (wave*2+1) << 9;
  f32x4 zero = {0.f,0.f,0.f,0.f};
  f32x4 acc[4][4];
  #pragma unroll
  for (int i=0;i<4;++i) for (int j=0;j<4;++j) acc[i][j] = zero;
  const int nt = K / 32;

  #define SP2_STAGE(b, k0) do { \
    g2l16(Ahg + (size_t)(row0+r0)*K + (k0) + c0, &Ah[b][lo0]); \
    g2l16(Ahg + (size_t)(row0+r1)*K + (k0) + c1, &Ah[b][lo1]); \
    g2l16(Alg + (size_t)(row0+r0)*K + (k0) + c0, &Al[b][lo0]); \
    g2l16(Alg + (size_t)(row0+r1)*K + (k0) + c1, &Al[b][lo1]); \
    g2l16(Bhg + (size_t)(col0+r0)*K + (k0) + c0, &Bh[b][lo0]); \
    g2l16(Bhg + (size_t)(col0+r1)*K + (k0) + c1, &Bh[b][lo1]); \
    g2l16(Blg + (size_t)(col0+r0)*K + (k0) + c0, &Bl[b][lo0]); \
    g2l16(Blg + (size_t)(col0+r1)*K + (k0) + c1, &Bl[b][lo1]); } while(0)

  SP2_STAGE(0, 0);
  SP2_STAGE(1, 32);
  int cur = 0;
  for (int t = 0; t < nt; ++t) {
    int sb = cur + 2; if (sb >= 3) sb -= 3;
    if (t + 2 < nt) SP2_STAGE(sb, (t+2)*32);       // early issue into free buf
    if (t + 2 < nt) { VMW(16); } else if (t + 1 < nt) { VMW(8); } else { VMW(0); }
    SBAR(); SCHED0();
    bf16x8 ah[4], al_[4], bh_[4], bl_[4];
    #pragma unroll
    for (int mi = 0; mi < 4; ++mi) {
      int ro = (wm*64 + mi*16 + l15) << 5;
      ah[mi]  = *(const bf16x8*)(&Ah[cur][ro + ((l4 ^ sw) << 3)]);
      al_[mi] = *(const bf16x8*)(&Al[cur][ro + ((l4 ^ sw) << 3)]);
    }
    #pragma unroll
    for (int ni = 0; ni < 4; ++ni) {
      int ro = (wn*64 + ni*16 + l15) << 5;
      bh_[ni] = *(const bf16x8*)(&Bh[cur][ro + ((l4 ^ sw) << 3)]);
      bl_[ni] = *(const bf16x8*)(&Bl[cur][ro + ((l4 ^ sw) << 3)]);
    }
    #pragma unroll
    for (int mi = 0; mi < 4; ++mi)
      #pragma unroll
      for (int ni = 0; ni < 4; ++ni) {
        acc[mi][ni] = __builtin_amdgcn_mfma_f32_16x16x32_bf16(ah[mi], bh_[ni], acc[mi][ni], 0,0,0);
        acc[mi][ni] = __builtin_amdgcn_mfma_f32_16x16x32_bf16(ah[mi], bl_[ni], acc[mi][ni], 0,0,0);
        acc[mi][ni] = __builtin_amdgcn_mfma_f32_16x16x32_bf16(al_[mi], bh_[ni], acc[mi][ni], 0,0,0);
      }
    SBAR();                                        // readers done with buf[cur]
    cur = (cur == 2) ? 0 : cur + 1;
  }
  #undef SP2_STAGE
  #pragma unroll
  for (int mi = 0; mi < 4; ++mi)
    #pragma unroll
    for (int r = 0; r < 4; ++r) {
      int row = row0 + wm*64 + mi*16 + l4*4 + r;
      #pragma unroll
      for (int ni = 0; ni < 4; ++ni) {
        int col = col0 + wn*64 + ni*16 + l15;
        float vv = acc[mi][ni][r] + bias[col];
        if (RESID) vv += resid[(size_t)row*N + col];
        C[(size_t)row*N + col] = vv;
      }
    }
}

// ---------------- RoPE trig table (f64) ------------------------------------
__global__ void tb_trig(float* __restrict__ tab) {
  int t = blockIdx.x, d = threadIdx.x;
  double theta = pow(10000.0, -(double)d / 32.0);
  double ang = (double)t * theta;
  tab[(t*32 + d)*2 + 0] = (float)cos(ang);
  tab[(t*32 + d)*2 + 1] = (float)sin(ang);
}

// ---------------- qkv -> Q f32, K bf16 hi/lo (all [bh][t][d]), V f32 -------
__global__ __launch_bounds__(256) void tb_rope2(const float* __restrict__ qkv,
    const float* __restrict__ tab, float* __restrict__ Qf, u16* __restrict__ Khg,
    u16* __restrict__ Klg, float* __restrict__ Vf) {
  int n = blockIdx.x;
  int b = n >> 10, t = n & 1023;
  const float* src = qkv + (size_t)n * 3072;
  for (int idx = threadIdx.x; idx < 512; idx += 256) {
    int h = idx >> 5, d = idx & 31;
    float ca = tab[(t*32+d)*2], sa = tab[(t*32+d)*2+1];
    size_t base = ((size_t)(b*NHEAD + h) * T_LEN + t) * HDIM;
    { float x1 = src[h*64 + d], x2 = src[h*64 + d + 32];
      Qf[base + d]      = x1*ca - x2*sa;
      Qf[base + d + 32] = x1*sa + x2*ca; }
    { float x1 = src[1024 + h*64 + d], x2 = src[1024 + h*64 + d + 32];
      float k1 = x1*ca - x2*sa, k2 = x1*sa + x2*ca;
      u16 h1 = f2bf(k1), h2 = f2bf(k2);
      Khg[base + d] = h1;      Khg[base + d + 32] = h2;
      Klg[base + d] = f2bf(k1 - bf2f(h1));
      Klg[base + d + 32] = f2bf(k2 - bf2f(h2)); }
  }
  for (int c = threadIdx.x; c < 1024; c += 256) {
    int h = c >> 6, d = c & 63;
    Vf[((size_t)(b*NHEAD + h) * T_LEN + t) * HDIM + d] = src[2048 + c];
  }
}

// ---------------- V transpose+split: [bh][t][d] f32 -> [bh][d][t] bf16 -----
__global__ __launch_bounds__(256) void tb_vt(const float* __restrict__ Vf,
    u16* __restrict__ Vh, u16* __restrict__ Vl) {
  __shared__ float Tf[64*68];
  int t0 = blockIdx.x * 64, bh = blockIdx.y;
  const float* Vb = Vf + (size_t)bh * (T_LEN*HDIM);
  int tid = threadIdx.x, r = tid >> 2, c = tid & 3;
  const float* vp = Vb + (size_t)(t0+r)*HDIM + c*16;
  float vv[16];
  *(float4*)&vv[0]  = ((const float4*)vp)[0];
  *(float4*)&vv[4]  = ((const float4*)vp)[1];
  *(float4*)&vv[8]  = ((const float4*)vp)[2];
  *(float4*)&vv[12] = ((const float4*)vp)[3];
  #pragma unroll
  for (int j = 0; j < 16; ++j) Tf[(c*16+j)*68 + r] = vv[j];
  __syncthreads();
  int d = tid >> 2, tc = tid & 3;
  float tv[16];
  #pragma unroll
  for (int j = 0; j < 16; ++j) tv[j] = Tf[d*68 + tc*16 + j];
  u32 H[8], L[8];
  split16(tv, H, L);
  u16* oh = Vh + (size_t)bh*(HDIM*T_LEN) + (size_t)d*T_LEN + t0 + tc*16;
  u16* ol = Vl + (size_t)bh*(HDIM*T_LEN) + (size_t)d*T_LEN + t0 + tc*16;
  *(uint4*)oh       = make_uint4(H[0],H[1],H[2],H[3]);
  *(uint4*)(oh + 8) = make_uint4(H[4],H[5],H[6],H[7]);
  *(uint4*)ol       = make_uint4(L[0],L[1],L[2],L[3]);
  *(uint4*)(ol + 8) = make_uint4(L[4],L[5],L[6],L[7]);
}

// ---------------- MFMA flash attention; writes O as hi/lo bf16 split -------
__global__ __launch_bounds__(256) void tb_attn_mfma(const float* __restrict__ Qf,
    const u16* __restrict__ Khg, const u16* __restrict__ Klg,
    const u16* __restrict__ Vhg, const u16* __restrict__ Vlg,
    u16* __restrict__ Obh, u16* __restrict__ Obl) {
  __shared__ __align__(16) u16 Kh[64*72], Kl[64*72];
  __shared__ __align__(16) u16 Vh[64*72], Vl[64*72];
  __shared__ __align__(16) u16 Ph[64*72], Pl[64*72];
  int qt = blockIdx.x, bh = blockIdx.y;
  int tid = threadIdx.x, lane = tid & 63, w = tid >> 6;
  int l15 = lane & 15, l4 = lane >> 4;
  int b = bh >> 4, h = bh & 15;
  const float* Qb = Qf + (size_t)bh * (T_LEN*HDIM);
  const u16* Khb = Khg + (size_t)bh * (T_LEN*HDIM);
  const u16* Klb = Klg + (size_t)bh * (T_LEN*HDIM);
  const u16* Vhb = Vhg + (size_t)bh * (HDIM*T_LEN);
  const u16* Vlb = Vlg + (size_t)bh * (HDIM*T_LEN);
  int q0 = qt * 64;
  int qrow = q0 + w*16 + l15;
  bf16x8 qh[2], ql[2];
  #pragma unroll
  for (int ks = 0; ks < 2; ++ks) {
    const float* qp = Qb + (size_t)qrow*HDIM + ks*32 + l4*8;
    float vv[8];
    *(float4*)&vv[0] = ((const float4*)qp)[0];
    *(float4*)&vv[4] = ((const float4*)qp)[1];
    u32 H[4], L[4];
    #pragma unroll
    for (int j = 0; j < 4; ++j) {
      float a = vv[2*j], bb = vv[2*j+1];
      u16 ha = f2bf(a), hb = f2bf(bb);
      u16 la = f2bf(a - bf2f(ha)), lb = f2bf(bb - bf2f(hb));
      H[j] = (u32)ha | ((u32)hb << 16);
      L[j] = (u32)la | ((u32)lb << 16);
    }
    union { uint4 u; bf16x8 b; } th, tl;
    th.u = make_uint4(H[0],H[1],H[2],H[3]);
    tl.u = make_uint4(L[0],L[1],L[2],L[3]);
    qh[ks] = th.b; ql[ks] = tl.b;
  }
  int qg[4];
  #pragma unroll
  for (int r = 0; r < 4; ++r) qg[r] = q0 + w*16 + l4*4 + r;
  float mrow[4], lrow[4];
  f32x4 oacc[4];
  f32x4 zero = {0.f,0.f,0.f,0.f};
  #pragma unroll
  for (int r = 0; r < 4; ++r) { mrow[r] = -1e30f; lrow[r] = 0.f; }
  #pragma unroll
  for (int d = 0; d < 4; ++d) oacc[d] = zero;

  int sr = tid >> 2, sc = tid & 3;
  for (int kt = 0; kt <= qt; ++kt) {
    int k0 = kt * 64;
    __syncthreads();
    {
      const u16* kp = Khb + (size_t)(k0+sr)*HDIM + sc*16;
      *(uint4*)(Kh + sr*72 + sc*16)     = ((const uint4*)kp)[0];
      *(uint4*)(Kh + sr*72 + sc*16 + 8) = ((const uint4*)kp)[1];
      const u16* kl2 = Klb + (size_t)(k0+sr)*HDIM + sc*16;
      *(uint4*)(Kl + sr*72 + sc*16)     = ((const uint4*)kl2)[0];
      *(uint4*)(Kl + sr*72 + sc*16 + 8) = ((const uint4*)kl2)[1];
      const u16* vp = Vhb + (size_t)sr*T_LEN + k0 + sc*16;
      *(uint4*)(Vh + sr*72 + sc*16)     = ((const uint4*)vp)[0];
      *(uint4*)(Vh + sr*72 + sc*16 + 8) = ((const uint4*)vp)[1];
      const u16* vl2 = Vlb + (size_t)sr*T_LEN + k0 + sc*16;
      *(uint4*)(Vl + sr*72 + sc*16)     = ((const uint4*)vl2)[0];
      *(uint4*)(Vl + sr*72 + sc*16 + 8) = ((const uint4*)vl2)[1];
    }
    __syncthreads();
    f32x4 sacc[4];
    #pragma unroll
    for (int ni = 0; ni < 4; ++ni) {
      sacc[ni] = zero;
      #pragma unroll
      for (int ks = 0; ks < 2; ++ks) {
        bf16x8 kh_ = *(const bf16x8*)(Kh + (ni*16 + l15)*72 + ks*32 + l4*8);
        bf16x8 kl_ = *(const bf16x8*)(Kl + (ni*16 + l15)*72 + ks*32 + l4*8);
        sacc[ni] = __builtin_amdgcn_mfma_f32_16x16x32_bf16(qh[ks], kh_, sacc[ni], 0,0,0);
        sacc[ni] = __builtin_amdgcn_mfma_f32_16x16x32_bf16(qh[ks], kl_, sacc[ni], 0,0,0);
        sacc[ni] = __builtin_amdgcn_mfma_f32_16x16x32_bf16(ql[ks], kh_, sacc[ni], 0,0,0);
      }
    }
    bool diag = (kt == qt);
    float sv[4][4];
    #pragma unroll
    for (int ni = 0; ni < 4; ++ni)
      #pragma unroll
      for (int r = 0; r < 4; ++r) {
        float s = sacc[ni][r] * 0.125f;
        if (diag && (k0 + ni*16 + l15 > qg[r])) s = -1e30f;
        sv[ni][r] = s;
      }
    float mt[4];
    #pragma unroll
    for (int r = 0; r < 4; ++r)
      mt[r] = fmaxf(fmaxf(sv[0][r], sv[1][r]), fmaxf(sv[2][r], sv[3][r]));
    #pragma unroll
    for (int off = 1; off < 16; off <<= 1)
      #pragma unroll
      for (int r = 0; r < 4; ++r) mt[r] = fmaxf(mt[r], __shfl_xor(mt[r], off));
    float al[4];
    #pragma unroll
    for (int r = 0; r < 4; ++r) {
      float mn = fmaxf(mrow[r], mt[r]);
      al[r] = expf(mrow[r] - mn);
      mrow[r] = mn;
    }
    float ls[4] = {0.f,0.f,0.f,0.f};
    #pragma unroll
    for (int ni = 0; ni < 4; ++ni)
      #pragma unroll
      for (int r = 0; r < 4; ++r) {
        float p = expf(sv[ni][r] - mrow[r]);
        u16 ph2 = f2bf(p);
        int qrl = w*16 + l4*4 + r;
        Ph[qrl*72 + ni*16 + l15] = ph2;
        Pl[qrl*72 + ni*16 + l15] = f2bf(p - bf2f(ph2));
        ls[r] += p;
      }
    #pragma unroll
    for (int off = 1; off < 16; off <<= 1)
      #pragma unroll
      for (int r = 0; r < 4; ++r) ls[r] += __shfl_xor(ls[r], off);
    #pragma unroll
    for (int r = 0; r < 4; ++r) lrow[r] = lrow[r]*al[r] + ls[r];
    #pragma unroll
    for (int d = 0; d < 4; ++d)
      #pragma unroll
      for (int r = 0; r < 4; ++r) oacc[d][r] *= al[r];
    bf16x8 ph_[2], pl_[2];
    #pragma unroll
    for (int ks = 0; ks < 2; ++ks) {
      ph_[ks] = *(const bf16x8*)(Ph + (w*16 + l15)*72 + ks*32 + l4*8);
      pl_[ks] = *(const bf16x8*)(Pl + (w*16 + l15)*72 + ks*32 + l4*8);
    }
    #pragma unroll
    for (int dblk = 0; dblk < 4; ++dblk)
      #pragma unroll
      for (int ks = 0; ks < 2; ++ks) {
        bf16x8 vh_ = *(const bf16x8*)(Vh + (dblk*16 + l15)*72 + ks*32 + l4*8);
        bf16x8 vl_ = *(const bf16x8*)(Vl + (dblk*16 + l15)*72 + ks*32 + l4*8);
        oacc[dblk] = __builtin_amdgcn_mfma_f32_16x16x32_bf16(ph_[ks], vh_, oacc[dblk], 0,0,0);
        oacc[dblk] = __builtin_amdgcn_mfma_f32_16x16x32_bf16(ph_[ks], vl_, oacc[dblk], 0,0,0);
        oacc[dblk] = __builtin_amdgcn_mfma_f32_16x16x32_bf16(pl_[ks], vh_, oacc[dblk], 0,0,0);
      }
  }
  #pragma unroll
  for (int dblk = 0; dblk < 4; ++dblk)
    #pragma unroll
    for (int r = 0; r < 4; ++r) {
      int q = qg[r];
      int d = dblk*16 + l15;
      float ov = oacc[dblk][r] / lrow[r];
      u16 hh = f2bf(ov);
      size_t oi = ((size_t)b * T_LEN + q) * DMODEL + h * HDIM + d;
      Obh[oi] = hh;
      Obl[oi] = f2bf(ov - bf2f(hh));
    }
}

// ---------------- router: f64 logits, top-2 --------------------------------
__global__ __launch_bounds__(64) void tb_gating(const float* __restrict__ xn2,
    const float* __restrict__ wg, const float* __restrict__ bg,
    int* __restrict__ top_idx, float* __restrict__ gate_w, int* __restrict__ counts) {
  int t = blockIdx.x, lane = threadIdx.x;
  const float* xr = xn2 + (size_t)t * DMODEL;
  double part[8];
  #pragma unroll
  for (int e = 0; e < 8; ++e) part[e] = 0.0;
  for (int i = lane; i < DMODEL; i += 64) {
    double xv = (double)xr[i];
    const float* wr = wg + (size_t)i * 8;
    #pragma unroll
    for (int e = 0; e < 8; ++e) part[e] += xv * (double)wr[e];
  }
  #pragma unroll
  for (int e = 0; e < 8; ++e)
    for (int off = 32; off; off >>= 1) part[e] += __shfl_xor(part[e], off);
  if (lane == 0) {
    double lg[8];
    for (int e = 0; e < 8; ++e) lg[e] = part[e] + (double)bg[e];
    int i1 = 0;
    for (int e = 1; e < 8; ++e) if (lg[e] > lg[i1]) i1 = e;
    int i2 = (i1 == 0) ? 1 : 0;
    for (int e = 0; e < 8; ++e) if (e != i1 && lg[e] > lg[i2]) i2 = e;
    double e2 = exp(lg[i2] - lg[i1]);
    double den = 1.0 + e2;
    top_idx[t*2] = i1; top_idx[t*2+1] = i2;
    gate_w[t*2] = (float)(1.0/den); gate_w[t*2+1] = (float)(e2/den);
    atomicAdd(&counts[i1], 1); atomicAdd(&counts[i2], 1);
  }
}

__global__ void tb_scan(const int* __restrict__ counts, int* __restrict__ offs,
    int* __restrict__ cursor, float* __restrict__ aux_out) {
  if (threadIdx.x == 0) {
    int off = 0; float aux = 0.f;
    for (int e = 0; e < 8; ++e) {
      offs[e] = off; cursor[e] = off; off += counts[e];
      float fr = (float)counts[e] / 4096.0f - 0.125f;
      aux += fr * fr;
    }
    aux_out[0] = aux;
  }
}

__global__ __launch_bounds__(128) void tb_gather(const u16* __restrict__ xn2b,
    const int* __restrict__ top_idx, int* __restrict__ cursor,
    int* __restrict__ slot_of, u16* __restrict__ Xg) {
  int t = blockIdx.x;
  __shared__ int sl[2];
  if (threadIdx.x < 2) {
    int e = top_idx[t*2 + threadIdx.x];
    int s = atomicAdd(&cursor[e], 1);
    sl[threadIdx.x] = s;
    slot_of[t*2 + threadIdx.x] = s;
  }
  __syncthreads();
  uint4 v = *(const uint4*)(xn2b + (size_t)t * DMODEL + threadIdx.x * 8);
  *(uint4*)(Xg + (size_t)sl[0] * DMODEL + threadIdx.x * 8) = v;
  *(uint4*)(Xg + (size_t)sl[1] * DMODEL + threadIdx.x * 8) = v;
}

// --- fused MoE MLP: 256m x 128n tile, 8 waves, bf16 weights ----------------
// Depth-3 early-issue pipeline (see tb_gemm_sp2 comment). 96KB LDS.
__global__ __launch_bounds__(512, 1) void tb_moe_mlp2(const u16* __restrict__ Ag,
    const u16* __restrict__ B1t, const u16* __restrict__ B2t,
    const float* __restrict__ b1g, const float* __restrict__ b2g,
    u16* __restrict__ Hout, const int* __restrict__ counts,
    const int* __restrict__ offs, int ebase) {
  const int K = DMODEL, N = FFDIM;
  int ez = blockIdx.z, e = ebase + ez;
  int cnt = counts[e];
  if ((int)blockIdx.y * 256 >= cnt) return;
  int row0 = offs[e] + blockIdx.y * 256;
  int rend = offs[e] + cnt;
  int col0 = blockIdx.x * 128;
  const u16* B1 = B1t + (size_t)ez * K * N;
  const u16* B2 = B2t + (size_t)ez * K * N;
  const float* bb1 = b1g + (size_t)e * N;
  const float* bb2 = b2g + (size_t)e * N;
  __shared__ __align__(16) u16 As[3][256*32];    // 48KB
  __shared__ __align__(16) u16 Bs1[3][128*32];   // 24KB
  __shared__ __align__(16) u16 Bs2[3][128*32];   // 24KB
  int tid = threadIdx.x, lane = tid & 63, wave = tid >> 6;  // 8 waves
  int wm = wave >> 1, wn = wave & 1;
  int l15 = lane & 15, l4 = lane >> 4;
  int sw = (l15 >> 1) & 3;
  int ai0 = ((wave*2+0)<<6) + lane, ai1 = ((wave*2+1)<<6) + lane;
  int ar0 = ai0 >> 2, ac0 = ((ai0 & 3) ^ ((ar0 >> 1) & 3)) << 3;
  int ar1 = ai1 >> 2, ac1 = ((ai1 & 3) ^ ((ar1 >> 1) & 3)) << 3;
  int ga0 = row0 + ar0 < rend ? row0 + ar0 : rend - 1;
  int ga1 = row0 + ar1 < rend ? row0 + ar1 : rend - 1;
  int alo0 = (wave*2+0) << 9, alo1 = (wave*2+1) << 9;
  int bi = (wave << 6) + lane;
  int br = bi >> 2, bc = ((bi & 3) ^ ((br >> 1) & 3)) << 3;
  int blo = wave << 9;
  f32x4 zero = {0.f,0.f,0.f,0.f};
  f32x4 acc1[4][4], acc2[4][4];
  #pragma unroll
  for (int i=0;i<4;++i) for (int j=0;j<4;++j) { acc1[i][j] = zero; acc2[i][j] = zero; }

  #define MLP2_STAGE(b, k0) do { \
    g2l16(Ag + (size_t)ga0*K + (k0) + ac0,        &As[b][alo0]); \
    g2l16(Ag + (size_t)ga1*K + (k0) + ac1,        &As[b][alo1]); \
    g2l16(B1 + (size_t)(col0+br)*K + (k0) + bc,  &Bs1[b][blo]); \
    g2l16(B2 + (size_t)(col0+br)*K + (k0) + bc,  &Bs2[b][blo]); } while(0)

  MLP2_STAGE(0, 0);
  MLP2_STAGE(1, 32);
  const int nt = K / 32;
  int cur = 0;
  for (int t = 0; t < nt; ++t) {
    int sb = cur + 2; if (sb >= 3) sb -= 3;
    if (t + 2 < nt) MLP2_STAGE(sb, (t+2)*32);      // early issue into free buf
    if (t + 2 < nt) { VMW(8); } else if (t + 1 < nt) { VMW(4); } else { VMW(0); }
    SBAR(); SCHED0();
    bf16x8 af[4], bf1[4], bf2[4];
    #pragma unroll
    for (int mi = 0; mi < 4; ++mi)
      af[mi] = *(const bf16x8*)(&As[cur][((wm*64 + mi*16 + l15) << 5) + ((l4 ^ sw) << 3)]);
    #pragma unroll
    for (int ni = 0; ni < 4; ++ni)
      bf1[ni] = *(const bf16x8*)(&Bs1[cur][((wn*64 + ni*16 + l15) << 5) + ((l4 ^ sw) << 3)]);
    #pragma unroll
    for (int mi = 0; mi < 4; ++mi)
      #pragma unroll
      for (int ni = 0; ni < 4; ++ni)
        acc1[mi][ni] = __builtin_amdgcn_mfma_f32_16x16x32_bf16(af[mi], bf1[ni], acc1[mi][ni], 0,0,0);
    #pragma unroll
    for (int ni = 0; ni < 4; ++ni)
      bf2[ni] = *(const bf16x8*)(&Bs2[cur][((wn*64 + ni*16 + l15) << 5) + ((l4 ^ sw) << 3)]);
    #pragma unroll
    for (int mi = 0; mi < 4; ++mi)
      #pragma unroll
      for (int ni = 0; ni < 4; ++ni)
        acc2[mi][ni] = __builtin_amdgcn_mfma_f32_16x16x32_bf16(af[mi], bf2[ni], acc2[mi][ni], 0,0,0);
    SBAR();                                        // readers done with buf[cur]
    cur = (cur == 2) ? 0 : cur + 1;
  }
  #undef MLP2_STAGE
  #pragma unroll
  for (int mi = 0; mi < 4; ++mi) {
    #pragma unroll
    for (int r = 0; r < 4; ++r) {
      int row = row0 + wm*64 + mi*16 + l4*4 + r;
      if (row >= rend) continue;
      #pragma unroll
      for (int ni = 0; ni < 4; ++ni) {
        int col = col0 + wn*64 + ni*16 + l15;
        float v1 = acc1[mi][ni][r] + bb1[col];
        float v2 = acc2[mi][ni][r] + bb2[col];
        float hv = (v1 / (1.f + expf(-v1))) * v2;
        Hout[(size_t)row * N + col] = f2bf(hv);
      }
    }
  }
}

// --- MoE down-proj, split-K=4, in-kernel f32 convert; partials (no bias) ---
__global__ __launch_bounds__(256) void tb_moe_wp(const u16* __restrict__ Ag,
    const float* __restrict__ Wp, float* __restrict__ Pout,
    const int* __restrict__ counts, const int* __restrict__ offs) {
  const int K = FFDIM, N = DMODEL;
  int e = blockIdx.z & 7, ks = blockIdx.z >> 3;
  int cnt = counts[e];
  if ((int)blockIdx.y * 128 >= cnt) return;
  int row0 = offs[e] + blockIdx.y * 128;
  int rend = offs[e] + cnt;
  int col0 = blockIdx.x * 128;
  int kbase = ks * 1024;
  const float* Bw = Wp + (size_t)e * K * N;
  float* out = Pout + (size_t)ks * (4096u*1024u);
  __shared__ __align__(16) u16 As[2][128*32], Bs[2][128*32];
  int tid = threadIdx.x, lane = tid & 63, wave = tid >> 6;
  int wm = wave >> 1, wn = wave & 1;
  int l15 = lane & 15, l4 = lane >> 4;
  int sw = (l15 >> 1) & 3;
  int ci0 = ((wave*2+0)<<6) + lane, ci1 = ((wave*2+1)<<6) + lane;
  int ar0 = ci0 >> 2, ac0 = ((ci0 & 3) ^ ((ar0 >> 1) & 3)) << 3;
  int ar1 = ci1 >> 2, ac1 = ((ci1 & 3) ^ ((ar1 >> 1) & 3)) << 3;
  int ga0 = row0 + ar0 < rend ? row0 + ar0 : rend - 1;
  int ga1 = row0 + ar1 < rend ? row0 + ar1 : rend - 1;
  int lo0 = (wave*2+0) << 9, lo1 = (wave*2+1) << 9;
  int bn = tid & 127;
  int bkg = (tid >> 7) << 4;
  int bsw = (bn >> 1) & 3;
  int bc0 = bkg >> 3;
  int boff0 = bn*32 + (( bc0    ^ bsw) << 3);
  int boff1 = bn*32 + (((bc0+1) ^ bsw) << 3);
  f32x4 zero = {0.f,0.f,0.f,0.f};
  f32x4 acc[4][4];
  #pragma unroll
  for (int i=0;i<4;++i) for (int j=0;j<4;++j) acc[i][j] = zero;
  float r1[16];

  #define WP_ISSUE_A(b, k0) do { \
    g2l16(Ag + (size_t)ga0*K + kbase + (k0) + ac0, &As[b][lo0]); \
    g2l16(Ag + (size_t)ga1*K + kbase + (k0) + ac1, &As[b][lo1]); } while(0)
  #define WP_LOAD_B(k0) do { \
    const float* p1 = Bw + (size_t)(kbase+(k0)+bkg)*N + col0 + bn; \
    _Pragma("unroll") \
    for (int j = 0; j < 16; ++j) r1[j] = p1[(size_t)j*N]; } while(0)
  #define WP_WRITE_B(b) do { \
    u32 P1[8]; \
    _Pragma("unroll") \
    for (int j = 0; j < 8; ++j) \
      asm("v_cvt_pk_bf16_f32 %0, %1, %2" : "=v"(P1[j]) : "v"(r1[2*j]), "v"(r1[2*j+1])); \
    *(uint4*)(&Bs[b][boff0]) = make_uint4(P1[0],P1[1],P1[2],P1[3]); \
    *(uint4*)(&Bs[b][boff1]) = make_uint4(P1[4],P1[5],P1[6],P1[7]); } while(0)

  WP_ISSUE_A(0, 0);
  WP_LOAD_B(0);
  VMW(0);
  WP_WRITE_B(0);
  asm volatile("s_waitcnt lgkmcnt(0)" ::: "memory");
  SBAR();
  const int nt = 1024 / 32;
  for (int t = 0; t < nt; ++t) {
    int cur = t & 1;
    if (t + 1 < nt) { WP_ISSUE_A(cur^1, (t+1)*32); WP_LOAD_B((t+1)*32); }
    bf16x8 af[4], bfr[4];
    #pragma unroll
    for (int mi = 0; mi < 4; ++mi)
      af[mi] = *(const bf16x8*)(&As[cur][((wm*64 + mi*16 + l15) << 5) + ((l4 ^ sw) << 3)]);
    #pragma unroll
    for (int ni = 0; ni < 4; ++ni)
      bfr[ni] = *(const bf16x8*)(&Bs[cur][((wn*64 + ni*16 + l15) << 5) + ((l4 ^ sw) << 3)]);
    #pragma unroll
    for (int mi = 0; mi < 4; ++mi)
      #pragma unroll
      for (int ni = 0; ni < 4; ++ni)
        acc[mi][ni] = __builtin_amdgcn_mfma_f32_16x16x32_bf16(af[mi], bfr[ni], acc[mi][ni], 0,0,0);
    if (t + 1 < nt) {
      VMW(0);
      SBAR(); SCHED0();
      WP_WRITE_B(cur ^ 1);
      asm volatile("s_waitcnt lgkmcnt(0)" ::: "memory");
      SBAR();
    }
  }
  #undef WP_ISSUE_A
  #undef WP_LOAD_B
  #undef WP_WRITE_B
  #pragma unroll
  for (int mi = 0; mi < 4; ++mi) {
    #pragma unroll
    for (int r = 0; r < 4; ++r) {
      int row = row0 + wm*64 + mi*16 + l4*4 + r;
      if (row >= rend) continue;
      #pragma unroll
      for (int ni = 0; ni < 4; ++ni) {
        int col = col0 + wn*64 + ni*16 + l15;
        out[(size_t)row * N + col] = acc[mi][ni][r];
      }
    }
  }
}

// --- final: out = x1 + sum_s g_s*(P0..P3[slot_s] + bp[e_s]) -----------------
__global__ __launch_bounds__(256) void tb_combine(const float* __restrict__ x1,
    const float* __restrict__ P, const int* __restrict__ slot_of,
    const int* __restrict__ top_idx, const float* __restrict__ gate_w,
    const float* __restrict__ bp, float* __restrict__ out) {
  const size_t SL = (size_t)4096 * 1024;
  int t = blockIdx.x;
  int c = threadIdx.x * 4;
  float4 a = *(const float4*)(x1 + (size_t)t*DMODEL + c);
  float ox = a.x, oy = a.y, oz = a.z, ow = a.w;
  #pragma unroll
  for (int s = 0; s < 2; ++s) {
    int slot = slot_of[t*2+s], e = top_idx[t*2+s];
    float g = gate_w[t*2+s];
    float4 v = *(const float4*)(bp + (size_t)e*DMODEL + c);
    #pragma unroll
    for (int ks = 0; ks < 4; ++ks) {
      float4 p = *(const float4*)(P + ks*SL + (size_t)slot*DMODEL + c);
      v.x += p.x; v.y += p.y; v.z += p.z; v.w += p.w;
    }
    ox += g*v.x; oy += g*v.y; oz += g*v.z; ow += g*v.w;
  }
  *(float4*)(out + (size_t)t*DMODEL + c) = make_float4(ox,oy,oz,ow);
}

extern "C" void kernel_launch(void* const* d_in, const int* in_sizes, int n_in,
                              void* d_out, int out_size, void* d_ws, size_t ws_size,
                              hipStream_t stream) {
  const float* x      = (const float*)d_in[0];
  const float* w_qkv  = (const float*)d_in[1];
  const float* b_qkv  = (const float*)d_in[2];
  const float* w_out  = (const float*)d_in[3];
  const float* b_out  = (const float*)d_in[4];
  const float* scale1 = (const float*)d_in[5];
  const float* scale2 = (const float*)d_in[6];
  const float* w_gate = (const float*)d_in[7];
  const float* b_gate = (const float*)d_in[8];
  const float* w1     = (const float*)d_in[9];
  const float* b1     = (const float*)d_in[10];
  const float* w2     = (const float*)d_in[11];
  const float* b2     = (const float*)d_in[12];
  const float* wp     = (const float*)d_in[13];
  const float* bp     = (const float*)d_in[14];
  float* out = (float*)d_out;

  char* ws = (char*)d_ws;
  const size_t MB = 1024 * 1024;
  bool full8 = ws_size >= (size_t)198 * MB;   // room for 128MB bf16 w1+w2

  // Residents:
  u16*   XN1h = (u16*)  (ws + 0*MB);    // 4MB  rms1 hi  (dead after QKV gemm)
  u16*   XN1l = (u16*)  (ws + 4*MB);    // 4MB  rms1 lo
  u16*   XG   = (u16*)  (ws + 0*MB);    // 8MB  (overlay XN1h/l; written at gather)
  float* X1   = (float*)(ws + 8*MB);    // 8MB  alive till combine
  float* XN2F = (float*)(ws + 16*MB);   // 8MB  dead after gating
  u16*   XN2B = (u16*)  (ws + 32*MB);   // 4MB
  u16*   HB   = (u16*)  (ws + 36*MB);   // 32MB [36,68)
  float* PPART= (float*)(ws + 68*MB);   // 64MB [68,132) wp partials (after MLP)
  u16*   WT1  = (u16*)  (ws + 68*MB);   // w1 bf16: 64MB full8 / 32MB halves
  u16*   WT2  = (u16*)  (ws + (full8 ? 132 : 100)*MB);  // w2 bf16
  // Attention-phase overlays (dead before MoE):
  float* QKV  = (float*)(ws + 36*MB);   // 24MB (inside HB)
  float* Qf   = (float*)(ws + 60*MB);   // 8MB  (inside HB)
  float* Vf   = (float*)(ws + 68*MB);   // 8MB
  u16*   Khg  = (u16*)  (ws + 76*MB);   // 4MB
  u16*   Klg  = (u16*)  (ws + 80*MB);   // 4MB
  u16*   Vth  = (u16*)  (ws + 84*MB);   // 4MB
  u16*   Vtl  = (u16*)  (ws + 88*MB);   // 4MB
  u16*   Obh  = (u16*)  (ws + 92*MB);   // 4MB attn out hi
  u16*   Obl  = (u16*)  (ws + 96*MB);   // 4MB attn out lo
  u16*   Wqh  = (u16*)  (ws + 100*MB);  // 6MB
  u16*   Wql  = (u16*)  (ws + 106*MB);  // 6MB
  u16*   Woh  = (u16*)  (ws + 112*MB);  // 2MB
  u16*   Wol  = (u16*)  (ws + 114*MB);  // 2MB
  char*  GT   = ws + (full8 ? 196 : 132)*MB;
  int*   top_idx = (int*)  (GT);
  float* gate_w  = (float*)(GT + 16*1024);
  int*   slot_of = (int*)  (GT + 32*1024);
  int*   counts  = (int*)  (GT + 48*1024);
  int*   offs    = (int*)  (GT + 48*1024 + 64);
  int*   cursor  = (int*)  (GT + 48*1024 + 128);
  float* trig    = (float*)(GT + 64*1024);

  const size_t KN = (size_t)1024 * 4096;

  hipMemsetAsync(counts, 0, 32, stream);
  tb_trig<<<1024, 32, 0, stream>>>(trig);
  tb_wsplit<1><<<dim3(48,16,1), 256, 0, stream>>>(w_qkv, Wqh, Wql, 1024, 3072);
  tb_wsplit<1><<<dim3(16,16,1), 256, 0, stream>>>(w_out, Woh, Wol, 1024, 1024);
  tb_rms_hl<<<2048, 256, 0, stream>>>(x, scale1, XN1h, XN1l);
  tb_gemm_sp2<0><<<dim3(24,16), 256, 0, stream>>>(XN1h, XN1l, Wqh, Wql, b_qkv, nullptr, QKV, 2048, 3072, 1024);
  tb_rope2<<<2048, 256, 0, stream>>>(QKV, trig, Qf, Khg, Klg, Vf);
  tb_vt<<<dim3(16,32), 256, 0, stream>>>(Vf, Vth, Vtl);
  tb_attn_mfma<<<dim3(16,32), 256, 0, stream>>>(Qf, Khg, Klg, Vth, Vtl, Obh, Obl);
  tb_gemm_sp2<1><<<dim3(8,16), 256, 0, stream>>>(Obh, Obl, Woh, Wol, b_out, x, X1, 2048, 1024, 1024);
  tb_rms<<<2048, 256, 0, stream>>>(X1, scale2, XN2F, XN2B);
  tb_gating<<<2048, 64, 0, stream>>>(XN2F, w_gate, b_gate, top_idx, gate_w, counts);
  tb_scan<<<1, 64, 0, stream>>>(counts, offs, cursor, out + (size_t)NTOK*DMODEL);
  tb_gather<<<2048, 128, 0, stream>>>(XN2B, top_idx, cursor, slot_of, XG);
  // MoE MLP: pre-convert w1/w2 to [n][k] bf16, then 256x128-tile fused GEMM.
  if (full8) {
    tb_wsplit<0><<<dim3(64,16,8), 256, 0, stream>>>(w1, WT1, nullptr, 1024, 4096);
    tb_wsplit<0><<<dim3(64,16,8), 256, 0, stream>>>(w2, WT2, nullptr, 1024, 4096);
    tb_moe_mlp2<<<dim3(32,16,8), 512, 0, stream>>>(XG, WT1, WT2, b1, b2, HB, counts, offs, 0);
  } else {
    tb_wsplit<0><<<dim3(64,16,4), 256, 0, stream>>>(w1, WT1, nullptr, 1024, 4096);
    tb_wsplit<0><<<dim3(64,16,4), 256, 0, stream>>>(w2, WT2, nullptr, 1024, 4096);
    tb_moe_mlp2<<<dim3(32,16,4), 512, 0, stream>>>(XG, WT1, WT2, b1, b2, HB, counts, offs, 0);
    tb_wsplit<0><<<dim3(64,16,4), 256, 0, stream>>>(w1 + 4*KN, WT1, nullptr, 1024, 4096);
    tb_wsplit<0><<<dim3(64,16,4), 256, 0, stream>>>(w2 + 4*KN, WT2, nullptr, 1024, 4096);
    tb_moe_mlp2<<<dim3(32,16,4), 512, 0, stream>>>(XG, WT1, WT2, b1, b2, HB, counts, offs, 4);
  }
  // Down-projection: split-K=4 partials (f32 weights read directly).
  tb_moe_wp<<<dim3(8,16,32), 256, 0, stream>>>(HB, wp, PPART, counts, offs);
  tb_combine<<<2048, 256, 0, stream>>>(X1, PPART, slot_of, top_idx, gate_w, bp, out);
}

// Round 11
// 616.602 us; speedup vs baseline: 1.0589x; 1.0589x over previous
//
#include <hip/hip_runtime.h>
#include <math.h>

typedef unsigned short u16;
typedef unsigned int   u32;
typedef float f32x4 __attribute__((ext_vector_type(4)));
typedef __bf16 bf16x8 __attribute__((ext_vector_type(8)));

#define T_LEN  1024
#define DMODEL 1024
#define NTOK   2048
#define NHEAD  16
#define HDIM   64
#define NEXP   8
#define FFDIM  4096

#define VMW(n)   asm volatile("s_waitcnt vmcnt(" #n ")" ::: "memory")
#define SBAR()   __builtin_amdgcn_s_barrier()
#define SCHED0() __builtin_amdgcn_sched_barrier(0)
#define PRIO(n)  __builtin_amdgcn_s_setprio(n)

__device__ __forceinline__ u16 f2bf(float f) {          // RNE
  union { float f; u32 u; } v; v.f = f;
  u32 r = v.u + 0x7FFFu + ((v.u >> 16) & 1u);
  return (u16)(r >> 16);
}
__device__ __forceinline__ float bf2f(u16 h) {
  union { u32 u; float f; } v; v.u = ((u32)h) << 16; return v.f;
}

// async 16B global->LDS (wave-uniform LDS base; HW adds lane*16)
__device__ __forceinline__ void g2l16(const u16* src, u16* ldsbase) {
  __builtin_amdgcn_global_load_lds(
      (const __attribute__((address_space(1))) void*)src,
      (__attribute__((address_space(3))) void*)ldsbase, 16, 0, 0);
}

// split 16 f32 -> 8 packed u32 hi + 8 packed u32 lo
__device__ __forceinline__ void split16(const float* src, u32* H, u32* L) {
  #pragma unroll
  for (int j = 0; j < 8; ++j) {
    float a = src[2*j], b = src[2*j+1];
    u16 ha = f2bf(a), hb = f2bf(b);
    u16 la = f2bf(a - bf2f(ha)), lb = f2bf(b - bf2f(hb));
    H[j] = (u32)ha | ((u32)hb << 16);
    L[j] = (u32)la | ((u32)lb << 16);
  }
}

// ---------------- RMSNorm -> hi/lo bf16 split (for GEMM A-operand) ---------
__global__ __launch_bounds__(256) void tb_rms_hl(const float* __restrict__ x,
    const float* __restrict__ scale, u16* __restrict__ oh, u16* __restrict__ ol) {
  int t = blockIdx.x, tid = threadIdx.x;
  const float* xr = x + (size_t)t * DMODEL;
  float4 v = *(const float4*)(xr + tid * 4);
  double ss = (double)v.x*v.x + (double)v.y*v.y + (double)v.z*v.z + (double)v.w*v.w;
  #pragma unroll
  for (int off = 32; off; off >>= 1) ss += __shfl_xor(ss, off);
  __shared__ double red[4];
  if ((tid & 63) == 0) red[tid >> 6] = ss;
  __syncthreads();
  double denom = sqrt((red[0]+red[1]+red[2]+red[3]) / (double)DMODEL) + 1e-5;
  float4 sc = *(const float4*)(scale + tid * 4);
  float y[4];
  y[0] = (float)((double)v.x / denom * (double)sc.x);
  y[1] = (float)((double)v.y / denom * (double)sc.y);
  y[2] = (float)((double)v.z / denom * (double)sc.z);
  y[3] = (float)((double)v.w / denom * (double)sc.w);
  u16* ph = oh + (size_t)t*DMODEL + tid*4;
  u16* pl = ol + (size_t)t*DMODEL + tid*4;
  #pragma unroll
  for (int j = 0; j < 4; ++j) {
    u16 h = f2bf(y[j]);
    ph[j] = h;
    pl[j] = f2bf(y[j] - bf2f(h));
  }
}

// ---------------- RMSNorm (f64 accumulate; f32 + bf16 outputs) -------------
__global__ __launch_bounds__(256) void tb_rms(const float* __restrict__ x,
    const float* __restrict__ scale, float* __restrict__ out_f, u16* __restrict__ out_b) {
  int t = blockIdx.x, tid = threadIdx.x;
  const float* xr = x + (size_t)t * DMODEL;
  float4 v = *(const float4*)(xr + tid * 4);
  double ss = (double)v.x*v.x + (double)v.y*v.y + (double)v.z*v.z + (double)v.w*v.w;
  #pragma unroll
  for (int off = 32; off; off >>= 1) ss += __shfl_xor(ss, off);
  __shared__ double red[4];
  if ((tid & 63) == 0) red[tid >> 6] = ss;
  __syncthreads();
  double denom = sqrt((red[0]+red[1]+red[2]+red[3]) / (double)DMODEL) + 1e-5;
  float4 sc = *(const float4*)(scale + tid * 4);
  float y0 = (float)((double)v.x / denom * (double)sc.x);
  float y1 = (float)((double)v.y / denom * (double)sc.y);
  float y2 = (float)((double)v.z / denom * (double)sc.z);
  float y3 = (float)((double)v.w / denom * (double)sc.w);
  *(float4*)(out_f + (size_t)t*DMODEL + tid*4) = make_float4(y0,y1,y2,y3);
  u16* ob = out_b + (size_t)t*DMODEL + tid*4;
  ob[0]=f2bf(y0); ob[1]=f2bf(y1); ob[2]=f2bf(y2); ob[3]=f2bf(y3);
}

// ------- weight pre-split+transpose: W[k][n] f32 -> Wt[n][k] bf16 (hi[,lo]) -
template<int HILO>
__global__ __launch_bounds__(256) void tb_wsplit(const float* __restrict__ W,
    u16* __restrict__ Wh, u16* __restrict__ Wl, int K, int N) {
  __shared__ float Tf[64*68];
  size_t eo = (size_t)blockIdx.z * (size_t)K * N;
  const float* Wb = W + eo;
  int n0 = blockIdx.x*64, k0 = blockIdx.y*64;
  int tid = threadIdx.x;
  int r = tid >> 2, c = tid & 3;
  const float* wp = Wb + (size_t)(k0+r)*N + n0 + c*16;
  float vv[16];
  *(float4*)&vv[0]  = ((const float4*)wp)[0];
  *(float4*)&vv[4]  = ((const float4*)wp)[1];
  *(float4*)&vv[8]  = ((const float4*)wp)[2];
  *(float4*)&vv[12] = ((const float4*)wp)[3];
  #pragma unroll
  for (int j = 0; j < 16; ++j) Tf[(c*16+j)*68 + r] = vv[j];
  __syncthreads();
  int n = tid >> 2, kc = tid & 3;
  float tv[16];
  #pragma unroll
  for (int j = 0; j < 16; ++j) tv[j] = Tf[n*68 + kc*16 + j];
  u32 H[8], L[8];
  split16(tv, H, L);
  u16* oh = Wh + eo + (size_t)(n0+n)*K + k0 + kc*16;
  *(uint4*)oh       = make_uint4(H[0],H[1],H[2],H[3]);
  *(uint4*)(oh + 8) = make_uint4(H[4],H[5],H[6],H[7]);
  if (HILO) {
    u16* ol = Wl + eo + (size_t)(n0+n)*K + k0 + kc*16;
    *(uint4*)ol       = make_uint4(L[0],L[1],L[2],L[3]);
    *(uint4*)(ol + 8) = make_uint4(L[4],L[5],L[6],L[7]);
  }
}

// --- split-bf16 MFMA GEMM, all operands via global_load_lds ----------------
// Depth-2 counted-vmcnt dbuf (64KB LDS -> 2 blocks/CU co-residency).
template<int RESID>
__global__ __launch_bounds__(256) void tb_gemm_sp2(const u16* __restrict__ Ahg,
    const u16* __restrict__ Alg, const u16* __restrict__ Bhg,
    const u16* __restrict__ Blg, const float* __restrict__ bias,
    const float* __restrict__ resid, float* __restrict__ C,
    int M, int N, int K) {
  __shared__ __align__(16) u16 Ah[2][128*32], Al[2][128*32];
  __shared__ __align__(16) u16 Bh[2][128*32], Bl[2][128*32];   // 64KB total
  int tid = threadIdx.x;
  int row0 = blockIdx.y * 128, col0 = blockIdx.x * 128;
  int lane = tid & 63, wave = tid >> 6;
  int wm = wave >> 1, wn = wave & 1;
  int l15 = lane & 15, l4 = lane >> 4;
  int sw = (l15 >> 1) & 3;
  int ci0 = ((wave*2+0)<<6)+lane, ci1 = ((wave*2+1)<<6)+lane;
  int r0 = ci0 >> 2, c0 = ((ci0 & 3) ^ ((r0 >> 1) & 3)) << 3;
  int r1 = ci1 >> 2, c1 = ((ci1 & 3) ^ ((r1 >> 1) & 3)) << 3;
  int lo0 = (wave*2+0) << 9, lo1 = (wave*2+1) << 9;
  f32x4 zero = {0.f,0.f,0.f,0.f};
  f32x4 acc[4][4];
  #pragma unroll
  for (int i=0;i<4;++i) for (int j=0;j<4;++j) acc[i][j] = zero;
  const int nt = K / 32;

  #define SP2_STAGE(b, k0) do { \
    g2l16(Ahg + (size_t)(row0+r0)*K + (k0) + c0, &Ah[b][lo0]); \
    g2l16(Ahg + (size_t)(row0+r1)*K + (k0) + c1, &Ah[b][lo1]); \
    g2l16(Alg + (size_t)(row0+r0)*K + (k0) + c0, &Al[b][lo0]); \
    g2l16(Alg + (size_t)(row0+r1)*K + (k0) + c1, &Al[b][lo1]); \
    g2l16(Bhg + (size_t)(col0+r0)*K + (k0) + c0, &Bh[b][lo0]); \
    g2l16(Bhg + (size_t)(col0+r1)*K + (k0) + c1, &Bh[b][lo1]); \
    g2l16(Blg + (size_t)(col0+r0)*K + (k0) + c0, &Bl[b][lo0]); \
    g2l16(Blg + (size_t)(col0+r1)*K + (k0) + c1, &Bl[b][lo1]); } while(0)

  SP2_STAGE(0, 0);
  SP2_STAGE(1, 32);
  for (int t = 0; t < nt; ++t) {
    int cur = t & 1;
    if (t + 1 < nt) { VMW(8); } else { VMW(0); }
    SBAR(); SCHED0();
    bf16x8 ah[4], al_[4], bh_[4], bl_[4];
    #pragma unroll
    for (int mi = 0; mi < 4; ++mi) {
      int ro = (wm*64 + mi*16 + l15) << 5;
      ah[mi]  = *(const bf16x8*)(&Ah[cur][ro + ((l4 ^ sw) << 3)]);
      al_[mi] = *(const bf16x8*)(&Al[cur][ro + ((l4 ^ sw) << 3)]);
    }
    #pragma unroll
    for (int ni = 0; ni < 4; ++ni) {
      int ro = (wn*64 + ni*16 + l15) << 5;
      bh_[ni] = *(const bf16x8*)(&Bh[cur][ro + ((l4 ^ sw) << 3)]);
      bl_[ni] = *(const bf16x8*)(&Bl[cur][ro + ((l4 ^ sw) << 3)]);
    }
    PRIO(1);
    #pragma unroll
    for (int mi = 0; mi < 4; ++mi)
      #pragma unroll
      for (int ni = 0; ni < 4; ++ni) {
        acc[mi][ni] = __builtin_amdgcn_mfma_f32_16x16x32_bf16(ah[mi], bh_[ni], acc[mi][ni], 0,0,0);
        acc[mi][ni] = __builtin_amdgcn_mfma_f32_16x16x32_bf16(ah[mi], bl_[ni], acc[mi][ni], 0,0,0);
        acc[mi][ni] = __builtin_amdgcn_mfma_f32_16x16x32_bf16(al_[mi], bh_[ni], acc[mi][ni], 0,0,0);
      }
    PRIO(0);
    if (t + 1 < nt) {
      SBAR();
      if (t + 2 < nt) SP2_STAGE(cur, (t+2)*32);
    }
  }
  #undef SP2_STAGE
  #pragma unroll
  for (int mi = 0; mi < 4; ++mi)
    #pragma unroll
    for (int r = 0; r < 4; ++r) {
      int row = row0 + wm*64 + mi*16 + l4*4 + r;
      #pragma unroll
      for (int ni = 0; ni < 4; ++ni) {
        int col = col0 + wn*64 + ni*16 + l15;
        float vv = acc[mi][ni][r] + bias[col];
        if (RESID) vv += resid[(size_t)row*N + col];
        C[(size_t)row*N + col] = vv;
      }
    }
}

// ---------------- RoPE trig table (f64) ------------------------------------
__global__ void tb_trig(float* __restrict__ tab) {
  int t = blockIdx.x, d = threadIdx.x;
  double theta = pow(10000.0, -(double)d / 32.0);
  double ang = (double)t * theta;
  tab[(t*32 + d)*2 + 0] = (float)cos(ang);
  tab[(t*32 + d)*2 + 1] = (float)sin(ang);
}

// ---------------- qkv -> Q f32, K bf16 hi/lo (all [bh][t][d]), V f32 -------
__global__ __launch_bounds__(256) void tb_rope2(const float* __restrict__ qkv,
    const float* __restrict__ tab, float* __restrict__ Qf, u16* __restrict__ Khg,
    u16* __restrict__ Klg, float* __restrict__ Vf) {
  int n = blockIdx.x;
  int b = n >> 10, t = n & 1023;
  const float* src = qkv + (size_t)n * 3072;
  for (int idx = threadIdx.x; idx < 512; idx += 256) {
    int h = idx >> 5, d = idx & 31;
    float ca = tab[(t*32+d)*2], sa = tab[(t*32+d)*2+1];
    size_t base = ((size_t)(b*NHEAD + h) * T_LEN + t) * HDIM;
    { float x1 = src[h*64 + d], x2 = src[h*64 + d + 32];
      Qf[base + d]      = x1*ca - x2*sa;
      Qf[base + d + 32] = x1*sa + x2*ca; }
    { float x1 = src[1024 + h*64 + d], x2 = src[1024 + h*64 + d + 32];
      float k1 = x1*ca - x2*sa, k2 = x1*sa + x2*ca;
      u16 h1 = f2bf(k1), h2 = f2bf(k2);
      Khg[base + d] = h1;      Khg[base + d + 32] = h2;
      Klg[base + d] = f2bf(k1 - bf2f(h1));
      Klg[base + d + 32] = f2bf(k2 - bf2f(h2)); }
  }
  for (int c = threadIdx.x; c < 1024; c += 256) {
    int h = c >> 6, d = c & 63;
    Vf[((size_t)(b*NHEAD + h) * T_LEN + t) * HDIM + d] = src[2048 + c];
  }
}

// ---------------- V transpose+split: [bh][t][d] f32 -> [bh][d][t] bf16 -----
__global__ __launch_bounds__(256) void tb_vt(const float* __restrict__ Vf,
    u16* __restrict__ Vh, u16* __restrict__ Vl) {
  __shared__ float Tf[64*68];
  int t0 = blockIdx.x * 64, bh = blockIdx.y;
  const float* Vb = Vf + (size_t)bh * (T_LEN*HDIM);
  int tid = threadIdx.x, r = tid >> 2, c = tid & 3;
  const float* vp = Vb + (size_t)(t0+r)*HDIM + c*16;
  float vv[16];
  *(float4*)&vv[0]  = ((const float4*)vp)[0];
  *(float4*)&vv[4]  = ((const float4*)vp)[1];
  *(float4*)&vv[8]  = ((const float4*)vp)[2];
  *(float4*)&vv[12] = ((const float4*)vp)[3];
  #pragma unroll
  for (int j = 0; j < 16; ++j) Tf[(c*16+j)*68 + r] = vv[j];
  __syncthreads();
  int d = tid >> 2, tc = tid & 3;
  float tv[16];
  #pragma unroll
  for (int j = 0; j < 16; ++j) tv[j] = Tf[d*68 + tc*16 + j];
  u32 H[8], L[8];
  split16(tv, H, L);
  u16* oh = Vh + (size_t)bh*(HDIM*T_LEN) + (size_t)d*T_LEN + t0 + tc*16;
  u16* ol = Vl + (size_t)bh*(HDIM*T_LEN) + (size_t)d*T_LEN + t0 + tc*16;
  *(uint4*)oh       = make_uint4(H[0],H[1],H[2],H[3]);
  *(uint4*)(oh + 8) = make_uint4(H[4],H[5],H[6],H[7]);
  *(uint4*)ol       = make_uint4(L[0],L[1],L[2],L[3]);
  *(uint4*)(ol + 8) = make_uint4(L[4],L[5],L[6],L[7]);
}

// ---------------- MFMA flash attention; writes O as hi/lo bf16 split -------
__global__ __launch_bounds__(256) void tb_attn_mfma(const float* __restrict__ Qf,
    const u16* __restrict__ Khg, const u16* __restrict__ Klg,
    const u16* __restrict__ Vhg, const u16* __restrict__ Vlg,
    u16* __restrict__ Obh, u16* __restrict__ Obl) {
  __shared__ __align__(16) u16 Kh[64*72], Kl[64*72];
  __shared__ __align__(16) u16 Vh[64*72], Vl[64*72];
  __shared__ __align__(16) u16 Ph[64*72], Pl[64*72];
  int qt = blockIdx.x, bh = blockIdx.y;
  int tid = threadIdx.x, lane = tid & 63, w = tid >> 6;
  int l15 = lane & 15, l4 = lane >> 4;
  int b = bh >> 4, h = bh & 15;
  const float* Qb = Qf + (size_t)bh * (T_LEN*HDIM);
  const u16* Khb = Khg + (size_t)bh * (T_LEN*HDIM);
  const u16* Klb = Klg + (size_t)bh * (T_LEN*HDIM);
  const u16* Vhb = Vhg + (size_t)bh * (HDIM*T_LEN);
  const u16* Vlb = Vlg + (size_t)bh * (HDIM*T_LEN);
  int q0 = qt * 64;
  int qrow = q0 + w*16 + l15;
  bf16x8 qh[2], ql[2];
  #pragma unroll
  for (int ks = 0; ks < 2; ++ks) {
    const float* qp = Qb + (size_t)qrow*HDIM + ks*32 + l4*8;
    float vv[8];
    *(float4*)&vv[0] = ((const float4*)qp)[0];
    *(float4*)&vv[4] = ((const float4*)qp)[1];
    u32 H[4], L[4];
    #pragma unroll
    for (int j = 0; j < 4; ++j) {
      float a = vv[2*j], bb = vv[2*j+1];
      u16 ha = f2bf(a), hb = f2bf(bb);
      u16 la = f2bf(a - bf2f(ha)), lb = f2bf(bb - bf2f(hb));
      H[j] = (u32)ha | ((u32)hb << 16);
      L[j] = (u32)la | ((u32)lb << 16);
    }
    union { uint4 u; bf16x8 b; } th, tl;
    th.u = make_uint4(H[0],H[1],H[2],H[3]);
    tl.u = make_uint4(L[0],L[1],L[2],L[3]);
    qh[ks] = th.b; ql[ks] = tl.b;
  }
  int qg[4];
  #pragma unroll
  for (int r = 0; r < 4; ++r) qg[r] = q0 + w*16 + l4*4 + r;
  float mrow[4], lrow[4];
  f32x4 oacc[4];
  f32x4 zero = {0.f,0.f,0.f,0.f};
  #pragma unroll
  for (int r = 0; r < 4; ++r) { mrow[r] = -1e30f; lrow[r] = 0.f; }
  #pragma unroll
  for (int d = 0; d < 4; ++d) oacc[d] = zero;

  int sr = tid >> 2, sc = tid & 3;
  for (int kt = 0; kt <= qt; ++kt) {
    int k0 = kt * 64;
    __syncthreads();
    {
      const u16* kp = Khb + (size_t)(k0+sr)*HDIM + sc*16;
      *(uint4*)(Kh + sr*72 + sc*16)     = ((const uint4*)kp)[0];
      *(uint4*)(Kh + sr*72 + sc*16 + 8) = ((const uint4*)kp)[1];
      const u16* kl2 = Klb + (size_t)(k0+sr)*HDIM + sc*16;
      *(uint4*)(Kl + sr*72 + sc*16)     = ((const uint4*)kl2)[0];
      *(uint4*)(Kl + sr*72 + sc*16 + 8) = ((const uint4*)kl2)[1];
      const u16* vp = Vhb + (size_t)sr*T_LEN + k0 + sc*16;
      *(uint4*)(Vh + sr*72 + sc*16)     = ((const uint4*)vp)[0];
      *(uint4*)(Vh + sr*72 + sc*16 + 8) = ((const uint4*)vp)[1];
      const u16* vl2 = Vlb + (size_t)sr*T_LEN + k0 + sc*16;
      *(uint4*)(Vl + sr*72 + sc*16)     = ((const uint4*)vl2)[0];
      *(uint4*)(Vl + sr*72 + sc*16 + 8) = ((const uint4*)vl2)[1];
    }
    __syncthreads();
    f32x4 sacc[4];
    #pragma unroll
    for (int ni = 0; ni < 4; ++ni) {
      sacc[ni] = zero;
      #pragma unroll
      for (int ks = 0; ks < 2; ++ks) {
        bf16x8 kh_ = *(const bf16x8*)(Kh + (ni*16 + l15)*72 + ks*32 + l4*8);
        bf16x8 kl_ = *(const bf16x8*)(Kl + (ni*16 + l15)*72 + ks*32 + l4*8);
        sacc[ni] = __builtin_amdgcn_mfma_f32_16x16x32_bf16(qh[ks], kh_, sacc[ni], 0,0,0);
        sacc[ni] = __builtin_amdgcn_mfma_f32_16x16x32_bf16(qh[ks], kl_, sacc[ni], 0,0,0);
        sacc[ni] = __builtin_amdgcn_mfma_f32_16x16x32_bf16(ql[ks], kh_, sacc[ni], 0,0,0);
      }
    }
    bool diag = (kt == qt);
    float sv[4][4];
    #pragma unroll
    for (int ni = 0; ni < 4; ++ni)
      #pragma unroll
      for (int r = 0; r < 4; ++r) {
        float s = sacc[ni][r] * 0.125f;
        if (diag && (k0 + ni*16 + l15 > qg[r])) s = -1e30f;
        sv[ni][r] = s;
      }
    float mt[4];
    #pragma unroll
    for (int r = 0; r < 4; ++r)
      mt[r] = fmaxf(fmaxf(sv[0][r], sv[1][r]), fmaxf(sv[2][r], sv[3][r]));
    #pragma unroll
    for (int off = 1; off < 16; off <<= 1)
      #pragma unroll
      for (int r = 0; r < 4; ++r) mt[r] = fmaxf(mt[r], __shfl_xor(mt[r], off));
    float al[4];
    #pragma unroll
    for (int r = 0; r < 4; ++r) {
      float mn = fmaxf(mrow[r], mt[r]);
      al[r] = expf(mrow[r] - mn);
      mrow[r] = mn;
    }
    float ls[4] = {0.f,0.f,0.f,0.f};
    #pragma unroll
    for (int ni = 0; ni < 4; ++ni)
      #pragma unroll
      for (int r = 0; r < 4; ++r) {
        float p = expf(sv[ni][r] - mrow[r]);
        u16 ph2 = f2bf(p);
        int qrl = w*16 + l4*4 + r;
        Ph[qrl*72 + ni*16 + l15] = ph2;
        Pl[qrl*72 + ni*16 + l15] = f2bf(p - bf2f(ph2));
        ls[r] += p;
      }
    #pragma unroll
    for (int off = 1; off < 16; off <<= 1)
      #pragma unroll
      for (int r = 0; r < 4; ++r) ls[r] += __shfl_xor(ls[r], off);
    #pragma unroll
    for (int r = 0; r < 4; ++r) lrow[r] = lrow[r]*al[r] + ls[r];
    #pragma unroll
    for (int d = 0; d < 4; ++d)
      #pragma unroll
      for (int r = 0; r < 4; ++r) oacc[d][r] *= al[r];
    bf16x8 ph_[2], pl_[2];
    #pragma unroll
    for (int ks = 0; ks < 2; ++ks) {
      ph_[ks] = *(const bf16x8*)(Ph + (w*16 + l15)*72 + ks*32 + l4*8);
      pl_[ks] = *(const bf16x8*)(Pl + (w*16 + l15)*72 + ks*32 + l4*8);
    }
    #pragma unroll
    for (int dblk = 0; dblk < 4; ++dblk)
      #pragma unroll
      for (int ks = 0; ks < 2; ++ks) {
        bf16x8 vh_ = *(const bf16x8*)(Vh + (dblk*16 + l15)*72 + ks*32 + l4*8);
        bf16x8 vl_ = *(const bf16x8*)(Vl + (dblk*16 + l15)*72 + ks*32 + l4*8);
        oacc[dblk] = __builtin_amdgcn_mfma_f32_16x16x32_bf16(ph_[ks], vh_, oacc[dblk], 0,0,0);
        oacc[dblk] = __builtin_amdgcn_mfma_f32_16x16x32_bf16(ph_[ks], vl_, oacc[dblk], 0,0,0);
        oacc[dblk] = __builtin_amdgcn_mfma_f32_16x16x32_bf16(pl_[ks], vh_, oacc[dblk], 0,0,0);
      }
  }
  #pragma unroll
  for (int dblk = 0; dblk < 4; ++dblk)
    #pragma unroll
    for (int r = 0; r < 4; ++r) {
      int q = qg[r];
      int d = dblk*16 + l15;
      float ov = oacc[dblk][r] / lrow[r];
      u16 hh = f2bf(ov);
      size_t oi = ((size_t)b * T_LEN + q) * DMODEL + h * HDIM + d;
      Obh[oi] = hh;
      Obl[oi] = f2bf(ov - bf2f(hh));
    }
}

// ---------------- router: f64 logits, top-2 --------------------------------
__global__ __launch_bounds__(64) void tb_gating(const float* __restrict__ xn2,
    const float* __restrict__ wg, const float* __restrict__ bg,
    int* __restrict__ top_idx, float* __restrict__ gate_w, int* __restrict__ counts) {
  int t = blockIdx.x, lane = threadIdx.x;
  const float* xr = xn2 + (size_t)t * DMODEL;
  double part[8];
  #pragma unroll
  for (int e = 0; e < 8; ++e) part[e] = 0.0;
  for (int i = lane; i < DMODEL; i += 64) {
    double xv = (double)xr[i];
    const float* wr = wg + (size_t)i * 8;
    #pragma unroll
    for (int e = 0; e < 8; ++e) part[e] += xv * (double)wr[e];
  }
  #pragma unroll
  for (int e = 0; e < 8; ++e)
    for (int off = 32; off; off >>= 1) part[e] += __shfl_xor(part[e], off);
  if (lane == 0) {
    double lg[8];
    for (int e = 0; e < 8; ++e) lg[e] = part[e] + (double)bg[e];
    int i1 = 0;
    for (int e = 1; e < 8; ++e) if (lg[e] > lg[i1]) i1 = e;
    int i2 = (i1 == 0) ? 1 : 0;
    for (int e = 0; e < 8; ++e) if (e != i1 && lg[e] > lg[i2]) i2 = e;
    double e2 = exp(lg[i2] - lg[i1]);
    double den = 1.0 + e2;
    top_idx[t*2] = i1; top_idx[t*2+1] = i2;
    gate_w[t*2] = (float)(1.0/den); gate_w[t*2+1] = (float)(e2/den);
    atomicAdd(&counts[i1], 1); atomicAdd(&counts[i2], 1);
  }
}

__global__ void tb_scan(const int* __restrict__ counts, int* __restrict__ offs,
    int* __restrict__ cursor, float* __restrict__ aux_out) {
  if (threadIdx.x == 0) {
    int off = 0; float aux = 0.f;
    for (int e = 0; e < 8; ++e) {
      offs[e] = off; cursor[e] = off; off += counts[e];
      float fr = (float)counts[e] / 4096.0f - 0.125f;
      aux += fr * fr;
    }
    aux_out[0] = aux;
  }
}

__global__ __launch_bounds__(128) void tb_gather(const u16* __restrict__ xn2b,
    const int* __restrict__ top_idx, int* __restrict__ cursor,
    int* __restrict__ slot_of, u16* __restrict__ Xg) {
  int t = blockIdx.x;
  __shared__ int sl[2];
  if (threadIdx.x < 2) {
    int e = top_idx[t*2 + threadIdx.x];
    int s = atomicAdd(&cursor[e], 1);
    sl[threadIdx.x] = s;
    slot_of[t*2 + threadIdx.x] = s;
  }
  __syncthreads();
  uint4 v = *(const uint4*)(xn2b + (size_t)t * DMODEL + threadIdx.x * 8);
  *(uint4*)(Xg + (size_t)sl[0] * DMODEL + threadIdx.x * 8) = v;
  *(uint4*)(Xg + (size_t)sl[1] * DMODEL + threadIdx.x * 8) = v;
}

// --- fused MoE MLP: 256m x 128n tile, 8 waves, bf16 weights ----------------
// Depth-2 counted-vmcnt dbuf, 64KB LDS (2 blocks/CU), setprio on MFMA.
__global__ __launch_bounds__(512, 1) void tb_moe_mlp2(const u16* __restrict__ Ag,
    const u16* __restrict__ B1t, const u16* __restrict__ B2t,
    const float* __restrict__ b1g, const float* __restrict__ b2g,
    u16* __restrict__ Hout, const int* __restrict__ counts,
    const int* __restrict__ offs, int ebase) {
  const int K = DMODEL, N = FFDIM;
  int ez = blockIdx.z, e = ebase + ez;
  int cnt = counts[e];
  if ((int)blockIdx.y * 256 >= cnt) return;
  int row0 = offs[e] + blockIdx.y * 256;
  int rend = offs[e] + cnt;
  int col0 = blockIdx.x * 128;
  const u16* B1 = B1t + (size_t)ez * K * N;
  const u16* B2 = B2t + (size_t)ez * K * N;
  const float* bb1 = b1g + (size_t)e * N;
  const float* bb2 = b2g + (size_t)e * N;
  __shared__ __align__(16) u16 As[2][256*32];    // 32KB
  __shared__ __align__(16) u16 Bs1[2][128*32];   // 16KB
  __shared__ __align__(16) u16 Bs2[2][128*32];   // 16KB
  int tid = threadIdx.x, lane = tid & 63, wave = tid >> 6;  // 8 waves
  int wm = wave >> 1, wn = wave & 1;
  int l15 = lane & 15, l4 = lane >> 4;
  int sw = (l15 >> 1) & 3;
  int ai0 = ((wave*2+0)<<6) + lane, ai1 = ((wave*2+1)<<6) + lane;
  int ar0 = ai0 >> 2, ac0 = ((ai0 & 3) ^ ((ar0 >> 1) & 3)) << 3;
  int ar1 = ai1 >> 2, ac1 = ((ai1 & 3) ^ ((ar1 >> 1) & 3)) << 3;
  int ga0 = row0 + ar0 < rend ? row0 + ar0 : rend - 1;
  int ga1 = row0 + ar1 < rend ? row0 + ar1 : rend - 1;
  int alo0 = (wave*2+0) << 9, alo1 = (wave*2+1) << 9;
  int bi = (wave << 6) + lane;
  int br = bi >> 2, bc = ((bi & 3) ^ ((br >> 1) & 3)) << 3;
  int blo = wave << 9;
  f32x4 zero = {0.f,0.f,0.f,0.f};
  f32x4 acc1[4][4], acc2[4][4];
  #pragma unroll
  for (int i=0;i<4;++i) for (int j=0;j<4;++j) { acc1[i][j] = zero; acc2[i][j] = zero; }

  #define MLP2_STAGE(b, k0) do { \
    g2l16(Ag + (size_t)ga0*K + (k0) + ac0,        &As[b][alo0]); \
    g2l16(Ag + (size_t)ga1*K + (k0) + ac1,        &As[b][alo1]); \
    g2l16(B1 + (size_t)(col0+br)*K + (k0) + bc,  &Bs1[b][blo]); \
    g2l16(B2 + (size_t)(col0+br)*K + (k0) + bc,  &Bs2[b][blo]); } while(0)

  MLP2_STAGE(0, 0);
  MLP2_STAGE(1, 32);
  const int nt = K / 32;
  for (int t = 0; t < nt; ++t) {
    int cur = t & 1;
    if (t + 1 < nt) { VMW(4); } else { VMW(0); }
    SBAR(); SCHED0();
    bf16x8 af[4], bf1[4], bf2[4];
    #pragma unroll
    for (int mi = 0; mi < 4; ++mi)
      af[mi] = *(const bf16x8*)(&As[cur][((wm*64 + mi*16 + l15) << 5) + ((l4 ^ sw) << 3)]);
    #pragma unroll
    for (int ni = 0; ni < 4; ++ni)
      bf1[ni] = *(const bf16x8*)(&Bs1[cur][((wn*64 + ni*16 + l15) << 5) + ((l4 ^ sw) << 3)]);
    PRIO(1);
    #pragma unroll
    for (int mi = 0; mi < 4; ++mi)
      #pragma unroll
      for (int ni = 0; ni < 4; ++ni)
        acc1[mi][ni] = __builtin_amdgcn_mfma_f32_16x16x32_bf16(af[mi], bf1[ni], acc1[mi][ni], 0,0,0);
    #pragma unroll
    for (int ni = 0; ni < 4; ++ni)
      bf2[ni] = *(const bf16x8*)(&Bs2[cur][((wn*64 + ni*16 + l15) << 5) + ((l4 ^ sw) << 3)]);
    #pragma unroll
    for (int mi = 0; mi < 4; ++mi)
      #pragma unroll
      for (int ni = 0; ni < 4; ++ni)
        acc2[mi][ni] = __builtin_amdgcn_mfma_f32_16x16x32_bf16(af[mi], bf2[ni], acc2[mi][ni], 0,0,0);
    PRIO(0);
    if (t + 1 < nt) {
      SBAR();
      if (t + 2 < nt) MLP2_STAGE(cur, (t+2)*32);
    }
  }
  #undef MLP2_STAGE
  #pragma unroll
  for (int mi = 0; mi < 4; ++mi) {
    #pragma unroll
    for (int r = 0; r < 4; ++r) {
      int row = row0 + wm*64 + mi*16 + l4*4 + r;
      if (row >= rend) continue;
      #pragma unroll
      for (int ni = 0; ni < 4; ++ni) {
        int col = col0 + wn*64 + ni*16 + l15;
        float v1 = acc1[mi][ni][r] + bb1[col];
        float v2 = acc2[mi][ni][r] + bb2[col];
        float hv = (v1 / (1.f + expf(-v1))) * v2;
        Hout[(size_t)row * N + col] = f2bf(hv);
      }
    }
  }
}

// --- MoE down-proj, split-K=4, in-kernel f32 convert; partials (no bias) ---
__global__ __launch_bounds__(256) void tb_moe_wp(const u16* __restrict__ Ag,
    const float* __restrict__ Wp, float* __restrict__ Pout,
    const int* __restrict__ counts, const int* __restrict__ offs) {
  const int K = FFDIM, N = DMODEL;
  int e = blockIdx.z & 7, ks = blockIdx.z >> 3;
  int cnt = counts[e];
  if ((int)blockIdx.y * 128 >= cnt) return;
  int row0 = offs[e] + blockIdx.y * 128;
  int rend = offs[e] + cnt;
  int col0 = blockIdx.x * 128;
  int kbase = ks * 1024;
  const float* Bw = Wp + (size_t)e * K * N;
  float* out = Pout + (size_t)ks * (4096u*1024u);
  __shared__ __align__(16) u16 As[2][128*32], Bs[2][128*32];
  int tid = threadIdx.x, lane = tid & 63, wave = tid >> 6;
  int wm = wave >> 1, wn = wave & 1;
  int l15 = lane & 15, l4 = lane >> 4;
  int sw = (l15 >> 1) & 3;
  int ci0 = ((wave*2+0)<<6) + lane, ci1 = ((wave*2+1)<<6) + lane;
  int ar0 = ci0 >> 2, ac0 = ((ci0 & 3) ^ ((ar0 >> 1) & 3)) << 3;
  int ar1 = ci1 >> 2, ac1 = ((ci1 & 3) ^ ((ar1 >> 1) & 3)) << 3;
  int ga0 = row0 + ar0 < rend ? row0 + ar0 : rend - 1;
  int ga1 = row0 + ar1 < rend ? row0 + ar1 : rend - 1;
  int lo0 = (wave*2+0) << 9, lo1 = (wave*2+1) << 9;
  int bn = tid & 127;
  int bkg = (tid >> 7) << 4;
  int bsw = (bn >> 1) & 3;
  int bc0 = bkg >> 3;
  int boff0 = bn*32 + (( bc0    ^ bsw) << 3);
  int boff1 = bn*32 + (((bc0+1) ^ bsw) << 3);
  f32x4 zero = {0.f,0.f,0.f,0.f};
  f32x4 acc[4][4];
  #pragma unroll
  for (int i=0;i<4;++i) for (int j=0;j<4;++j) acc[i][j] = zero;
  float r1[16];

  #define WP_ISSUE_A(b, k0) do { \
    g2l16(Ag + (size_t)ga0*K + kbase + (k0) + ac0, &As[b][lo0]); \
    g2l16(Ag + (size_t)ga1*K + kbase + (k0) + ac1, &As[b][lo1]); } while(0)
  #define WP_LOAD_B(k0) do { \
    const float* p1 = Bw + (size_t)(kbase+(k0)+bkg)*N + col0 + bn; \
    _Pragma("unroll") \
    for (int j = 0; j < 16; ++j) r1[j] = p1[(size_t)j*N]; } while(0)
  #define WP_WRITE_B(b) do { \
    u32 P1[8]; \
    _Pragma("unroll") \
    for (int j = 0; j < 8; ++j) \
      asm("v_cvt_pk_bf16_f32 %0, %1, %2" : "=v"(P1[j]) : "v"(r1[2*j]), "v"(r1[2*j+1])); \
    *(uint4*)(&Bs[b][boff0]) = make_uint4(P1[0],P1[1],P1[2],P1[3]); \
    *(uint4*)(&Bs[b][boff1]) = make_uint4(P1[4],P1[5],P1[6],P1[7]); } while(0)

  WP_ISSUE_A(0, 0);
  WP_LOAD_B(0);
  VMW(0);
  WP_WRITE_B(0);
  asm volatile("s_waitcnt lgkmcnt(0)" ::: "memory");
  SBAR();
  const int nt = 1024 / 32;
  for (int t = 0; t < nt; ++t) {
    int cur = t & 1;
    if (t + 1 < nt) { WP_ISSUE_A(cur^1, (t+1)*32); WP_LOAD_B((t+1)*32); }
    bf16x8 af[4], bfr[4];
    #pragma unroll
    for (int mi = 0; mi < 4; ++mi)
      af[mi] = *(const bf16x8*)(&As[cur][((wm*64 + mi*16 + l15) << 5) + ((l4 ^ sw) << 3)]);
    #pragma unroll
    for (int ni = 0; ni < 4; ++ni)
      bfr[ni] = *(const bf16x8*)(&Bs[cur][((wn*64 + ni*16 + l15) << 5) + ((l4 ^ sw) << 3)]);
    PRIO(1);
    #pragma unroll
    for (int mi = 0; mi < 4; ++mi)
      #pragma unroll
      for (int ni = 0; ni < 4; ++ni)
        acc[mi][ni] = __builtin_amdgcn_mfma_f32_16x16x32_bf16(af[mi], bfr[ni], acc[mi][ni], 0,0,0);
    PRIO(0);
    if (t + 1 < nt) {
      VMW(0);
      SBAR(); SCHED0();
      WP_WRITE_B(cur ^ 1);
      asm volatile("s_waitcnt lgkmcnt(0)" ::: "memory");
      SBAR();
    }
  }
  #undef WP_ISSUE_A
  #undef WP_LOAD_B
  #undef WP_WRITE_B
  #pragma unroll
  for (int mi = 0; mi < 4; ++mi) {
    #pragma unroll
    for (int r = 0; r < 4; ++r) {
      int row = row0 + wm*64 + mi*16 + l4*4 + r;
      if (row >= rend) continue;
      #pragma unroll
      for (int ni = 0; ni < 4; ++ni) {
        int col = col0 + wn*64 + ni*16 + l15;
        out[(size_t)row * N + col] = acc[mi][ni][r];
      }
    }
  }
}

// --- final: out = x1 + sum_s g_s*(P0..P3[slot_s] + bp[e_s]) -----------------
__global__ __launch_bounds__(256) void tb_combine(const float* __restrict__ x1,
    const float* __restrict__ P, const int* __restrict__ slot_of,
    const int* __restrict__ top_idx, const float* __restrict__ gate_w,
    const float* __restrict__ bp, float* __restrict__ out) {
  const size_t SL = (size_t)4096 * 1024;
  int t = blockIdx.x;
  int c = threadIdx.x * 4;
  float4 a = *(const float4*)(x1 + (size_t)t*DMODEL + c);
  float ox = a.x, oy = a.y, oz = a.z, ow = a.w;
  #pragma unroll
  for (int s = 0; s < 2; ++s) {
    int slot = slot_of[t*2+s], e = top_idx[t*2+s];
    float g = gate_w[t*2+s];
    float4 v = *(const float4*)(bp + (size_t)e*DMODEL + c);
    #pragma unroll
    for (int ks = 0; ks < 4; ++ks) {
      float4 p = *(const float4*)(P + ks*SL + (size_t)slot*DMODEL + c);
      v.x += p.x; v.y += p.y; v.z += p.z; v.w += p.w;
    }
    ox += g*v.x; oy += g*v.y; oz += g*v.z; ow += g*v.w;
  }
  *(float4*)(out + (size_t)t*DMODEL + c) = make_float4(ox,oy,oz,ow);
}

extern "C" void kernel_launch(void* const* d_in, const int* in_sizes, int n_in,
                              void* d_out, int out_size, void* d_ws, size_t ws_size,
                              hipStream_t stream) {
  const float* x      = (const float*)d_in[0];
  const float* w_qkv  = (const float*)d_in[1];
  const float* b_qkv  = (const float*)d_in[2];
  const float* w_out  = (const float*)d_in[3];
  const float* b_out  = (const float*)d_in[4];
  const float* scale1 = (const float*)d_in[5];
  const float* scale2 = (const float*)d_in[6];
  const float* w_gate = (const float*)d_in[7];
  const float* b_gate = (const float*)d_in[8];
  const float* w1     = (const float*)d_in[9];
  const float* b1     = (const float*)d_in[10];
  const float* w2     = (const float*)d_in[11];
  const float* b2     = (const float*)d_in[12];
  const float* wp     = (const float*)d_in[13];
  const float* bp     = (const float*)d_in[14];
  float* out = (float*)d_out;

  char* ws = (char*)d_ws;
  const size_t MB = 1024 * 1024;
  bool full8 = ws_size >= (size_t)198 * MB;   // room for 128MB bf16 w1+w2

  // Residents:
  u16*   XN1h = (u16*)  (ws + 0*MB);    // 4MB  rms1 hi  (dead after QKV gemm)
  u16*   XN1l = (u16*)  (ws + 4*MB);    // 4MB  rms1 lo
  u16*   XG   = (u16*)  (ws + 0*MB);    // 8MB  (overlay XN1h/l; written at gather)
  float* X1   = (float*)(ws + 8*MB);    // 8MB  alive till combine
  float* XN2F = (float*)(ws + 16*MB);   // 8MB  dead after gating
  u16*   XN2B = (u16*)  (ws + 32*MB);   // 4MB
  u16*   HB   = (u16*)  (ws + 36*MB);   // 32MB [36,68)
  float* PPART= (float*)(ws + 68*MB);   // 64MB [68,132) wp partials (after MLP)
  u16*   WT1  = (u16*)  (ws + 68*MB);   // w1 bf16: 64MB full8 / 32MB halves
  u16*   WT2  = (u16*)  (ws + (full8 ? 132 : 100)*MB);  // w2 bf16
  // Attention-phase overlays (dead before MoE):
  float* QKV  = (float*)(ws + 36*MB);   // 24MB (inside HB)
  float* Qf   = (float*)(ws + 60*MB);   // 8MB  (inside HB)
  float* Vf   = (float*)(ws + 68*MB);   // 8MB
  u16*   Khg  = (u16*)  (ws + 76*MB);   // 4MB
  u16*   Klg  = (u16*)  (ws + 80*MB);   // 4MB
  u16*   Vth  = (u16*)  (ws + 84*MB);   // 4MB
  u16*   Vtl  = (u16*)  (ws + 88*MB);   // 4MB
  u16*   Obh  = (u16*)  (ws + 92*MB);   // 4MB attn out hi
  u16*   Obl  = (u16*)  (ws + 96*MB);   // 4MB attn out lo
  u16*   Wqh  = (u16*)  (ws + 100*MB);  // 6MB
  u16*   Wql  = (u16*)  (ws + 106*MB);  // 6MB
  u16*   Woh  = (u16*)  (ws + 112*MB);  // 2MB
  u16*   Wol  = (u16*)  (ws + 114*MB);  // 2MB
  char*  GT   = ws + (full8 ? 196 : 132)*MB;
  int*   top_idx = (int*)  (GT);
  float* gate_w  = (float*)(GT + 16*1024);
  int*   slot_of = (int*)  (GT + 32*1024);
  int*   counts  = (int*)  (GT + 48*1024);
  int*   offs    = (int*)  (GT + 48*1024 + 64);
  int*   cursor  = (int*)  (GT + 48*1024 + 128);
  float* trig    = (float*)(GT + 64*1024);

  const size_t KN = (size_t)1024 * 4096;

  hipMemsetAsync(counts, 0, 32, stream);
  tb_trig<<<1024, 32, 0, stream>>>(trig);
  tb_wsplit<1><<<dim3(48,16,1), 256, 0, stream>>>(w_qkv, Wqh, Wql, 1024, 3072);
  tb_wsplit<1><<<dim3(16,16,1), 256, 0, stream>>>(w_out, Woh, Wol, 1024, 1024);
  tb_rms_hl<<<2048, 256, 0, stream>>>(x, scale1, XN1h, XN1l);
  tb_gemm_sp2<0><<<dim3(24,16), 256, 0, stream>>>(XN1h, XN1l, Wqh, Wql, b_qkv, nullptr, QKV, 2048, 3072, 1024);
  tb_rope2<<<2048, 256, 0, stream>>>(QKV, trig, Qf, Khg, Klg, Vf);
  tb_vt<<<dim3(16,32), 256, 0, stream>>>(Vf, Vth, Vtl);
  tb_attn_mfma<<<dim3(16,32), 256, 0, stream>>>(Qf, Khg, Klg, Vth, Vtl, Obh, Obl);
  tb_gemm_sp2<1><<<dim3(8,16), 256, 0, stream>>>(Obh, Obl, Woh, Wol, b_out, x, X1, 2048, 1024, 1024);
  tb_rms<<<2048, 256, 0, stream>>>(X1, scale2, XN2F, XN2B);
  tb_gating<<<2048, 64, 0, stream>>>(XN2F, w_gate, b_gate, top_idx, gate_w, counts);
  tb_scan<<<1, 64, 0, stream>>>(counts, offs, cursor, out + (size_t)NTOK*DMODEL);
  tb_gather<<<2048, 128, 0, stream>>>(XN2B, top_idx, cursor, slot_of, XG);
  // MoE MLP: pre-convert w1/w2 to [n][k] bf16, then 256x128-tile fused GEMM.
  if (full8) {
    tb_wsplit<0><<<dim3(64,16,8), 256, 0, stream>>>(w1, WT1, nullptr, 1024, 4096);
    tb_wsplit<0><<<dim3(64,16,8), 256, 0, stream>>>(w2, WT2, nullptr, 1024, 4096);
    tb_moe_mlp2<<<dim3(32,16,8), 512, 0, stream>>>(XG, WT1, WT2, b1, b2, HB, counts, offs, 0);
  } else {
    tb_wsplit<0><<<dim3(64,16,4), 256, 0, stream>>>(w1, WT1, nullptr, 1024, 4096);
    tb_wsplit<0><<<dim3(64,16,4), 256, 0, stream>>>(w2, WT2, nullptr, 1024, 4096);
    tb_moe_mlp2<<<dim3(32,16,4), 512, 0, stream>>>(XG, WT1, WT2, b1, b2, HB, counts, offs, 0);
    tb_wsplit<0><<<dim3(64,16,4), 256, 0, stream>>>(w1 + 4*KN, WT1, nullptr, 1024, 4096);
    tb_wsplit<0><<<dim3(64,16,4), 256, 0, stream>>>(w2 + 4*KN, WT2, nullptr, 1024, 4096);
    tb_moe_mlp2<<<dim3(32,16,4), 512, 0, stream>>>(XG, WT1, WT2, b1, b2, HB, counts, offs, 4);
  }
  // Down-projection: split-K=4 partials (f32 weights read directly).
  tb_moe_wp<<<dim3(8,16,32), 256, 0, stream>>>(HB, wp, PPART, counts, offs);
  tb_combine<<<2048, 256, 0, stream>>>(X1, PPART, slot_of, top_idx, gate_w, bp, out);
}

// Round 12
// 599.002 us; speedup vs baseline: 1.0900x; 1.0294x over previous
//
#include <hip/hip_runtime.h>
#include <math.h>

typedef unsigned short u16;
typedef unsigned int   u32;
typedef float f32x4 __attribute__((ext_vector_type(4)));
typedef __bf16 bf16x8 __attribute__((ext_vector_type(8)));

#define T_LEN  1024
#define DMODEL 1024
#define NTOK   2048
#define NHEAD  16
#define HDIM   64
#define NEXP   8
#define FFDIM  4096

#define VMW(n)   asm volatile("s_waitcnt vmcnt(" #n ")" ::: "memory")
#define LGKM0()  asm volatile("s_waitcnt lgkmcnt(0)" ::: "memory")
#define SBAR()   __builtin_amdgcn_s_barrier()
#define SCHED0() __builtin_amdgcn_sched_barrier(0)
#define PRIO(n)  __builtin_amdgcn_s_setprio(n)

__device__ __forceinline__ u16 f2bf(float f) {          // RNE
  union { float f; u32 u; } v; v.f = f;
  u32 r = v.u + 0x7FFFu + ((v.u >> 16) & 1u);
  return (u16)(r >> 16);
}
__device__ __forceinline__ float bf2f(u16 h) {
  union { u32 u; float f; } v; v.u = ((u32)h) << 16; return v.f;
}

// async 16B global->LDS (wave-uniform LDS base; HW adds lane*16)
__device__ __forceinline__ void g2l16(const u16* src, u16* ldsbase) {
  __builtin_amdgcn_global_load_lds(
      (const __attribute__((address_space(1))) void*)src,
      (__attribute__((address_space(3))) void*)ldsbase, 16, 0, 0);
}

// split 16 f32 -> 8 packed u32 hi + 8 packed u32 lo
__device__ __forceinline__ void split16(const float* src, u32* H, u32* L) {
  #pragma unroll
  for (int j = 0; j < 8; ++j) {
    float a = src[2*j], b = src[2*j+1];
    u16 ha = f2bf(a), hb = f2bf(b);
    u16 la = f2bf(a - bf2f(ha)), lb = f2bf(b - bf2f(hb));
    H[j] = (u32)ha | ((u32)hb << 16);
    L[j] = (u32)la | ((u32)lb << 16);
  }
}

// ---------------- RMSNorm -> hi/lo bf16 split (for GEMM A-operand) ---------
__global__ __launch_bounds__(256) void tb_rms_hl(const float* __restrict__ x,
    const float* __restrict__ scale, u16* __restrict__ oh, u16* __restrict__ ol) {
  int t = blockIdx.x, tid = threadIdx.x;
  const float* xr = x + (size_t)t * DMODEL;
  float4 v = *(const float4*)(xr + tid * 4);
  double ss = (double)v.x*v.x + (double)v.y*v.y + (double)v.z*v.z + (double)v.w*v.w;
  #pragma unroll
  for (int off = 32; off; off >>= 1) ss += __shfl_xor(ss, off);
  __shared__ double red[4];
  if ((tid & 63) == 0) red[tid >> 6] = ss;
  __syncthreads();
  double denom = sqrt((red[0]+red[1]+red[2]+red[3]) / (double)DMODEL) + 1e-5;
  float4 sc = *(const float4*)(scale + tid * 4);
  float y[4];
  y[0] = (float)((double)v.x / denom * (double)sc.x);
  y[1] = (float)((double)v.y / denom * (double)sc.y);
  y[2] = (float)((double)v.z / denom * (double)sc.z);
  y[3] = (float)((double)v.w / denom * (double)sc.w);
  u16* ph = oh + (size_t)t*DMODEL + tid*4;
  u16* pl = ol + (size_t)t*DMODEL + tid*4;
  #pragma unroll
  for (int j = 0; j < 4; ++j) {
    u16 h = f2bf(y[j]);
    ph[j] = h;
    pl[j] = f2bf(y[j] - bf2f(h));
  }
}

// ---------------- RMSNorm (f64 accumulate; f32 + bf16 outputs) -------------
__global__ __launch_bounds__(256) void tb_rms(const float* __restrict__ x,
    const float* __restrict__ scale, float* __restrict__ out_f, u16* __restrict__ out_b) {
  int t = blockIdx.x, tid = threadIdx.x;
  const float* xr = x + (size_t)t * DMODEL;
  float4 v = *(const float4*)(xr + tid * 4);
  double ss = (double)v.x*v.x + (double)v.y*v.y + (double)v.z*v.z + (double)v.w*v.w;
  #pragma unroll
  for (int off = 32; off; off >>= 1) ss += __shfl_xor(ss, off);
  __shared__ double red[4];
  if ((tid & 63) == 0) red[tid >> 6] = ss;
  __syncthreads();
  double denom = sqrt((red[0]+red[1]+red[2]+red[3]) / (double)DMODEL) + 1e-5;
  float4 sc = *(const float4*)(scale + tid * 4);
  float y0 = (float)((double)v.x / denom * (double)sc.x);
  float y1 = (float)((double)v.y / denom * (double)sc.y);
  float y2 = (float)((double)v.z / denom * (double)sc.z);
  float y3 = (float)((double)v.w / denom * (double)sc.w);
  *(float4*)(out_f + (size_t)t*DMODEL + tid*4) = make_float4(y0,y1,y2,y3);
  u16* ob = out_b + (size_t)t*DMODEL + tid*4;
  ob[0]=f2bf(y0); ob[1]=f2bf(y1); ob[2]=f2bf(y2); ob[3]=f2bf(y3);
}

// ------- weight pre-split+transpose: W[k][n] f32 -> Wt[n][k] bf16 (hi[,lo]) -
template<int HILO>
__global__ __launch_bounds__(256) void tb_wsplit(const float* __restrict__ W,
    u16* __restrict__ Wh, u16* __restrict__ Wl, int K, int N) {
  __shared__ float Tf[64*68];
  size_t eo = (size_t)blockIdx.z * (size_t)K * N;
  const float* Wb = W + eo;
  int n0 = blockIdx.x*64, k0 = blockIdx.y*64;
  int tid = threadIdx.x;
  int r = tid >> 2, c = tid & 3;
  const float* wp = Wb + (size_t)(k0+r)*N + n0 + c*16;
  float vv[16];
  *(float4*)&vv[0]  = ((const float4*)wp)[0];
  *(float4*)&vv[4]  = ((const float4*)wp)[1];
  *(float4*)&vv[8]  = ((const float4*)wp)[2];
  *(float4*)&vv[12] = ((const float4*)wp)[3];
  #pragma unroll
  for (int j = 0; j < 16; ++j) Tf[(c*16+j)*68 + r] = vv[j];
  __syncthreads();
  int n = tid >> 2, kc = tid & 3;
  float tv[16];
  #pragma unroll
  for (int j = 0; j < 16; ++j) tv[j] = Tf[n*68 + kc*16 + j];
  u32 H[8], L[8];
  split16(tv, H, L);
  u16* oh = Wh + eo + (size_t)(n0+n)*K + k0 + kc*16;
  *(uint4*)oh       = make_uint4(H[0],H[1],H[2],H[3]);
  *(uint4*)(oh + 8) = make_uint4(H[4],H[5],H[6],H[7]);
  if (HILO) {
    u16* ol = Wl + eo + (size_t)(n0+n)*K + k0 + kc*16;
    *(uint4*)ol       = make_uint4(L[0],L[1],L[2],L[3]);
    *(uint4*)(ol + 8) = make_uint4(L[4],L[5],L[6],L[7]);
  }
}

// --- split-bf16 MFMA GEMM, all operands via global_load_lds ----------------
// Depth-2 counted-vmcnt dbuf (64KB LDS -> 2 blocks/CU co-residency).
template<int RESID>
__global__ __launch_bounds__(256) void tb_gemm_sp2(const u16* __restrict__ Ahg,
    const u16* __restrict__ Alg, const u16* __restrict__ Bhg,
    const u16* __restrict__ Blg, const float* __restrict__ bias,
    const float* __restrict__ resid, float* __restrict__ C,
    int M, int N, int K) {
  __shared__ __align__(16) u16 Ah[2][128*32], Al[2][128*32];
  __shared__ __align__(16) u16 Bh[2][128*32], Bl[2][128*32];   // 64KB total
  int tid = threadIdx.x;
  int row0 = blockIdx.y * 128, col0 = blockIdx.x * 128;
  int lane = tid & 63, wave = tid >> 6;
  int wm = wave >> 1, wn = wave & 1;
  int l15 = lane & 15, l4 = lane >> 4;
  int sw = (l15 >> 1) & 3;
  int ci0 = ((wave*2+0)<<6)+lane, ci1 = ((wave*2+1)<<6)+lane;
  int r0 = ci0 >> 2, c0 = ((ci0 & 3) ^ ((r0 >> 1) & 3)) << 3;
  int r1 = ci1 >> 2, c1 = ((ci1 & 3) ^ ((r1 >> 1) & 3)) << 3;
  int lo0 = (wave*2+0) << 9, lo1 = (wave*2+1) << 9;
  f32x4 zero = {0.f,0.f,0.f,0.f};
  f32x4 acc[4][4];
  #pragma unroll
  for (int i=0;i<4;++i) for (int j=0;j<4;++j) acc[i][j] = zero;
  const int nt = K / 32;

  #define SP2_STAGE(b, k0) do { \
    g2l16(Ahg + (size_t)(row0+r0)*K + (k0) + c0, &Ah[b][lo0]); \
    g2l16(Ahg + (size_t)(row0+r1)*K + (k0) + c1, &Ah[b][lo1]); \
    g2l16(Alg + (size_t)(row0+r0)*K + (k0) + c0, &Al[b][lo0]); \
    g2l16(Alg + (size_t)(row0+r1)*K + (k0) + c1, &Al[b][lo1]); \
    g2l16(Bhg + (size_t)(col0+r0)*K + (k0) + c0, &Bh[b][lo0]); \
    g2l16(Bhg + (size_t)(col0+r1)*K + (k0) + c1, &Bh[b][lo1]); \
    g2l16(Blg + (size_t)(col0+r0)*K + (k0) + c0, &Bl[b][lo0]); \
    g2l16(Blg + (size_t)(col0+r1)*K + (k0) + c1, &Bl[b][lo1]); } while(0)

  SP2_STAGE(0, 0);
  SP2_STAGE(1, 32);
  for (int t = 0; t < nt; ++t) {
    int cur = t & 1;
    if (t + 1 < nt) { VMW(8); } else { VMW(0); }
    SBAR(); SCHED0();
    bf16x8 ah[4], al_[4], bh_[4], bl_[4];
    #pragma unroll
    for (int mi = 0; mi < 4; ++mi) {
      int ro = (wm*64 + mi*16 + l15) << 5;
      ah[mi]  = *(const bf16x8*)(&Ah[cur][ro + ((l4 ^ sw) << 3)]);
      al_[mi] = *(const bf16x8*)(&Al[cur][ro + ((l4 ^ sw) << 3)]);
    }
    #pragma unroll
    for (int ni = 0; ni < 4; ++ni) {
      int ro = (wn*64 + ni*16 + l15) << 5;
      bh_[ni] = *(const bf16x8*)(&Bh[cur][ro + ((l4 ^ sw) << 3)]);
      bl_[ni] = *(const bf16x8*)(&Bl[cur][ro + ((l4 ^ sw) << 3)]);
    }
    PRIO(1);
    #pragma unroll
    for (int mi = 0; mi < 4; ++mi)
      #pragma unroll
      for (int ni = 0; ni < 4; ++ni) {
        acc[mi][ni] = __builtin_amdgcn_mfma_f32_16x16x32_bf16(ah[mi], bh_[ni], acc[mi][ni], 0,0,0);
        acc[mi][ni] = __builtin_amdgcn_mfma_f32_16x16x32_bf16(ah[mi], bl_[ni], acc[mi][ni], 0,0,0);
        acc[mi][ni] = __builtin_amdgcn_mfma_f32_16x16x32_bf16(al_[mi], bh_[ni], acc[mi][ni], 0,0,0);
      }
    PRIO(0);
    if (t + 1 < nt) {
      SBAR();
      if (t + 2 < nt) SP2_STAGE(cur, (t+2)*32);
    }
  }
  #undef SP2_STAGE
  #pragma unroll
  for (int mi = 0; mi < 4; ++mi)
    #pragma unroll
    for (int r = 0; r < 4; ++r) {
      int row = row0 + wm*64 + mi*16 + l4*4 + r;
      #pragma unroll
      for (int ni = 0; ni < 4; ++ni) {
        int col = col0 + wn*64 + ni*16 + l15;
        float vv = acc[mi][ni][r] + bias[col];
        if (RESID) vv += resid[(size_t)row*N + col];
        C[(size_t)row*N + col] = vv;
      }
    }
}

// ---------------- RoPE trig table (f64) ------------------------------------
__global__ void tb_trig(float* __restrict__ tab) {
  int t = blockIdx.x, d = threadIdx.x;
  double theta = pow(10000.0, -(double)d / 32.0);
  double ang = (double)t * theta;
  tab[(t*32 + d)*2 + 0] = (float)cos(ang);
  tab[(t*32 + d)*2 + 1] = (float)sin(ang);
}

// ---------------- qkv -> Q f32, K bf16 hi/lo (all [bh][t][d]), V f32 -------
__global__ __launch_bounds__(256) void tb_rope2(const float* __restrict__ qkv,
    const float* __restrict__ tab, float* __restrict__ Qf, u16* __restrict__ Khg,
    u16* __restrict__ Klg, float* __restrict__ Vf) {
  int n = blockIdx.x;
  int b = n >> 10, t = n & 1023;
  const float* src = qkv + (size_t)n * 3072;
  for (int idx = threadIdx.x; idx < 512; idx += 256) {
    int h = idx >> 5, d = idx & 31;
    float ca = tab[(t*32+d)*2], sa = tab[(t*32+d)*2+1];
    size_t base = ((size_t)(b*NHEAD + h) * T_LEN + t) * HDIM;
    { float x1 = src[h*64 + d], x2 = src[h*64 + d + 32];
      Qf[base + d]      = x1*ca - x2*sa;
      Qf[base + d + 32] = x1*sa + x2*ca; }
    { float x1 = src[1024 + h*64 + d], x2 = src[1024 + h*64 + d + 32];
      float k1 = x1*ca - x2*sa, k2 = x1*sa + x2*ca;
      u16 h1 = f2bf(k1), h2 = f2bf(k2);
      Khg[base + d] = h1;      Khg[base + d + 32] = h2;
      Klg[base + d] = f2bf(k1 - bf2f(h1));
      Klg[base + d + 32] = f2bf(k2 - bf2f(h2)); }
  }
  for (int c = threadIdx.x; c < 1024; c += 256) {
    int h = c >> 6, d = c & 63;
    Vf[((size_t)(b*NHEAD + h) * T_LEN + t) * HDIM + d] = src[2048 + c];
  }
}

// ---------------- V transpose+split: [bh][t][d] f32 -> [bh][d][t] bf16 -----
__global__ __launch_bounds__(256) void tb_vt(const float* __restrict__ Vf,
    u16* __restrict__ Vh, u16* __restrict__ Vl) {
  __shared__ float Tf[64*68];
  int t0 = blockIdx.x * 64, bh = blockIdx.y;
  const float* Vb = Vf + (size_t)bh * (T_LEN*HDIM);
  int tid = threadIdx.x, r = tid >> 2, c = tid & 3;
  const float* vp = Vb + (size_t)(t0+r)*HDIM + c*16;
  float vv[16];
  *(float4*)&vv[0]  = ((const float4*)vp)[0];
  *(float4*)&vv[4]  = ((const float4*)vp)[1];
  *(float4*)&vv[8]  = ((const float4*)vp)[2];
  *(float4*)&vv[12] = ((const float4*)vp)[3];
  #pragma unroll
  for (int j = 0; j < 16; ++j) Tf[(c*16+j)*68 + r] = vv[j];
  __syncthreads();
  int d = tid >> 2, tc = tid & 3;
  float tv[16];
  #pragma unroll
  for (int j = 0; j < 16; ++j) tv[j] = Tf[d*68 + tc*16 + j];
  u32 H[8], L[8];
  split16(tv, H, L);
  u16* oh = Vh + (size_t)bh*(HDIM*T_LEN) + (size_t)d*T_LEN + t0 + tc*16;
  u16* ol = Vl + (size_t)bh*(HDIM*T_LEN) + (size_t)d*T_LEN + t0 + tc*16;
  *(uint4*)oh       = make_uint4(H[0],H[1],H[2],H[3]);
  *(uint4*)(oh + 8) = make_uint4(H[4],H[5],H[6],H[7]);
  *(uint4*)ol       = make_uint4(L[0],L[1],L[2],L[3]);
  *(uint4*)(ol + 8) = make_uint4(L[4],L[5],L[6],L[7]);
}

// ---------------- MFMA flash attention; writes O as hi/lo bf16 split -------
__global__ __launch_bounds__(256) void tb_attn_mfma(const float* __restrict__ Qf,
    const u16* __restrict__ Khg, const u16* __restrict__ Klg,
    const u16* __restrict__ Vhg, const u16* __restrict__ Vlg,
    u16* __restrict__ Obh, u16* __restrict__ Obl) {
  __shared__ __align__(16) u16 Kh[64*72], Kl[64*72];
  __shared__ __align__(16) u16 Vh[64*72], Vl[64*72];
  __shared__ __align__(16) u16 Ph[64*72], Pl[64*72];
  int qt = blockIdx.x, bh = blockIdx.y;
  int tid = threadIdx.x, lane = tid & 63, w = tid >> 6;
  int l15 = lane & 15, l4 = lane >> 4;
  int b = bh >> 4, h = bh & 15;
  const float* Qb = Qf + (size_t)bh * (T_LEN*HDIM);
  const u16* Khb = Khg + (size_t)bh * (T_LEN*HDIM);
  const u16* Klb = Klg + (size_t)bh * (T_LEN*HDIM);
  const u16* Vhb = Vhg + (size_t)bh * (HDIM*T_LEN);
  const u16* Vlb = Vlg + (size_t)bh * (HDIM*T_LEN);
  int q0 = qt * 64;
  int qrow = q0 + w*16 + l15;
  bf16x8 qh[2], ql[2];
  #pragma unroll
  for (int ks = 0; ks < 2; ++ks) {
    const float* qp = Qb + (size_t)qrow*HDIM + ks*32 + l4*8;
    float vv[8];
    *(float4*)&vv[0] = ((const float4*)qp)[0];
    *(float4*)&vv[4] = ((const float4*)qp)[1];
    u32 H[4], L[4];
    #pragma unroll
    for (int j = 0; j < 4; ++j) {
      float a = vv[2*j], bb = vv[2*j+1];
      u16 ha = f2bf(a), hb = f2bf(bb);
      u16 la = f2bf(a - bf2f(ha)), lb = f2bf(bb - bf2f(hb));
      H[j] = (u32)ha | ((u32)hb << 16);
      L[j] = (u32)la | ((u32)lb << 16);
    }
    union { uint4 u; bf16x8 b; } th, tl;
    th.u = make_uint4(H[0],H[1],H[2],H[3]);
    tl.u = make_uint4(L[0],L[1],L[2],L[3]);
    qh[ks] = th.b; ql[ks] = tl.b;
  }
  int qg[4];
  #pragma unroll
  for (int r = 0; r < 4; ++r) qg[r] = q0 + w*16 + l4*4 + r;
  float mrow[4], lrow[4];
  f32x4 oacc[4];
  f32x4 zero = {0.f,0.f,0.f,0.f};
  #pragma unroll
  for (int r = 0; r < 4; ++r) { mrow[r] = -1e30f; lrow[r] = 0.f; }
  #pragma unroll
  for (int d = 0; d < 4; ++d) oacc[d] = zero;

  int sr = tid >> 2, sc = tid & 3;
  for (int kt = 0; kt <= qt; ++kt) {
    int k0 = kt * 64;
    __syncthreads();
    {
      const u16* kp = Khb + (size_t)(k0+sr)*HDIM + sc*16;
      *(uint4*)(Kh + sr*72 + sc*16)     = ((const uint4*)kp)[0];
      *(uint4*)(Kh + sr*72 + sc*16 + 8) = ((const uint4*)kp)[1];
      const u16* kl2 = Klb + (size_t)(k0+sr)*HDIM + sc*16;
      *(uint4*)(Kl + sr*72 + sc*16)     = ((const uint4*)kl2)[0];
      *(uint4*)(Kl + sr*72 + sc*16 + 8) = ((const uint4*)kl2)[1];
      const u16* vp = Vhb + (size_t)sr*T_LEN + k0 + sc*16;
      *(uint4*)(Vh + sr*72 + sc*16)     = ((const uint4*)vp)[0];
      *(uint4*)(Vh + sr*72 + sc*16 + 8) = ((const uint4*)vp)[1];
      const u16* vl2 = Vlb + (size_t)sr*T_LEN + k0 + sc*16;
      *(uint4*)(Vl + sr*72 + sc*16)     = ((const uint4*)vl2)[0];
      *(uint4*)(Vl + sr*72 + sc*16 + 8) = ((const uint4*)vl2)[1];
    }
    __syncthreads();
    f32x4 sacc[4];
    #pragma unroll
    for (int ni = 0; ni < 4; ++ni) {
      sacc[ni] = zero;
      #pragma unroll
      for (int ks = 0; ks < 2; ++ks) {
        bf16x8 kh_ = *(const bf16x8*)(Kh + (ni*16 + l15)*72 + ks*32 + l4*8);
        bf16x8 kl_ = *(const bf16x8*)(Kl + (ni*16 + l15)*72 + ks*32 + l4*8);
        sacc[ni] = __builtin_amdgcn_mfma_f32_16x16x32_bf16(qh[ks], kh_, sacc[ni], 0,0,0);
        sacc[ni] = __builtin_amdgcn_mfma_f32_16x16x32_bf16(qh[ks], kl_, sacc[ni], 0,0,0);
        sacc[ni] = __builtin_amdgcn_mfma_f32_16x16x32_bf16(ql[ks], kh_, sacc[ni], 0,0,0);
      }
    }
    bool diag = (kt == qt);
    float sv[4][4];
    #pragma unroll
    for (int ni = 0; ni < 4; ++ni)
      #pragma unroll
      for (int r = 0; r < 4; ++r) {
        float s = sacc[ni][r] * 0.125f;
        if (diag && (k0 + ni*16 + l15 > qg[r])) s = -1e30f;
        sv[ni][r] = s;
      }
    float mt[4];
    #pragma unroll
    for (int r = 0; r < 4; ++r)
      mt[r] = fmaxf(fmaxf(sv[0][r], sv[1][r]), fmaxf(sv[2][r], sv[3][r]));
    #pragma unroll
    for (int off = 1; off < 16; off <<= 1)
      #pragma unroll
      for (int r = 0; r < 4; ++r) mt[r] = fmaxf(mt[r], __shfl_xor(mt[r], off));
    float al[4];
    #pragma unroll
    for (int r = 0; r < 4; ++r) {
      float mn = fmaxf(mrow[r], mt[r]);
      al[r] = expf(mrow[r] - mn);
      mrow[r] = mn;
    }
    float ls[4] = {0.f,0.f,0.f,0.f};
    #pragma unroll
    for (int ni = 0; ni < 4; ++ni)
      #pragma unroll
      for (int r = 0; r < 4; ++r) {
        float p = expf(sv[ni][r] - mrow[r]);
        u16 ph2 = f2bf(p);
        int qrl = w*16 + l4*4 + r;
        Ph[qrl*72 + ni*16 + l15] = ph2;
        Pl[qrl*72 + ni*16 + l15] = f2bf(p - bf2f(ph2));
        ls[r] += p;
      }
    #pragma unroll
    for (int off = 1; off < 16; off <<= 1)
      #pragma unroll
      for (int r = 0; r < 4; ++r) ls[r] += __shfl_xor(ls[r], off);
    #pragma unroll
    for (int r = 0; r < 4; ++r) lrow[r] = lrow[r]*al[r] + ls[r];
    #pragma unroll
    for (int d = 0; d < 4; ++d)
      #pragma unroll
      for (int r = 0; r < 4; ++r) oacc[d][r] *= al[r];
    bf16x8 ph_[2], pl_[2];
    #pragma unroll
    for (int ks = 0; ks < 2; ++ks) {
      ph_[ks] = *(const bf16x8*)(Ph + (w*16 + l15)*72 + ks*32 + l4*8);
      pl_[ks] = *(const bf16x8*)(Pl + (w*16 + l15)*72 + ks*32 + l4*8);
    }
    #pragma unroll
    for (int dblk = 0; dblk < 4; ++dblk)
      #pragma unroll
      for (int ks = 0; ks < 2; ++ks) {
        bf16x8 vh_ = *(const bf16x8*)(Vh + (dblk*16 + l15)*72 + ks*32 + l4*8);
        bf16x8 vl_ = *(const bf16x8*)(Vl + (dblk*16 + l15)*72 + ks*32 + l4*8);
        oacc[dblk] = __builtin_amdgcn_mfma_f32_16x16x32_bf16(ph_[ks], vh_, oacc[dblk], 0,0,0);
        oacc[dblk] = __builtin_amdgcn_mfma_f32_16x16x32_bf16(ph_[ks], vl_, oacc[dblk], 0,0,0);
        oacc[dblk] = __builtin_amdgcn_mfma_f32_16x16x32_bf16(pl_[ks], vh_, oacc[dblk], 0,0,0);
      }
  }
  #pragma unroll
  for (int dblk = 0; dblk < 4; ++dblk)
    #pragma unroll
    for (int r = 0; r < 4; ++r) {
      int q = qg[r];
      int d = dblk*16 + l15;
      float ov = oacc[dblk][r] / lrow[r];
      u16 hh = f2bf(ov);
      size_t oi = ((size_t)b * T_LEN + q) * DMODEL + h * HDIM + d;
      Obh[oi] = hh;
      Obl[oi] = f2bf(ov - bf2f(hh));
    }
}

// ---------------- router: f64 logits, top-2 --------------------------------
__global__ __launch_bounds__(64) void tb_gating(const float* __restrict__ xn2,
    const float* __restrict__ wg, const float* __restrict__ bg,
    int* __restrict__ top_idx, float* __restrict__ gate_w, int* __restrict__ counts) {
  int t = blockIdx.x, lane = threadIdx.x;
  const float* xr = xn2 + (size_t)t * DMODEL;
  double part[8];
  #pragma unroll
  for (int e = 0; e < 8; ++e) part[e] = 0.0;
  for (int i = lane; i < DMODEL; i += 64) {
    double xv = (double)xr[i];
    const float* wr = wg + (size_t)i * 8;
    #pragma unroll
    for (int e = 0; e < 8; ++e) part[e] += xv * (double)wr[e];
  }
  #pragma unroll
  for (int e = 0; e < 8; ++e)
    for (int off = 32; off; off >>= 1) part[e] += __shfl_xor(part[e], off);
  if (lane == 0) {
    double lg[8];
    for (int e = 0; e < 8; ++e) lg[e] = part[e] + (double)bg[e];
    int i1 = 0;
    for (int e = 1; e < 8; ++e) if (lg[e] > lg[i1]) i1 = e;
    int i2 = (i1 == 0) ? 1 : 0;
    for (int e = 0; e < 8; ++e) if (e != i1 && lg[e] > lg[i2]) i2 = e;
    double e2 = exp(lg[i2] - lg[i1]);
    double den = 1.0 + e2;
    top_idx[t*2] = i1; top_idx[t*2+1] = i2;
    gate_w[t*2] = (float)(1.0/den); gate_w[t*2+1] = (float)(e2/den);
    atomicAdd(&counts[i1], 1); atomicAdd(&counts[i2], 1);
  }
}

__global__ void tb_scan(const int* __restrict__ counts, int* __restrict__ offs,
    int* __restrict__ cursor, float* __restrict__ aux_out) {
  if (threadIdx.x == 0) {
    int off = 0; float aux = 0.f;
    for (int e = 0; e < 8; ++e) {
      offs[e] = off; cursor[e] = off; off += counts[e];
      float fr = (float)counts[e] / 4096.0f - 0.125f;
      aux += fr * fr;
    }
    aux_out[0] = aux;
  }
}

__global__ __launch_bounds__(128) void tb_gather(const u16* __restrict__ xn2b,
    const int* __restrict__ top_idx, int* __restrict__ cursor,
    int* __restrict__ slot_of, u16* __restrict__ Xg) {
  int t = blockIdx.x;
  __shared__ int sl[2];
  if (threadIdx.x < 2) {
    int e = top_idx[t*2 + threadIdx.x];
    int s = atomicAdd(&cursor[e], 1);
    sl[threadIdx.x] = s;
    slot_of[t*2 + threadIdx.x] = s;
  }
  __syncthreads();
  uint4 v = *(const uint4*)(xn2b + (size_t)t * DMODEL + threadIdx.x * 8);
  *(uint4*)(Xg + (size_t)sl[0] * DMODEL + threadIdx.x * 8) = v;
  *(uint4*)(Xg + (size_t)sl[1] * DMODEL + threadIdx.x * 8) = v;
}

// --- fused MoE MLP, multi-phase counted-vmcnt schedule (m201-style) --------
// 256m x 128n tile, 8 waves (4m x 2n). K32 staging units in a 4-deep LDS
// ring (128KB); per unit 2 phases {acc1-cluster, acc2-cluster}, each
// {reads, stage-issue(u+3), lgkm0, setprio-MFMA, barrier}. vmcnt(8) steady
// (units u+1,u+2 in flight, 4 loads/wave each); loads never drain.
__global__ __launch_bounds__(512, 1) void tb_moe_mlp8(const u16* __restrict__ Ag,
    const u16* __restrict__ B1t, const u16* __restrict__ B2t,
    const float* __restrict__ b1g, const float* __restrict__ b2g,
    u16* __restrict__ Hout, const int* __restrict__ counts,
    const int* __restrict__ offs, int ebase) {
  const int K = DMODEL, N = FFDIM;
  int ez = blockIdx.z, e = ebase + ez;
  int cnt = counts[e];
  if ((int)blockIdx.y * 256 >= cnt) return;
  int row0 = offs[e] + blockIdx.y * 256;
  int rend = offs[e] + cnt;
  int col0 = blockIdx.x * 128;
  const u16* B1 = B1t + (size_t)ez * K * N;
  const u16* B2 = B2t + (size_t)ez * K * N;
  const float* bb1 = b1g + (size_t)e * N;
  const float* bb2 = b2g + (size_t)e * N;
  __shared__ __align__(16) u16 As[4][256*32];    // 64KB
  __shared__ __align__(16) u16 Bs1[4][128*32];   // 32KB
  __shared__ __align__(16) u16 Bs2[4][128*32];   // 32KB
  int tid = threadIdx.x, lane = tid & 63, wave = tid >> 6;  // 8 waves
  int wm = wave >> 1, wn = wave & 1;
  int l15 = lane & 15, l4 = lane >> 4;
  int sw = (l15 >> 1) & 3;
  int ai0 = ((wave*2+0)<<6) + lane, ai1 = ((wave*2+1)<<6) + lane;
  int ar0 = ai0 >> 2, ac0 = ((ai0 & 3) ^ ((ar0 >> 1) & 3)) << 3;
  int ar1 = ai1 >> 2, ac1 = ((ai1 & 3) ^ ((ar1 >> 1) & 3)) << 3;
  int ga0 = row0 + ar0 < rend ? row0 + ar0 : rend - 1;
  int ga1 = row0 + ar1 < rend ? row0 + ar1 : rend - 1;
  int alo0 = (wave*2+0) << 9, alo1 = (wave*2+1) << 9;
  int bi = (wave << 6) + lane;
  int br = bi >> 2, bc = ((bi & 3) ^ ((br >> 1) & 3)) << 3;
  int blo = wave << 9;
  f32x4 zero = {0.f,0.f,0.f,0.f};
  f32x4 acc1[4][4], acc2[4][4];
  #pragma unroll
  for (int i=0;i<4;++i) for (int j=0;j<4;++j) { acc1[i][j] = zero; acc2[i][j] = zero; }

  #define M8_STAGE_A(b, k0) do { \
    g2l16(Ag + (size_t)ga0*K + (k0) + ac0, &As[b][alo0]); \
    g2l16(Ag + (size_t)ga1*K + (k0) + ac1, &As[b][alo1]); } while(0)
  #define M8_STAGE_B(b, k0) do { \
    g2l16(B1 + (size_t)(col0+br)*K + (k0) + bc, &Bs1[b][blo]); \
    g2l16(B2 + (size_t)(col0+br)*K + (k0) + bc, &Bs2[b][blo]); } while(0)

  // prologue: units 0,1,2 (4 loads/wave each -> 12 outstanding)
  M8_STAGE_A(0, 0);   M8_STAGE_B(0, 0);
  M8_STAGE_A(1, 32);  M8_STAGE_B(1, 32);
  M8_STAGE_A(2, 64);  M8_STAGE_B(2, 64);
  const int NT = K / 32;   // 32 units
  for (int u = 0; u < NT; ++u) {
    int buf = u & 3;
    // ---- phase 1: acc1 cluster ----
    if (u + 2 < NT) { VMW(8); } else if (u + 1 < NT) { VMW(4); } else { VMW(0); }
    SBAR(); SCHED0();                       // unit u landed for ALL waves
    bf16x8 af[4], bf1[4], bf2[4];
    #pragma unroll
    for (int mi = 0; mi < 4; ++mi)
      af[mi] = *(const bf16x8*)(&As[buf][((wm*64 + mi*16 + l15) << 5) + ((l4 ^ sw) << 3)]);
    #pragma unroll
    for (int ni = 0; ni < 4; ++ni)
      bf1[ni] = *(const bf16x8*)(&Bs1[buf][((wn*64 + ni*16 + l15) << 5) + ((l4 ^ sw) << 3)]);
    if (u + 3 < NT) M8_STAGE_A((u+3) & 3, (u+3)*32);   // buf[(u+3)&3] = buf[(u-1)&3]: readers sealed by barrier above
    LGKM0(); SCHED0();
    PRIO(1);
    #pragma unroll
    for (int mi = 0; mi < 4; ++mi)
      #pragma unroll
      for (int ni = 0; ni < 4; ++ni)
        acc1[mi][ni] = __builtin_amdgcn_mfma_f32_16x16x32_bf16(af[mi], bf1[ni], acc1[mi][ni], 0,0,0);
    PRIO(0);
    SBAR();
    // ---- phase 2: acc2 cluster ----
    #pragma unroll
    for (int ni = 0; ni < 4; ++ni)
      bf2[ni] = *(const bf16x8*)(&Bs2[buf][((wn*64 + ni*16 + l15) << 5) + ((l4 ^ sw) << 3)]);
    if (u + 3 < NT) M8_STAGE_B((u+3) & 3, (u+3)*32);
    LGKM0(); SCHED0();
    PRIO(1);
    #pragma unroll
    for (int mi = 0; mi < 4; ++mi)
      #pragma unroll
      for (int ni = 0; ni < 4; ++ni)
        acc2[mi][ni] = __builtin_amdgcn_mfma_f32_16x16x32_bf16(af[mi], bf2[ni], acc2[mi][ni], 0,0,0);
    PRIO(0);
    SBAR();
  }
  #undef M8_STAGE_A
  #undef M8_STAGE_B
  #pragma unroll
  for (int mi = 0; mi < 4; ++mi) {
    #pragma unroll
    for (int r = 0; r < 4; ++r) {
      int row = row0 + wm*64 + mi*16 + l4*4 + r;
      if (row >= rend) continue;
      #pragma unroll
      for (int ni = 0; ni < 4; ++ni) {
        int col = col0 + wn*64 + ni*16 + l15;
        float v1 = acc1[mi][ni][r] + bb1[col];
        float v2 = acc2[mi][ni][r] + bb2[col];
        float hv = (v1 / (1.f + expf(-v1))) * v2;
        Hout[(size_t)row * N + col] = f2bf(hv);
      }
    }
  }
}

// --- MoE down-proj, split-K=4, in-kernel f32 convert; partials (no bias) ---
__global__ __launch_bounds__(256) void tb_moe_wp(const u16* __restrict__ Ag,
    const float* __restrict__ Wp, float* __restrict__ Pout,
    const int* __restrict__ counts, const int* __restrict__ offs) {
  const int K = FFDIM, N = DMODEL;
  int e = blockIdx.z & 7, ks = blockIdx.z >> 3;
  int cnt = counts[e];
  if ((int)blockIdx.y * 128 >= cnt) return;
  int row0 = offs[e] + blockIdx.y * 128;
  int rend = offs[e] + cnt;
  int col0 = blockIdx.x * 128;
  int kbase = ks * 1024;
  const float* Bw = Wp + (size_t)e * K * N;
  float* out = Pout + (size_t)ks * (4096u*1024u);
  __shared__ __align__(16) u16 As[2][128*32], Bs[2][128*32];
  int tid = threadIdx.x, lane = tid & 63, wave = tid >> 6;
  int wm = wave >> 1, wn = wave & 1;
  int l15 = lane & 15, l4 = lane >> 4;
  int sw = (l15 >> 1) & 3;
  int ci0 = ((wave*2+0)<<6) + lane, ci1 = ((wave*2+1)<<6) + lane;
  int ar0 = ci0 >> 2, ac0 = ((ci0 & 3) ^ ((ar0 >> 1) & 3)) << 3;
  int ar1 = ci1 >> 2, ac1 = ((ci1 & 3) ^ ((ar1 >> 1) & 3)) << 3;
  int ga0 = row0 + ar0 < rend ? row0 + ar0 : rend - 1;
  int ga1 = row0 + ar1 < rend ? row0 + ar1 : rend - 1;
  int lo0 = (wave*2+0) << 9, lo1 = (wave*2+1) << 9;
  int bn = tid & 127;
  int bkg = (tid >> 7) << 4;
  int bsw = (bn >> 1) & 3;
  int bc0 = bkg >> 3;
  int boff0 = bn*32 + (( bc0    ^ bsw) << 3);
  int boff1 = bn*32 + (((bc0+1) ^ bsw) << 3);
  f32x4 zero = {0.f,0.f,0.f,0.f};
  f32x4 acc[4][4];
  #pragma unroll
  for (int i=0;i<4;++i) for (int j=0;j<4;++j) acc[i][j] = zero;
  float r1[16];

  #define WP_ISSUE_A(b, k0) do { \
    g2l16(Ag + (size_t)ga0*K + kbase + (k0) + ac0, &As[b][lo0]); \
    g2l16(Ag + (size_t)ga1*K + kbase + (k0) + ac1, &As[b][lo1]); } while(0)
  #define WP_LOAD_B(k0) do { \
    const float* p1 = Bw + (size_t)(kbase+(k0)+bkg)*N + col0 + bn; \
    _Pragma("unroll") \
    for (int j = 0; j < 16; ++j) r1[j] = p1[(size_t)j*N]; } while(0)
  #define WP_WRITE_B(b) do { \
    u32 P1[8]; \
    _Pragma("unroll") \
    for (int j = 0; j < 8; ++j) \
      asm("v_cvt_pk_bf16_f32 %0, %1, %2" : "=v"(P1[j]) : "v"(r1[2*j]), "v"(r1[2*j+1])); \
    *(uint4*)(&Bs[b][boff0]) = make_uint4(P1[0],P1[1],P1[2],P1[3]); \
    *(uint4*)(&Bs[b][boff1]) = make_uint4(P1[4],P1[5],P1[6],P1[7]); } while(0)

  WP_ISSUE_A(0, 0);
  WP_LOAD_B(0);
  VMW(0);
  WP_WRITE_B(0);
  LGKM0();
  SBAR();
  const int nt = 1024 / 32;
  for (int t = 0; t < nt; ++t) {
    int cur = t & 1;
    if (t + 1 < nt) { WP_ISSUE_A(cur^1, (t+1)*32); WP_LOAD_B((t+1)*32); }
    bf16x8 af[4], bfr[4];
    #pragma unroll
    for (int mi = 0; mi < 4; ++mi)
      af[mi] = *(const bf16x8*)(&As[cur][((wm*64 + mi*16 + l15) << 5) + ((l4 ^ sw) << 3)]);
    #pragma unroll
    for (int ni = 0; ni < 4; ++ni)
      bfr[ni] = *(const bf16x8*)(&Bs[cur][((wn*64 + ni*16 + l15) << 5) + ((l4 ^ sw) << 3)]);
    PRIO(1);
    #pragma unroll
    for (int mi = 0; mi < 4; ++mi)
      #pragma unroll
      for (int ni = 0; ni < 4; ++ni)
        acc[mi][ni] = __builtin_amdgcn_mfma_f32_16x16x32_bf16(af[mi], bfr[ni], acc[mi][ni], 0,0,0);
    PRIO(0);
    if (t + 1 < nt) {
      VMW(0);
      SBAR(); SCHED0();
      WP_WRITE_B(cur ^ 1);
      LGKM0();
      SBAR();
    }
  }
  #undef WP_ISSUE_A
  #undef WP_LOAD_B
  #undef WP_WRITE_B
  #pragma unroll
  for (int mi = 0; mi < 4; ++mi) {
    #pragma unroll
    for (int r = 0; r < 4; ++r) {
      int row = row0 + wm*64 + mi*16 + l4*4 + r;
      if (row >= rend) continue;
      #pragma unroll
      for (int ni = 0; ni < 4; ++ni) {
        int col = col0 + wn*64 + ni*16 + l15;
        out[(size_t)row * N + col] = acc[mi][ni][r];
      }
    }
  }
}

// --- final: out = x1 + sum_s g_s*(P0..P3[slot_s] + bp[e_s]) -----------------
__global__ __launch_bounds__(256) void tb_combine(const float* __restrict__ x1,
    const float* __restrict__ P, const int* __restrict__ slot_of,
    const int* __restrict__ top_idx, const float* __restrict__ gate_w,
    const float* __restrict__ bp, float* __restrict__ out) {
  const size_t SL = (size_t)4096 * 1024;
  int t = blockIdx.x;
  int c = threadIdx.x * 4;
  float4 a = *(const float4*)(x1 + (size_t)t*DMODEL + c);
  float ox = a.x, oy = a.y, oz = a.z, ow = a.w;
  #pragma unroll
  for (int s = 0; s < 2; ++s) {
    int slot = slot_of[t*2+s], e = top_idx[t*2+s];
    float g = gate_w[t*2+s];
    float4 v = *(const float4*)(bp + (size_t)e*DMODEL + c);
    #pragma unroll
    for (int ks = 0; ks < 4; ++ks) {
      float4 p = *(const float4*)(P + ks*SL + (size_t)slot*DMODEL + c);
      v.x += p.x; v.y += p.y; v.z += p.z; v.w += p.w;
    }
    ox += g*v.x; oy += g*v.y; oz += g*v.z; ow += g*v.w;
  }
  *(float4*)(out + (size_t)t*DMODEL + c) = make_float4(ox,oy,oz,ow);
}

extern "C" void kernel_launch(void* const* d_in, const int* in_sizes, int n_in,
                              void* d_out, int out_size, void* d_ws, size_t ws_size,
                              hipStream_t stream) {
  const float* x      = (const float*)d_in[0];
  const float* w_qkv  = (const float*)d_in[1];
  const float* b_qkv  = (const float*)d_in[2];
  const float* w_out  = (const float*)d_in[3];
  const float* b_out  = (const float*)d_in[4];
  const float* scale1 = (const float*)d_in[5];
  const float* scale2 = (const float*)d_in[6];
  const float* w_gate = (const float*)d_in[7];
  const float* b_gate = (const float*)d_in[8];
  const float* w1     = (const float*)d_in[9];
  const float* b1     = (const float*)d_in[10];
  const float* w2     = (const float*)d_in[11];
  const float* b2     = (const float*)d_in[12];
  const float* wp     = (const float*)d_in[13];
  const float* bp     = (const float*)d_in[14];
  float* out = (float*)d_out;

  char* ws = (char*)d_ws;
  const size_t MB = 1024 * 1024;
  bool full8 = ws_size >= (size_t)198 * MB;   // room for 128MB bf16 w1+w2

  // Residents:
  u16*   XN1h = (u16*)  (ws + 0*MB);    // 4MB  rms1 hi  (dead after QKV gemm)
  u16*   XN1l = (u16*)  (ws + 4*MB);    // 4MB  rms1 lo
  u16*   XG   = (u16*)  (ws + 0*MB);    // 8MB  (overlay XN1h/l; written at gather)
  float* X1   = (float*)(ws + 8*MB);    // 8MB  alive till combine
  float* XN2F = (float*)(ws + 16*MB);   // 8MB  dead after gating
  u16*   XN2B = (u16*)  (ws + 32*MB);   // 4MB
  u16*   HB   = (u16*)  (ws + 36*MB);   // 32MB [36,68)
  float* PPART= (float*)(ws + 68*MB);   // 64MB [68,132) wp partials (after MLP)
  u16*   WT1  = (u16*)  (ws + 68*MB);   // w1 bf16: 64MB full8 / 32MB halves
  u16*   WT2  = (u16*)  (ws + (full8 ? 132 : 100)*MB);  // w2 bf16
  // Attention-phase overlays (dead before MoE):
  float* QKV  = (float*)(ws + 36*MB);   // 24MB (inside HB)
  float* Qf   = (float*)(ws + 60*MB);   // 8MB  (inside HB)
  float* Vf   = (float*)(ws + 68*MB);   // 8MB
  u16*   Khg  = (u16*)  (ws + 76*MB);   // 4MB
  u16*   Klg  = (u16*)  (ws + 80*MB);   // 4MB
  u16*   Vth  = (u16*)  (ws + 84*MB);   // 4MB
  u16*   Vtl  = (u16*)  (ws + 88*MB);   // 4MB
  u16*   Obh  = (u16*)  (ws + 92*MB);   // 4MB attn out hi
  u16*   Obl  = (u16*)  (ws + 96*MB);   // 4MB attn out lo
  u16*   Wqh  = (u16*)  (ws + 100*MB);  // 6MB
  u16*   Wql  = (u16*)  (ws + 106*MB);  // 6MB
  u16*   Woh  = (u16*)  (ws + 112*MB);  // 2MB
  u16*   Wol  = (u16*)  (ws + 114*MB);  // 2MB
  char*  GT   = ws + (full8 ? 196 : 132)*MB;
  int*   top_idx = (int*)  (GT);
  float* gate_w  = (float*)(GT + 16*1024);
  int*   slot_of = (int*)  (GT + 32*1024);
  int*   counts  = (int*)  (GT + 48*1024);
  int*   offs    = (int*)  (GT + 48*1024 + 64);
  int*   cursor  = (int*)  (GT + 48*1024 + 128);
  float* trig    = (float*)(GT + 64*1024);

  const size_t KN = (size_t)1024 * 4096;

  hipMemsetAsync(counts, 0, 32, stream);
  tb_trig<<<1024, 32, 0, stream>>>(trig);
  tb_wsplit<1><<<dim3(48,16,1), 256, 0, stream>>>(w_qkv, Wqh, Wql, 1024, 3072);
  tb_wsplit<1><<<dim3(16,16,1), 256, 0, stream>>>(w_out, Woh, Wol, 1024, 1024);
  tb_rms_hl<<<2048, 256, 0, stream>>>(x, scale1, XN1h, XN1l);
  tb_gemm_sp2<0><<<dim3(24,16), 256, 0, stream>>>(XN1h, XN1l, Wqh, Wql, b_qkv, nullptr, QKV, 2048, 3072, 1024);
  tb_rope2<<<2048, 256, 0, stream>>>(QKV, trig, Qf, Khg, Klg, Vf);
  tb_vt<<<dim3(16,32), 256, 0, stream>>>(Vf, Vth, Vtl);
  tb_attn_mfma<<<dim3(16,32), 256, 0, stream>>>(Qf, Khg, Klg, Vth, Vtl, Obh, Obl);
  tb_gemm_sp2<1><<<dim3(8,16), 256, 0, stream>>>(Obh, Obl, Woh, Wol, b_out, x, X1, 2048, 1024, 1024);
  tb_rms<<<2048, 256, 0, stream>>>(X1, scale2, XN2F, XN2B);
  tb_gating<<<2048, 64, 0, stream>>>(XN2F, w_gate, b_gate, top_idx, gate_w, counts);
  tb_scan<<<1, 64, 0, stream>>>(counts, offs, cursor, out + (size_t)NTOK*DMODEL);
  tb_gather<<<2048, 128, 0, stream>>>(XN2B, top_idx, cursor, slot_of, XG);
  // MoE MLP: pre-convert w1/w2 to [n][k] bf16, then multi-phase fused GEMM.
  if (full8) {
    tb_wsplit<0><<<dim3(64,16,8), 256, 0, stream>>>(w1, WT1, nullptr, 1024, 4096);
    tb_wsplit<0><<<dim3(64,16,8), 256, 0, stream>>>(w2, WT2, nullptr, 1024, 4096);
    tb_moe_mlp8<<<dim3(32,16,8), 512, 0, stream>>>(XG, WT1, WT2, b1, b2, HB, counts, offs, 0);
  } else {
    tb_wsplit<0><<<dim3(64,16,4), 256, 0, stream>>>(w1, WT1, nullptr, 1024, 4096);
    tb_wsplit<0><<<dim3(64,16,4), 256, 0, stream>>>(w2, WT2, nullptr, 1024, 4096);
    tb_moe_mlp8<<<dim3(32,16,4), 512, 0, stream>>>(XG, WT1, WT2, b1, b2, HB, counts, offs, 0);
    tb_wsplit<0><<<dim3(64,16,4), 256, 0, stream>>>(w1 + 4*KN, WT1, nullptr, 1024, 4096);
    tb_wsplit<0><<<dim3(64,16,4), 256, 0, stream>>>(w2 + 4*KN, WT2, nullptr, 1024, 4096);
    tb_moe_mlp8<<<dim3(32,16,4), 512, 0, stream>>>(XG, WT1, WT2, b1, b2, HB, counts, offs, 4);
  }
  // Down-projection: split-K=4 partials (f32 weights read directly).
  tb_moe_wp<<<dim3(8,16,32), 256, 0, stream>>>(HB, wp, PPART, counts, offs);
  tb_combine<<<2048, 256, 0, stream>>>(X1, PPART, slot_of, top_idx, gate_w, bp, out);
}

// Round 13
// 590.633 us; speedup vs baseline: 1.1055x; 1.0142x over previous
//
#include <hip/hip_runtime.h>
#include <math.h>

typedef unsigned short u16;
typedef unsigned int   u32;
typedef float f32x4 __attribute__((ext_vector_type(4)));
typedef __bf16 bf16x8 __attribute__((ext_vector_type(8)));

#define T_LEN  1024
#define DMODEL 1024
#define NTOK   2048
#define NHEAD  16
#define HDIM   64
#define NEXP   8
#define FFDIM  4096

#define VMW(n)   asm volatile("s_waitcnt vmcnt(" #n ")" ::: "memory")
#define LGKM0()  asm volatile("s_waitcnt lgkmcnt(0)" ::: "memory")
#define SBAR()   __builtin_amdgcn_s_barrier()
#define SCHED0() __builtin_amdgcn_sched_barrier(0)
#define PRIO(n)  __builtin_amdgcn_s_setprio(n)

__device__ __forceinline__ u16 f2bf(float f) {          // RNE
  union { float f; u32 u; } v; v.f = f;
  u32 r = v.u + 0x7FFFu + ((v.u >> 16) & 1u);
  return (u16)(r >> 16);
}
__device__ __forceinline__ float bf2f(u16 h) {
  union { u32 u; float f; } v; v.u = ((u32)h) << 16; return v.f;
}

// async 16B global->LDS (wave-uniform LDS base; HW adds lane*16)
__device__ __forceinline__ void g2l16(const u16* src, u16* ldsbase) {
  __builtin_amdgcn_global_load_lds(
      (const __attribute__((address_space(1))) void*)src,
      (__attribute__((address_space(3))) void*)ldsbase, 16, 0, 0);
}

// split 16 f32 -> 8 packed u32 hi + 8 packed u32 lo
__device__ __forceinline__ void split16(const float* src, u32* H, u32* L) {
  #pragma unroll
  for (int j = 0; j < 8; ++j) {
    float a = src[2*j], b = src[2*j+1];
    u16 ha = f2bf(a), hb = f2bf(b);
    u16 la = f2bf(a - bf2f(ha)), lb = f2bf(b - bf2f(hb));
    H[j] = (u32)ha | ((u32)hb << 16);
    L[j] = (u32)la | ((u32)lb << 16);
  }
}

// ---------------- RMSNorm -> hi/lo bf16 split (for GEMM A-operand) ---------
__global__ __launch_bounds__(256) void tb_rms_hl(const float* __restrict__ x,
    const float* __restrict__ scale, u16* __restrict__ oh, u16* __restrict__ ol) {
  int t = blockIdx.x, tid = threadIdx.x;
  const float* xr = x + (size_t)t * DMODEL;
  float4 v = *(const float4*)(xr + tid * 4);
  double ss = (double)v.x*v.x + (double)v.y*v.y + (double)v.z*v.z + (double)v.w*v.w;
  #pragma unroll
  for (int off = 32; off; off >>= 1) ss += __shfl_xor(ss, off);
  __shared__ double red[4];
  if ((tid & 63) == 0) red[tid >> 6] = ss;
  __syncthreads();
  double denom = sqrt((red[0]+red[1]+red[2]+red[3]) / (double)DMODEL) + 1e-5;
  float4 sc = *(const float4*)(scale + tid * 4);
  float y[4];
  y[0] = (float)((double)v.x / denom * (double)sc.x);
  y[1] = (float)((double)v.y / denom * (double)sc.y);
  y[2] = (float)((double)v.z / denom * (double)sc.z);
  y[3] = (float)((double)v.w / denom * (double)sc.w);
  u16* ph = oh + (size_t)t*DMODEL + tid*4;
  u16* pl = ol + (size_t)t*DMODEL + tid*4;
  #pragma unroll
  for (int j = 0; j < 4; ++j) {
    u16 h = f2bf(y[j]);
    ph[j] = h;
    pl[j] = f2bf(y[j] - bf2f(h));
  }
}

// ---------------- RMSNorm (f64 accumulate; f32 + bf16 outputs) -------------
__global__ __launch_bounds__(256) void tb_rms(const float* __restrict__ x,
    const float* __restrict__ scale, float* __restrict__ out_f, u16* __restrict__ out_b) {
  int t = blockIdx.x, tid = threadIdx.x;
  const float* xr = x + (size_t)t * DMODEL;
  float4 v = *(const float4*)(xr + tid * 4);
  double ss = (double)v.x*v.x + (double)v.y*v.y + (double)v.z*v.z + (double)v.w*v.w;
  #pragma unroll
  for (int off = 32; off; off >>= 1) ss += __shfl_xor(ss, off);
  __shared__ double red[4];
  if ((tid & 63) == 0) red[tid >> 6] = ss;
  __syncthreads();
  double denom = sqrt((red[0]+red[1]+red[2]+red[3]) / (double)DMODEL) + 1e-5;
  float4 sc = *(const float4*)(scale + tid * 4);
  float y0 = (float)((double)v.x / denom * (double)sc.x);
  float y1 = (float)((double)v.y / denom * (double)sc.y);
  float y2 = (float)((double)v.z / denom * (double)sc.z);
  float y3 = (float)((double)v.w / denom * (double)sc.w);
  *(float4*)(out_f + (size_t)t*DMODEL + tid*4) = make_float4(y0,y1,y2,y3);
  u16* ob = out_b + (size_t)t*DMODEL + tid*4;
  ob[0]=f2bf(y0); ob[1]=f2bf(y1); ob[2]=f2bf(y2); ob[3]=f2bf(y3);
}

// ------- weight pre-split+transpose: W[k][n] f32 -> Wt[n][k] bf16 (hi[,lo]) -
template<int HILO>
__global__ __launch_bounds__(256) void tb_wsplit(const float* __restrict__ W,
    u16* __restrict__ Wh, u16* __restrict__ Wl, int K, int N) {
  __shared__ float Tf[64*68];
  size_t eo = (size_t)blockIdx.z * (size_t)K * N;
  const float* Wb = W + eo;
  int n0 = blockIdx.x*64, k0 = blockIdx.y*64;
  int tid = threadIdx.x;
  int r = tid >> 2, c = tid & 3;
  const float* wp = Wb + (size_t)(k0+r)*N + n0 + c*16;
  float vv[16];
  *(float4*)&vv[0]  = ((const float4*)wp)[0];
  *(float4*)&vv[4]  = ((const float4*)wp)[1];
  *(float4*)&vv[8]  = ((const float4*)wp)[2];
  *(float4*)&vv[12] = ((const float4*)wp)[3];
  #pragma unroll
  for (int j = 0; j < 16; ++j) Tf[(c*16+j)*68 + r] = vv[j];
  __syncthreads();
  int n = tid >> 2, kc = tid & 3;
  float tv[16];
  #pragma unroll
  for (int j = 0; j < 16; ++j) tv[j] = Tf[n*68 + kc*16 + j];
  u32 H[8], L[8];
  split16(tv, H, L);
  u16* oh = Wh + eo + (size_t)(n0+n)*K + k0 + kc*16;
  *(uint4*)oh       = make_uint4(H[0],H[1],H[2],H[3]);
  *(uint4*)(oh + 8) = make_uint4(H[4],H[5],H[6],H[7]);
  if (HILO) {
    u16* ol = Wl + eo + (size_t)(n0+n)*K + k0 + kc*16;
    *(uint4*)ol       = make_uint4(L[0],L[1],L[2],L[3]);
    *(uint4*)(ol + 8) = make_uint4(L[4],L[5],L[6],L[7]);
  }
}

// --- split-bf16 MFMA GEMM, all operands via global_load_lds ----------------
// Depth-2 counted-vmcnt dbuf (64KB LDS -> 2 blocks/CU co-residency).
template<int RESID>
__global__ __launch_bounds__(256) void tb_gemm_sp2(const u16* __restrict__ Ahg,
    const u16* __restrict__ Alg, const u16* __restrict__ Bhg,
    const u16* __restrict__ Blg, const float* __restrict__ bias,
    const float* __restrict__ resid, float* __restrict__ C,
    int M, int N, int K) {
  __shared__ __align__(16) u16 Ah[2][128*32], Al[2][128*32];
  __shared__ __align__(16) u16 Bh[2][128*32], Bl[2][128*32];   // 64KB total
  int tid = threadIdx.x;
  int row0 = blockIdx.y * 128, col0 = blockIdx.x * 128;
  int lane = tid & 63, wave = tid >> 6;
  int wm = wave >> 1, wn = wave & 1;
  int l15 = lane & 15, l4 = lane >> 4;
  int sw = (l15 >> 1) & 3;
  int ci0 = ((wave*2+0)<<6)+lane, ci1 = ((wave*2+1)<<6)+lane;
  int r0 = ci0 >> 2, c0 = ((ci0 & 3) ^ ((r0 >> 1) & 3)) << 3;
  int r1 = ci1 >> 2, c1 = ((ci1 & 3) ^ ((r1 >> 1) & 3)) << 3;
  int lo0 = (wave*2+0) << 9, lo1 = (wave*2+1) << 9;
  f32x4 zero = {0.f,0.f,0.f,0.f};
  f32x4 acc[4][4];
  #pragma unroll
  for (int i=0;i<4;++i) for (int j=0;j<4;++j) acc[i][j] = zero;
  const int nt = K / 32;

  #define SP2_STAGE(b, k0) do { \
    g2l16(Ahg + (size_t)(row0+r0)*K + (k0) + c0, &Ah[b][lo0]); \
    g2l16(Ahg + (size_t)(row0+r1)*K + (k0) + c1, &Ah[b][lo1]); \
    g2l16(Alg + (size_t)(row0+r0)*K + (k0) + c0, &Al[b][lo0]); \
    g2l16(Alg + (size_t)(row0+r1)*K + (k0) + c1, &Al[b][lo1]); \
    g2l16(Bhg + (size_t)(col0+r0)*K + (k0) + c0, &Bh[b][lo0]); \
    g2l16(Bhg + (size_t)(col0+r1)*K + (k0) + c1, &Bh[b][lo1]); \
    g2l16(Blg + (size_t)(col0+r0)*K + (k0) + c0, &Bl[b][lo0]); \
    g2l16(Blg + (size_t)(col0+r1)*K + (k0) + c1, &Bl[b][lo1]); } while(0)

  SP2_STAGE(0, 0);
  SP2_STAGE(1, 32);
  for (int t = 0; t < nt; ++t) {
    int cur = t & 1;
    if (t + 1 < nt) { VMW(8); } else { VMW(0); }
    SBAR(); SCHED0();
    bf16x8 ah[4], al_[4], bh_[4], bl_[4];
    #pragma unroll
    for (int mi = 0; mi < 4; ++mi) {
      int ro = (wm*64 + mi*16 + l15) << 5;
      ah[mi]  = *(const bf16x8*)(&Ah[cur][ro + ((l4 ^ sw) << 3)]);
      al_[mi] = *(const bf16x8*)(&Al[cur][ro + ((l4 ^ sw) << 3)]);
    }
    #pragma unroll
    for (int ni = 0; ni < 4; ++ni) {
      int ro = (wn*64 + ni*16 + l15) << 5;
      bh_[ni] = *(const bf16x8*)(&Bh[cur][ro + ((l4 ^ sw) << 3)]);
      bl_[ni] = *(const bf16x8*)(&Bl[cur][ro + ((l4 ^ sw) << 3)]);
    }
    PRIO(1);
    #pragma unroll
    for (int mi = 0; mi < 4; ++mi)
      #pragma unroll
      for (int ni = 0; ni < 4; ++ni) {
        acc[mi][ni] = __builtin_amdgcn_mfma_f32_16x16x32_bf16(ah[mi], bh_[ni], acc[mi][ni], 0,0,0);
        acc[mi][ni] = __builtin_amdgcn_mfma_f32_16x16x32_bf16(ah[mi], bl_[ni], acc[mi][ni], 0,0,0);
        acc[mi][ni] = __builtin_amdgcn_mfma_f32_16x16x32_bf16(al_[mi], bh_[ni], acc[mi][ni], 0,0,0);
      }
    PRIO(0);
    if (t + 1 < nt) {
      SBAR();
      if (t + 2 < nt) SP2_STAGE(cur, (t+2)*32);
    }
  }
  #undef SP2_STAGE
  #pragma unroll
  for (int mi = 0; mi < 4; ++mi)
    #pragma unroll
    for (int r = 0; r < 4; ++r) {
      int row = row0 + wm*64 + mi*16 + l4*4 + r;
      #pragma unroll
      for (int ni = 0; ni < 4; ++ni) {
        int col = col0 + wn*64 + ni*16 + l15;
        float vv = acc[mi][ni][r] + bias[col];
        if (RESID) vv += resid[(size_t)row*N + col];
        C[(size_t)row*N + col] = vv;
      }
    }
}

// ---------------- RoPE trig table (f64) ------------------------------------
__global__ void tb_trig(float* __restrict__ tab) {
  int t = blockIdx.x, d = threadIdx.x;
  double theta = pow(10000.0, -(double)d / 32.0);
  double ang = (double)t * theta;
  tab[(t*32 + d)*2 + 0] = (float)cos(ang);
  tab[(t*32 + d)*2 + 1] = (float)sin(ang);
}

// ---------------- qkv -> Q f32, K bf16 hi/lo (all [bh][t][d]), V f32 -------
__global__ __launch_bounds__(256) void tb_rope2(const float* __restrict__ qkv,
    const float* __restrict__ tab, float* __restrict__ Qf, u16* __restrict__ Khg,
    u16* __restrict__ Klg, float* __restrict__ Vf) {
  int n = blockIdx.x;
  int b = n >> 10, t = n & 1023;
  const float* src = qkv + (size_t)n * 3072;
  for (int idx = threadIdx.x; idx < 512; idx += 256) {
    int h = idx >> 5, d = idx & 31;
    float ca = tab[(t*32+d)*2], sa = tab[(t*32+d)*2+1];
    size_t base = ((size_t)(b*NHEAD + h) * T_LEN + t) * HDIM;
    { float x1 = src[h*64 + d], x2 = src[h*64 + d + 32];
      Qf[base + d]      = x1*ca - x2*sa;
      Qf[base + d + 32] = x1*sa + x2*ca; }
    { float x1 = src[1024 + h*64 + d], x2 = src[1024 + h*64 + d + 32];
      float k1 = x1*ca - x2*sa, k2 = x1*sa + x2*ca;
      u16 h1 = f2bf(k1), h2 = f2bf(k2);
      Khg[base + d] = h1;      Khg[base + d + 32] = h2;
      Klg[base + d] = f2bf(k1 - bf2f(h1));
      Klg[base + d + 32] = f2bf(k2 - bf2f(h2)); }
  }
  for (int c = threadIdx.x; c < 1024; c += 256) {
    int h = c >> 6, d = c & 63;
    Vf[((size_t)(b*NHEAD + h) * T_LEN + t) * HDIM + d] = src[2048 + c];
  }
}

// ---------------- V transpose+split: [bh][t][d] f32 -> [bh][d][t] bf16 -----
__global__ __launch_bounds__(256) void tb_vt(const float* __restrict__ Vf,
    u16* __restrict__ Vh, u16* __restrict__ Vl) {
  __shared__ float Tf[64*68];
  int t0 = blockIdx.x * 64, bh = blockIdx.y;
  const float* Vb = Vf + (size_t)bh * (T_LEN*HDIM);
  int tid = threadIdx.x, r = tid >> 2, c = tid & 3;
  const float* vp = Vb + (size_t)(t0+r)*HDIM + c*16;
  float vv[16];
  *(float4*)&vv[0]  = ((const float4*)vp)[0];
  *(float4*)&vv[4]  = ((const float4*)vp)[1];
  *(float4*)&vv[8]  = ((const float4*)vp)[2];
  *(float4*)&vv[12] = ((const float4*)vp)[3];
  #pragma unroll
  for (int j = 0; j < 16; ++j) Tf[(c*16+j)*68 + r] = vv[j];
  __syncthreads();
  int d = tid >> 2, tc = tid & 3;
  float tv[16];
  #pragma unroll
  for (int j = 0; j < 16; ++j) tv[j] = Tf[d*68 + tc*16 + j];
  u32 H[8], L[8];
  split16(tv, H, L);
  u16* oh = Vh + (size_t)bh*(HDIM*T_LEN) + (size_t)d*T_LEN + t0 + tc*16;
  u16* ol = Vl + (size_t)bh*(HDIM*T_LEN) + (size_t)d*T_LEN + t0 + tc*16;
  *(uint4*)oh       = make_uint4(H[0],H[1],H[2],H[3]);
  *(uint4*)(oh + 8) = make_uint4(H[4],H[5],H[6],H[7]);
  *(uint4*)ol       = make_uint4(L[0],L[1],L[2],L[3]);
  *(uint4*)(ol + 8) = make_uint4(L[4],L[5],L[6],L[7]);
}

// ---------------- MFMA flash attention; writes O as hi/lo bf16 split -------
__global__ __launch_bounds__(256) void tb_attn_mfma(const float* __restrict__ Qf,
    const u16* __restrict__ Khg, const u16* __restrict__ Klg,
    const u16* __restrict__ Vhg, const u16* __restrict__ Vlg,
    u16* __restrict__ Obh, u16* __restrict__ Obl) {
  __shared__ __align__(16) u16 Kh[64*72], Kl[64*72];
  __shared__ __align__(16) u16 Vh[64*72], Vl[64*72];
  __shared__ __align__(16) u16 Ph[64*72], Pl[64*72];
  int qt = blockIdx.x, bh = blockIdx.y;
  int tid = threadIdx.x, lane = tid & 63, w = tid >> 6;
  int l15 = lane & 15, l4 = lane >> 4;
  int b = bh >> 4, h = bh & 15;
  const float* Qb = Qf + (size_t)bh * (T_LEN*HDIM);
  const u16* Khb = Khg + (size_t)bh * (T_LEN*HDIM);
  const u16* Klb = Klg + (size_t)bh * (T_LEN*HDIM);
  const u16* Vhb = Vhg + (size_t)bh * (HDIM*T_LEN);
  const u16* Vlb = Vlg + (size_t)bh * (HDIM*T_LEN);
  int q0 = qt * 64;
  int qrow = q0 + w*16 + l15;
  bf16x8 qh[2], ql[2];
  #pragma unroll
  for (int ks = 0; ks < 2; ++ks) {
    const float* qp = Qb + (size_t)qrow*HDIM + ks*32 + l4*8;
    float vv[8];
    *(float4*)&vv[0] = ((const float4*)qp)[0];
    *(float4*)&vv[4] = ((const float4*)qp)[1];
    u32 H[4], L[4];
    #pragma unroll
    for (int j = 0; j < 4; ++j) {
      float a = vv[2*j], bb = vv[2*j+1];
      u16 ha = f2bf(a), hb = f2bf(bb);
      u16 la = f2bf(a - bf2f(ha)), lb = f2bf(bb - bf2f(hb));
      H[j] = (u32)ha | ((u32)hb << 16);
      L[j] = (u32)la | ((u32)lb << 16);
    }
    union { uint4 u; bf16x8 b; } th, tl;
    th.u = make_uint4(H[0],H[1],H[2],H[3]);
    tl.u = make_uint4(L[0],L[1],L[2],L[3]);
    qh[ks] = th.b; ql[ks] = tl.b;
  }
  int qg[4];
  #pragma unroll
  for (int r = 0; r < 4; ++r) qg[r] = q0 + w*16 + l4*4 + r;
  float mrow[4], lrow[4];
  f32x4 oacc[4];
  f32x4 zero = {0.f,0.f,0.f,0.f};
  #pragma unroll
  for (int r = 0; r < 4; ++r) { mrow[r] = -1e30f; lrow[r] = 0.f; }
  #pragma unroll
  for (int d = 0; d < 4; ++d) oacc[d] = zero;

  int sr = tid >> 2, sc = tid & 3;
  for (int kt = 0; kt <= qt; ++kt) {
    int k0 = kt * 64;
    __syncthreads();
    {
      const u16* kp = Khb + (size_t)(k0+sr)*HDIM + sc*16;
      *(uint4*)(Kh + sr*72 + sc*16)     = ((const uint4*)kp)[0];
      *(uint4*)(Kh + sr*72 + sc*16 + 8) = ((const uint4*)kp)[1];
      const u16* kl2 = Klb + (size_t)(k0+sr)*HDIM + sc*16;
      *(uint4*)(Kl + sr*72 + sc*16)     = ((const uint4*)kl2)[0];
      *(uint4*)(Kl + sr*72 + sc*16 + 8) = ((const uint4*)kl2)[1];
      const u16* vp = Vhb + (size_t)sr*T_LEN + k0 + sc*16;
      *(uint4*)(Vh + sr*72 + sc*16)     = ((const uint4*)vp)[0];
      *(uint4*)(Vh + sr*72 + sc*16 + 8) = ((const uint4*)vp)[1];
      const u16* vl2 = Vlb + (size_t)sr*T_LEN + k0 + sc*16;
      *(uint4*)(Vl + sr*72 + sc*16)     = ((const uint4*)vl2)[0];
      *(uint4*)(Vl + sr*72 + sc*16 + 8) = ((const uint4*)vl2)[1];
    }
    __syncthreads();
    f32x4 sacc[4];
    #pragma unroll
    for (int ni = 0; ni < 4; ++ni) {
      sacc[ni] = zero;
      #pragma unroll
      for (int ks = 0; ks < 2; ++ks) {
        bf16x8 kh_ = *(const bf16x8*)(Kh + (ni*16 + l15)*72 + ks*32 + l4*8);
        bf16x8 kl_ = *(const bf16x8*)(Kl + (ni*16 + l15)*72 + ks*32 + l4*8);
        sacc[ni] = __builtin_amdgcn_mfma_f32_16x16x32_bf16(qh[ks], kh_, sacc[ni], 0,0,0);
        sacc[ni] = __builtin_amdgcn_mfma_f32_16x16x32_bf16(qh[ks], kl_, sacc[ni], 0,0,0);
        sacc[ni] = __builtin_amdgcn_mfma_f32_16x16x32_bf16(ql[ks], kh_, sacc[ni], 0,0,0);
      }
    }
    bool diag = (kt == qt);
    float sv[4][4];
    #pragma unroll
    for (int ni = 0; ni < 4; ++ni)
      #pragma unroll
      for (int r = 0; r < 4; ++r) {
        float s = sacc[ni][r] * 0.125f;
        if (diag && (k0 + ni*16 + l15 > qg[r])) s = -1e30f;
        sv[ni][r] = s;
      }
    float mt[4];
    #pragma unroll
    for (int r = 0; r < 4; ++r)
      mt[r] = fmaxf(fmaxf(sv[0][r], sv[1][r]), fmaxf(sv[2][r], sv[3][r]));
    #pragma unroll
    for (int off = 1; off < 16; off <<= 1)
      #pragma unroll
      for (int r = 0; r < 4; ++r) mt[r] = fmaxf(mt[r], __shfl_xor(mt[r], off));
    float al[4];
    #pragma unroll
    for (int r = 0; r < 4; ++r) {
      float mn = fmaxf(mrow[r], mt[r]);
      al[r] = expf(mrow[r] - mn);
      mrow[r] = mn;
    }
    float ls[4] = {0.f,0.f,0.f,0.f};
    #pragma unroll
    for (int ni = 0; ni < 4; ++ni)
      #pragma unroll
      for (int r = 0; r < 4; ++r) {
        float p = expf(sv[ni][r] - mrow[r]);
        u16 ph2 = f2bf(p);
        int qrl = w*16 + l4*4 + r;
        Ph[qrl*72 + ni*16 + l15] = ph2;
        Pl[qrl*72 + ni*16 + l15] = f2bf(p - bf2f(ph2));
        ls[r] += p;
      }
    #pragma unroll
    for (int off = 1; off < 16; off <<= 1)
      #pragma unroll
      for (int r = 0; r < 4; ++r) ls[r] += __shfl_xor(ls[r], off);
    #pragma unroll
    for (int r = 0; r < 4; ++r) lrow[r] = lrow[r]*al[r] + ls[r];
    #pragma unroll
    for (int d = 0; d < 4; ++d)
      #pragma unroll
      for (int r = 0; r < 4; ++r) oacc[d][r] *= al[r];
    bf16x8 ph_[2], pl_[2];
    #pragma unroll
    for (int ks = 0; ks < 2; ++ks) {
      ph_[ks] = *(const bf16x8*)(Ph + (w*16 + l15)*72 + ks*32 + l4*8);
      pl_[ks] = *(const bf16x8*)(Pl + (w*16 + l15)*72 + ks*32 + l4*8);
    }
    #pragma unroll
    for (int dblk = 0; dblk < 4; ++dblk)
      #pragma unroll
      for (int ks = 0; ks < 2; ++ks) {
        bf16x8 vh_ = *(const bf16x8*)(Vh + (dblk*16 + l15)*72 + ks*32 + l4*8);
        bf16x8 vl_ = *(const bf16x8*)(Vl + (dblk*16 + l15)*72 + ks*32 + l4*8);
        oacc[dblk] = __builtin_amdgcn_mfma_f32_16x16x32_bf16(ph_[ks], vh_, oacc[dblk], 0,0,0);
        oacc[dblk] = __builtin_amdgcn_mfma_f32_16x16x32_bf16(ph_[ks], vl_, oacc[dblk], 0,0,0);
        oacc[dblk] = __builtin_amdgcn_mfma_f32_16x16x32_bf16(pl_[ks], vh_, oacc[dblk], 0,0,0);
      }
  }
  #pragma unroll
  for (int dblk = 0; dblk < 4; ++dblk)
    #pragma unroll
    for (int r = 0; r < 4; ++r) {
      int q = qg[r];
      int d = dblk*16 + l15;
      float ov = oacc[dblk][r] / lrow[r];
      u16 hh = f2bf(ov);
      size_t oi = ((size_t)b * T_LEN + q) * DMODEL + h * HDIM + d;
      Obh[oi] = hh;
      Obl[oi] = f2bf(ov - bf2f(hh));
    }
}

// ---------------- router: f64 logits, top-2 --------------------------------
__global__ __launch_bounds__(64) void tb_gating(const float* __restrict__ xn2,
    const float* __restrict__ wg, const float* __restrict__ bg,
    int* __restrict__ top_idx, float* __restrict__ gate_w, int* __restrict__ counts) {
  int t = blockIdx.x, lane = threadIdx.x;
  const float* xr = xn2 + (size_t)t * DMODEL;
  double part[8];
  #pragma unroll
  for (int e = 0; e < 8; ++e) part[e] = 0.0;
  for (int i = lane; i < DMODEL; i += 64) {
    double xv = (double)xr[i];
    const float* wr = wg + (size_t)i * 8;
    #pragma unroll
    for (int e = 0; e < 8; ++e) part[e] += xv * (double)wr[e];
  }
  #pragma unroll
  for (int e = 0; e < 8; ++e)
    for (int off = 32; off; off >>= 1) part[e] += __shfl_xor(part[e], off);
  if (lane == 0) {
    double lg[8];
    for (int e = 0; e < 8; ++e) lg[e] = part[e] + (double)bg[e];
    int i1 = 0;
    for (int e = 1; e < 8; ++e) if (lg[e] > lg[i1]) i1 = e;
    int i2 = (i1 == 0) ? 1 : 0;
    for (int e = 0; e < 8; ++e) if (e != i1 && lg[e] > lg[i2]) i2 = e;
    double e2 = exp(lg[i2] - lg[i1]);
    double den = 1.0 + e2;
    top_idx[t*2] = i1; top_idx[t*2+1] = i2;
    gate_w[t*2] = (float)(1.0/den); gate_w[t*2+1] = (float)(e2/den);
    atomicAdd(&counts[i1], 1); atomicAdd(&counts[i2], 1);
  }
}

__global__ void tb_scan(const int* __restrict__ counts, int* __restrict__ offs,
    int* __restrict__ cursor, float* __restrict__ aux_out) {
  if (threadIdx.x == 0) {
    int off = 0; float aux = 0.f;
    for (int e = 0; e < 8; ++e) {
      offs[e] = off; cursor[e] = off; off += counts[e];
      float fr = (float)counts[e] / 4096.0f - 0.125f;
      aux += fr * fr;
    }
    aux_out[0] = aux;
  }
}

__global__ __launch_bounds__(128) void tb_gather(const u16* __restrict__ xn2b,
    const int* __restrict__ top_idx, int* __restrict__ cursor,
    int* __restrict__ slot_of, u16* __restrict__ Xg) {
  int t = blockIdx.x;
  __shared__ int sl[2];
  if (threadIdx.x < 2) {
    int e = top_idx[t*2 + threadIdx.x];
    int s = atomicAdd(&cursor[e], 1);
    sl[threadIdx.x] = s;
    slot_of[t*2 + threadIdx.x] = s;
  }
  __syncthreads();
  uint4 v = *(const uint4*)(xn2b + (size_t)t * DMODEL + threadIdx.x * 8);
  *(uint4*)(Xg + (size_t)sl[0] * DMODEL + threadIdx.x * 8) = v;
  *(uint4*)(Xg + (size_t)sl[1] * DMODEL + threadIdx.x * 8) = v;
}

// --- fused MoE MLP, ring-4 counted-vmcnt, ONE merged phase per K32 unit ----
// 256m x 128n tile, 8 waves. Per unit: {VMW(8) counted, SBAR, 12 ds_reads ||
// stage(u+3), 32-MFMA setprio cluster, SBAR}. Loads never drain.
__global__ __launch_bounds__(512, 1) void tb_moe_mlp8(const u16* __restrict__ Ag,
    const u16* __restrict__ B1t, const u16* __restrict__ B2t,
    const float* __restrict__ b1g, const float* __restrict__ b2g,
    u16* __restrict__ Hout, const int* __restrict__ counts,
    const int* __restrict__ offs, int ebase) {
  const int K = DMODEL, N = FFDIM;
  int ez = blockIdx.z, e = ebase + ez;
  int cnt = counts[e];
  if ((int)blockIdx.y * 256 >= cnt) return;
  int row0 = offs[e] + blockIdx.y * 256;
  int rend = offs[e] + cnt;
  int col0 = blockIdx.x * 128;
  const u16* B1 = B1t + (size_t)ez * K * N;
  const u16* B2 = B2t + (size_t)ez * K * N;
  const float* bb1 = b1g + (size_t)e * N;
  const float* bb2 = b2g + (size_t)e * N;
  __shared__ __align__(16) u16 As[4][256*32];    // 64KB
  __shared__ __align__(16) u16 Bs1[4][128*32];   // 32KB
  __shared__ __align__(16) u16 Bs2[4][128*32];   // 32KB
  int tid = threadIdx.x, lane = tid & 63, wave = tid >> 6;  // 8 waves
  int wm = wave >> 1, wn = wave & 1;
  int l15 = lane & 15, l4 = lane >> 4;
  int sw = (l15 >> 1) & 3;
  int ai0 = ((wave*2+0)<<6) + lane, ai1 = ((wave*2+1)<<6) + lane;
  int ar0 = ai0 >> 2, ac0 = ((ai0 & 3) ^ ((ar0 >> 1) & 3)) << 3;
  int ar1 = ai1 >> 2, ac1 = ((ai1 & 3) ^ ((ar1 >> 1) & 3)) << 3;
  int ga0 = row0 + ar0 < rend ? row0 + ar0 : rend - 1;
  int ga1 = row0 + ar1 < rend ? row0 + ar1 : rend - 1;
  int alo0 = (wave*2+0) << 9, alo1 = (wave*2+1) << 9;
  int bi = (wave << 6) + lane;
  int br = bi >> 2, bc = ((bi & 3) ^ ((br >> 1) & 3)) << 3;
  int blo = wave << 9;
  f32x4 zero = {0.f,0.f,0.f,0.f};
  f32x4 acc1[4][4], acc2[4][4];
  #pragma unroll
  for (int i=0;i<4;++i) for (int j=0;j<4;++j) { acc1[i][j] = zero; acc2[i][j] = zero; }

  #define M8_STAGE(b, k0) do { \
    g2l16(Ag + (size_t)ga0*K + (k0) + ac0, &As[b][alo0]); \
    g2l16(Ag + (size_t)ga1*K + (k0) + ac1, &As[b][alo1]); \
    g2l16(B1 + (size_t)(col0+br)*K + (k0) + bc, &Bs1[b][blo]); \
    g2l16(B2 + (size_t)(col0+br)*K + (k0) + bc, &Bs2[b][blo]); } while(0)

  // prologue: units 0,1,2 (4 loads/wave each -> 12 outstanding)
  M8_STAGE(0, 0);
  M8_STAGE(1, 32);
  M8_STAGE(2, 64);
  const int NT = K / 32;   // 32 units
  for (int u = 0; u < NT; ++u) {
    int buf = u & 3;
    if (u + 2 < NT) { VMW(8); } else if (u + 1 < NT) { VMW(4); } else { VMW(0); }
    SBAR(); SCHED0();                       // unit u landed for ALL waves
    bf16x8 af[4], bf1[4], bf2[4];
    #pragma unroll
    for (int mi = 0; mi < 4; ++mi)
      af[mi] = *(const bf16x8*)(&As[buf][((wm*64 + mi*16 + l15) << 5) + ((l4 ^ sw) << 3)]);
    #pragma unroll
    for (int ni = 0; ni < 4; ++ni) {
      bf1[ni] = *(const bf16x8*)(&Bs1[buf][((wn*64 + ni*16 + l15) << 5) + ((l4 ^ sw) << 3)]);
      bf2[ni] = *(const bf16x8*)(&Bs2[buf][((wn*64 + ni*16 + l15) << 5) + ((l4 ^ sw) << 3)]);
    }
    if (u + 3 < NT) M8_STAGE((u+3) & 3, (u+3)*32);   // buf[(u-1)&3]: readers sealed by tail SBAR(u-1)+top SBAR(u)
    PRIO(1);
    #pragma unroll
    for (int mi = 0; mi < 4; ++mi)
      #pragma unroll
      for (int ni = 0; ni < 4; ++ni)
        acc1[mi][ni] = __builtin_amdgcn_mfma_f32_16x16x32_bf16(af[mi], bf1[ni], acc1[mi][ni], 0,0,0);
    #pragma unroll
    for (int mi = 0; mi < 4; ++mi)
      #pragma unroll
      for (int ni = 0; ni < 4; ++ni)
        acc2[mi][ni] = __builtin_amdgcn_mfma_f32_16x16x32_bf16(af[mi], bf2[ni], acc2[mi][ni], 0,0,0);
    PRIO(0);
    SBAR();
  }
  #undef M8_STAGE
  #pragma unroll
  for (int mi = 0; mi < 4; ++mi) {
    #pragma unroll
    for (int r = 0; r < 4; ++r) {
      int row = row0 + wm*64 + mi*16 + l4*4 + r;
      if (row >= rend) continue;
      #pragma unroll
      for (int ni = 0; ni < 4; ++ni) {
        int col = col0 + wn*64 + ni*16 + l15;
        float v1 = acc1[mi][ni][r] + bb1[col];
        float v2 = acc2[mi][ni][r] + bb2[col];
        float hv = (v1 / (1.f + expf(-v1))) * v2;
        Hout[(size_t)row * N + col] = f2bf(hv);
      }
    }
  }
}

// --- MoE down-proj, split-K=4, in-kernel f32 convert, counted waits --------
// B scalar-loads issued BEFORE A glds -> VMW(2) waits only B-regs (A stays
// in flight, landed by next iter's cheap VMW(0)). No mid-loop full drain.
__global__ __launch_bounds__(256) void tb_moe_wp(const u16* __restrict__ Ag,
    const float* __restrict__ Wp, float* __restrict__ Pout,
    const int* __restrict__ counts, const int* __restrict__ offs) {
  const int K = FFDIM, N = DMODEL;
  int e = blockIdx.z & 7, ks = blockIdx.z >> 3;
  int cnt = counts[e];
  if ((int)blockIdx.y * 128 >= cnt) return;
  int row0 = offs[e] + blockIdx.y * 128;
  int rend = offs[e] + cnt;
  int col0 = blockIdx.x * 128;
  int kbase = ks * 1024;
  const float* Bw = Wp + (size_t)e * K * N;
  float* out = Pout + (size_t)ks * (4096u*1024u);
  __shared__ __align__(16) u16 As[2][128*32], Bs[2][128*32];
  int tid = threadIdx.x, lane = tid & 63, wave = tid >> 6;
  int wm = wave >> 1, wn = wave & 1;
  int l15 = lane & 15, l4 = lane >> 4;
  int sw = (l15 >> 1) & 3;
  int ci0 = ((wave*2+0)<<6) + lane, ci1 = ((wave*2+1)<<6) + lane;
  int ar0 = ci0 >> 2, ac0 = ((ci0 & 3) ^ ((ar0 >> 1) & 3)) << 3;
  int ar1 = ci1 >> 2, ac1 = ((ci1 & 3) ^ ((ar1 >> 1) & 3)) << 3;
  int ga0 = row0 + ar0 < rend ? row0 + ar0 : rend - 1;
  int ga1 = row0 + ar1 < rend ? row0 + ar1 : rend - 1;
  int lo0 = (wave*2+0) << 9, lo1 = (wave*2+1) << 9;
  int bn = tid & 127;
  int bkg = (tid >> 7) << 4;
  int bsw = (bn >> 1) & 3;
  int bc0 = bkg >> 3;
  int boff0 = bn*32 + (( bc0    ^ bsw) << 3);
  int boff1 = bn*32 + (((bc0+1) ^ bsw) << 3);
  f32x4 zero = {0.f,0.f,0.f,0.f};
  f32x4 acc[4][4];
  #pragma unroll
  for (int i=0;i<4;++i) for (int j=0;j<4;++j) acc[i][j] = zero;
  float r1[16];

  #define WP_LOAD_B(k0) do { \
    const float* p1 = Bw + (size_t)(kbase+(k0)+bkg)*N + col0 + bn; \
    _Pragma("unroll") \
    for (int j = 0; j < 16; ++j) r1[j] = p1[(size_t)j*N]; } while(0)
  #define WP_ISSUE_A(b, k0) do { \
    g2l16(Ag + (size_t)ga0*K + kbase + (k0) + ac0, &As[b][lo0]); \
    g2l16(Ag + (size_t)ga1*K + kbase + (k0) + ac1, &As[b][lo1]); } while(0)
  #define WP_WRITE_B(b) do { \
    u32 P1[8]; \
    _Pragma("unroll") \
    for (int j = 0; j < 8; ++j) \
      asm("v_cvt_pk_bf16_f32 %0, %1, %2" : "=v"(P1[j]) : "v"(r1[2*j]), "v"(r1[2*j+1])); \
    *(uint4*)(&Bs[b][boff0]) = make_uint4(P1[0],P1[1],P1[2],P1[3]); \
    *(uint4*)(&Bs[b][boff1]) = make_uint4(P1[4],P1[5],P1[6],P1[7]); } while(0)

  // prologue: unit 0 (B first, then A -> VMW(2) leaves A in flight)
  WP_LOAD_B(0);
  WP_ISSUE_A(0, 0);
  VMW(2);
  WP_WRITE_B(0);
  const int nt = 1024 / 32;
  for (int t = 0; t < nt; ++t) {
    int cur = t & 1;
    VMW(0);            // A(t) landed (issued ~1 iter ago; cheap)
    LGKM0();           // own B ds_writes retired before barrier
    SBAR(); SCHED0();
    bf16x8 af[4], bfr[4];
    #pragma unroll
    for (int mi = 0; mi < 4; ++mi)
      af[mi] = *(const bf16x8*)(&As[cur][((wm*64 + mi*16 + l15) << 5) + ((l4 ^ sw) << 3)]);
    #pragma unroll
    for (int ni = 0; ni < 4; ++ni)
      bfr[ni] = *(const bf16x8*)(&Bs[cur][((wn*64 + ni*16 + l15) << 5) + ((l4 ^ sw) << 3)]);
    if (t + 1 < nt) { WP_LOAD_B((t+1)*32); WP_ISSUE_A(cur^1, (t+1)*32); }
    PRIO(1);
    #pragma unroll
    for (int mi = 0; mi < 4; ++mi)
      #pragma unroll
      for (int ni = 0; ni < 4; ++ni)
        acc[mi][ni] = __builtin_amdgcn_mfma_f32_16x16x32_bf16(af[mi], bfr[ni], acc[mi][ni], 0,0,0);
    PRIO(0);
    SBAR();            // readers done with buf[cur]; writes below target buf[cur^1]
    if (t + 1 < nt) {
      VMW(2); SCHED0();       // B(t+1) regs landed; A(t+1) stays in flight
      WP_WRITE_B(cur ^ 1);
    }
  }
  #undef WP_LOAD_B
  #undef WP_ISSUE_A
  #undef WP_WRITE_B
  #pragma unroll
  for (int mi = 0; mi < 4; ++mi) {
    #pragma unroll
    for (int r = 0; r < 4; ++r) {
      int row = row0 + wm*64 + mi*16 + l4*4 + r;
      if (row >= rend) continue;
      #pragma unroll
      for (int ni = 0; ni < 4; ++ni) {
        int col = col0 + wn*64 + ni*16 + l15;
        out[(size_t)row * N + col] = acc[mi][ni][r];
      }
    }
  }
}

// --- final: out = x1 + sum_s g_s*(P0..P3[slot_s] + bp[e_s]) -----------------
__global__ __launch_bounds__(256) void tb_combine(const float* __restrict__ x1,
    const float* __restrict__ P, const int* __restrict__ slot_of,
    const int* __restrict__ top_idx, const float* __restrict__ gate_w,
    const float* __restrict__ bp, float* __restrict__ out) {
  const size_t SL = (size_t)4096 * 1024;
  int t = blockIdx.x;
  int c = threadIdx.x * 4;
  float4 a = *(const float4*)(x1 + (size_t)t*DMODEL + c);
  float ox = a.x, oy = a.y, oz = a.z, ow = a.w;
  #pragma unroll
  for (int s = 0; s < 2; ++s) {
    int slot = slot_of[t*2+s], e = top_idx[t*2+s];
    float g = gate_w[t*2+s];
    float4 v = *(const float4*)(bp + (size_t)e*DMODEL + c);
    #pragma unroll
    for (int ks = 0; ks < 4; ++ks) {
      float4 p = *(const float4*)(P + ks*SL + (size_t)slot*DMODEL + c);
      v.x += p.x; v.y += p.y; v.z += p.z; v.w += p.w;
    }
    ox += g*v.x; oy += g*v.y; oz += g*v.z; ow += g*v.w;
  }
  *(float4*)(out + (size_t)t*DMODEL + c) = make_float4(ox,oy,oz,ow);
}

extern "C" void kernel_launch(void* const* d_in, const int* in_sizes, int n_in,
                              void* d_out, int out_size, void* d_ws, size_t ws_size,
                              hipStream_t stream) {
  const float* x      = (const float*)d_in[0];
  const float* w_qkv  = (const float*)d_in[1];
  const float* b_qkv  = (const float*)d_in[2];
  const float* w_out  = (const float*)d_in[3];
  const float* b_out  = (const float*)d_in[4];
  const float* scale1 = (const float*)d_in[5];
  const float* scale2 = (const float*)d_in[6];
  const float* w_gate = (const float*)d_in[7];
  const float* b_gate = (const float*)d_in[8];
  const float* w1     = (const float*)d_in[9];
  const float* b1     = (const float*)d_in[10];
  const float* w2     = (const float*)d_in[11];
  const float* b2     = (const float*)d_in[12];
  const float* wp     = (const float*)d_in[13];
  const float* bp     = (const float*)d_in[14];
  float* out = (float*)d_out;

  char* ws = (char*)d_ws;
  const size_t MB = 1024 * 1024;
  bool full8 = ws_size >= (size_t)198 * MB;   // room for 128MB bf16 w1+w2

  // Residents:
  u16*   XN1h = (u16*)  (ws + 0*MB);    // 4MB  rms1 hi  (dead after QKV gemm)
  u16*   XN1l = (u16*)  (ws + 4*MB);    // 4MB  rms1 lo
  u16*   XG   = (u16*)  (ws + 0*MB);    // 8MB  (overlay XN1h/l; written at gather)
  float* X1   = (float*)(ws + 8*MB);    // 8MB  alive till combine
  float* XN2F = (float*)(ws + 16*MB);   // 8MB  dead after gating
  u16*   XN2B = (u16*)  (ws + 32*MB);   // 4MB
  u16*   HB   = (u16*)  (ws + 36*MB);   // 32MB [36,68)
  float* PPART= (float*)(ws + 68*MB);   // 64MB [68,132) wp partials (after MLP)
  u16*   WT1  = (u16*)  (ws + 68*MB);   // w1 bf16: 64MB full8 / 32MB halves
  u16*   WT2  = (u16*)  (ws + (full8 ? 132 : 100)*MB);  // w2 bf16
  // Attention-phase overlays (dead before MoE):
  float* QKV  = (float*)(ws + 36*MB);   // 24MB (inside HB)
  float* Qf   = (float*)(ws + 60*MB);   // 8MB  (inside HB)
  float* Vf   = (float*)(ws + 68*MB);   // 8MB
  u16*   Khg  = (u16*)  (ws + 76*MB);   // 4MB
  u16*   Klg  = (u16*)  (ws + 80*MB);   // 4MB
  u16*   Vth  = (u16*)  (ws + 84*MB);   // 4MB
  u16*   Vtl  = (u16*)  (ws + 88*MB);   // 4MB
  u16*   Obh  = (u16*)  (ws + 92*MB);   // 4MB attn out hi
  u16*   Obl  = (u16*)  (ws + 96*MB);   // 4MB attn out lo
  u16*   Wqh  = (u16*)  (ws + 100*MB);  // 6MB
  u16*   Wql  = (u16*)  (ws + 106*MB);  // 6MB
  u16*   Woh  = (u16*)  (ws + 112*MB);  // 2MB
  u16*   Wol  = (u16*)  (ws + 114*MB);  // 2MB
  char*  GT   = ws + (full8 ? 196 : 132)*MB;
  int*   top_idx = (int*)  (GT);
  float* gate_w  = (float*)(GT + 16*1024);
  int*   slot_of = (int*)  (GT + 32*1024);
  int*   counts  = (int*)  (GT + 48*1024);
  int*   offs    = (int*)  (GT + 48*1024 + 64);
  int*   cursor  = (int*)  (GT + 48*1024 + 128);
  float* trig    = (float*)(GT + 64*1024);

  const size_t KN = (size_t)1024 * 4096;

  hipMemsetAsync(counts, 0, 32, stream);
  tb_trig<<<1024, 32, 0, stream>>>(trig);
  tb_wsplit<1><<<dim3(48,16,1), 256, 0, stream>>>(w_qkv, Wqh, Wql, 1024, 3072);
  tb_wsplit<1><<<dim3(16,16,1), 256, 0, stream>>>(w_out, Woh, Wol, 1024, 1024);
  tb_rms_hl<<<2048, 256, 0, stream>>>(x, scale1, XN1h, XN1l);
  tb_gemm_sp2<0><<<dim3(24,16), 256, 0, stream>>>(XN1h, XN1l, Wqh, Wql, b_qkv, nullptr, QKV, 2048, 3072, 1024);
  tb_rope2<<<2048, 256, 0, stream>>>(QKV, trig, Qf, Khg, Klg, Vf);
  tb_vt<<<dim3(16,32), 256, 0, stream>>>(Vf, Vth, Vtl);
  tb_attn_mfma<<<dim3(16,32), 256, 0, stream>>>(Qf, Khg, Klg, Vth, Vtl, Obh, Obl);
  tb_gemm_sp2<1><<<dim3(8,16), 256, 0, stream>>>(Obh, Obl, Woh, Wol, b_out, x, X1, 2048, 1024, 1024);
  tb_rms<<<2048, 256, 0, stream>>>(X1, scale2, XN2F, XN2B);
  tb_gating<<<2048, 64, 0, stream>>>(XN2F, w_gate, b_gate, top_idx, gate_w, counts);
  tb_scan<<<1, 64, 0, stream>>>(counts, offs, cursor, out + (size_t)NTOK*DMODEL);
  tb_gather<<<2048, 128, 0, stream>>>(XN2B, top_idx, cursor, slot_of, XG);
  // MoE MLP: pre-convert w1/w2 to [n][k] bf16, then merged-phase ring GEMM.
  if (full8) {
    tb_wsplit<0><<<dim3(64,16,8), 256, 0, stream>>>(w1, WT1, nullptr, 1024, 4096);
    tb_wsplit<0><<<dim3(64,16,8), 256, 0, stream>>>(w2, WT2, nullptr, 1024, 4096);
    tb_moe_mlp8<<<dim3(32,16,8), 512, 0, stream>>>(XG, WT1, WT2, b1, b2, HB, counts, offs, 0);
  } else {
    tb_wsplit<0><<<dim3(64,16,4), 256, 0, stream>>>(w1, WT1, nullptr, 1024, 4096);
    tb_wsplit<0><<<dim3(64,16,4), 256, 0, stream>>>(w2, WT2, nullptr, 1024, 4096);
    tb_moe_mlp8<<<dim3(32,16,4), 512, 0, stream>>>(XG, WT1, WT2, b1, b2, HB, counts, offs, 0);
    tb_wsplit<0><<<dim3(64,16,4), 256, 0, stream>>>(w1 + 4*KN, WT1, nullptr, 1024, 4096);
    tb_wsplit<0><<<dim3(64,16,4), 256, 0, stream>>>(w2 + 4*KN, WT2, nullptr, 1024, 4096);
    tb_moe_mlp8<<<dim3(32,16,4), 512, 0, stream>>>(XG, WT1, WT2, b1, b2, HB, counts, offs, 4);
  }
  // Down-projection: split-K=4 partials (f32 weights read directly).
  tb_moe_wp<<<dim3(8,16,32), 256, 0, stream>>>(HB, wp, PPART, counts, offs);
  tb_combine<<<2048, 256, 0, stream>>>(X1, PPART, slot_of, top_idx, gate_w, bp, out);
}

// Round 14
// 585.226 us; speedup vs baseline: 1.1157x; 1.0092x over previous
//
#include <hip/hip_runtime.h>
#include <math.h>

typedef unsigned short u16;
typedef unsigned int   u32;
typedef float f32x4 __attribute__((ext_vector_type(4)));
typedef __bf16 bf16x8 __attribute__((ext_vector_type(8)));

#define T_LEN  1024
#define DMODEL 1024
#define NTOK   2048
#define NHEAD  16
#define HDIM   64
#define NEXP   8
#define FFDIM  4096

#define VMW(n)   asm volatile("s_waitcnt vmcnt(" #n ")" ::: "memory")
#define LGKM0()  asm volatile("s_waitcnt lgkmcnt(0)" ::: "memory")
#define SBAR()   __builtin_amdgcn_s_barrier()
#define SCHED0() __builtin_amdgcn_sched_barrier(0)
#define PRIO(n)  __builtin_amdgcn_s_setprio(n)

__device__ __forceinline__ u16 f2bf(float f) {          // RNE
  union { float f; u32 u; } v; v.f = f;
  u32 r = v.u + 0x7FFFu + ((v.u >> 16) & 1u);
  return (u16)(r >> 16);
}
__device__ __forceinline__ float bf2f(u16 h) {
  union { u32 u; float f; } v; v.u = ((u32)h) << 16; return v.f;
}

// async 16B global->LDS (wave-uniform LDS base; HW adds lane*16)
__device__ __forceinline__ void g2l16(const u16* src, u16* ldsbase) {
  __builtin_amdgcn_global_load_lds(
      (const __attribute__((address_space(1))) void*)src,
      (__attribute__((address_space(3))) void*)ldsbase, 16, 0, 0);
}

// split 16 f32 -> 8 packed u32 hi + 8 packed u32 lo
__device__ __forceinline__ void split16(const float* src, u32* H, u32* L) {
  #pragma unroll
  for (int j = 0; j < 8; ++j) {
    float a = src[2*j], b = src[2*j+1];
    u16 ha = f2bf(a), hb = f2bf(b);
    u16 la = f2bf(a - bf2f(ha)), lb = f2bf(b - bf2f(hb));
    H[j] = (u32)ha | ((u32)hb << 16);
    L[j] = (u32)la | ((u32)lb << 16);
  }
}

// ---------------- RMSNorm -> hi/lo bf16 split (for GEMM A-operand) ---------
__global__ __launch_bounds__(256) void tb_rms_hl(const float* __restrict__ x,
    const float* __restrict__ scale, u16* __restrict__ oh, u16* __restrict__ ol) {
  int t = blockIdx.x, tid = threadIdx.x;
  const float* xr = x + (size_t)t * DMODEL;
  float4 v = *(const float4*)(xr + tid * 4);
  double ss = (double)v.x*v.x + (double)v.y*v.y + (double)v.z*v.z + (double)v.w*v.w;
  #pragma unroll
  for (int off = 32; off; off >>= 1) ss += __shfl_xor(ss, off);
  __shared__ double red[4];
  if ((tid & 63) == 0) red[tid >> 6] = ss;
  __syncthreads();
  double denom = sqrt((red[0]+red[1]+red[2]+red[3]) / (double)DMODEL) + 1e-5;
  float4 sc = *(const float4*)(scale + tid * 4);
  float y[4];
  y[0] = (float)((double)v.x / denom * (double)sc.x);
  y[1] = (float)((double)v.y / denom * (double)sc.y);
  y[2] = (float)((double)v.z / denom * (double)sc.z);
  y[3] = (float)((double)v.w / denom * (double)sc.w);
  u16* ph = oh + (size_t)t*DMODEL + tid*4;
  u16* pl = ol + (size_t)t*DMODEL + tid*4;
  #pragma unroll
  for (int j = 0; j < 4; ++j) {
    u16 h = f2bf(y[j]);
    ph[j] = h;
    pl[j] = f2bf(y[j] - bf2f(h));
  }
}

// ---------------- RMSNorm (f64 accumulate; f32 + bf16 outputs) -------------
__global__ __launch_bounds__(256) void tb_rms(const float* __restrict__ x,
    const float* __restrict__ scale, float* __restrict__ out_f, u16* __restrict__ out_b) {
  int t = blockIdx.x, tid = threadIdx.x;
  const float* xr = x + (size_t)t * DMODEL;
  float4 v = *(const float4*)(xr + tid * 4);
  double ss = (double)v.x*v.x + (double)v.y*v.y + (double)v.z*v.z + (double)v.w*v.w;
  #pragma unroll
  for (int off = 32; off; off >>= 1) ss += __shfl_xor(ss, off);
  __shared__ double red[4];
  if ((tid & 63) == 0) red[tid >> 6] = ss;
  __syncthreads();
  double denom = sqrt((red[0]+red[1]+red[2]+red[3]) / (double)DMODEL) + 1e-5;
  float4 sc = *(const float4*)(scale + tid * 4);
  float y0 = (float)((double)v.x / denom * (double)sc.x);
  float y1 = (float)((double)v.y / denom * (double)sc.y);
  float y2 = (float)((double)v.z / denom * (double)sc.z);
  float y3 = (float)((double)v.w / denom * (double)sc.w);
  *(float4*)(out_f + (size_t)t*DMODEL + tid*4) = make_float4(y0,y1,y2,y3);
  u16* ob = out_b + (size_t)t*DMODEL + tid*4;
  ob[0]=f2bf(y0); ob[1]=f2bf(y1); ob[2]=f2bf(y2); ob[3]=f2bf(y3);
}

// ------- weight pre-split+transpose: W[k][n] f32 -> Wt[n][k] bf16 (hi[,lo]) -
template<int HILO>
__global__ __launch_bounds__(256) void tb_wsplit(const float* __restrict__ W,
    u16* __restrict__ Wh, u16* __restrict__ Wl, int K, int N) {
  __shared__ float Tf[64*68];
  size_t eo = (size_t)blockIdx.z * (size_t)K * N;
  const float* Wb = W + eo;
  int n0 = blockIdx.x*64, k0 = blockIdx.y*64;
  int tid = threadIdx.x;
  int r = tid >> 2, c = tid & 3;
  const float* wp = Wb + (size_t)(k0+r)*N + n0 + c*16;
  float vv[16];
  *(float4*)&vv[0]  = ((const float4*)wp)[0];
  *(float4*)&vv[4]  = ((const float4*)wp)[1];
  *(float4*)&vv[8]  = ((const float4*)wp)[2];
  *(float4*)&vv[12] = ((const float4*)wp)[3];
  #pragma unroll
  for (int j = 0; j < 16; ++j) Tf[(c*16+j)*68 + r] = vv[j];
  __syncthreads();
  int n = tid >> 2, kc = tid & 3;
  float tv[16];
  #pragma unroll
  for (int j = 0; j < 16; ++j) tv[j] = Tf[n*68 + kc*16 + j];
  u32 H[8], L[8];
  split16(tv, H, L);
  u16* oh = Wh + eo + (size_t)(n0+n)*K + k0 + kc*16;
  *(uint4*)oh       = make_uint4(H[0],H[1],H[2],H[3]);
  *(uint4*)(oh + 8) = make_uint4(H[4],H[5],H[6],H[7]);
  if (HILO) {
    u16* ol = Wl + eo + (size_t)(n0+n)*K + k0 + kc*16;
    *(uint4*)ol       = make_uint4(L[0],L[1],L[2],L[3]);
    *(uint4*)(ol + 8) = make_uint4(L[4],L[5],L[6],L[7]);
  }
}

// --- split-bf16 MFMA GEMM, all operands via global_load_lds ----------------
// Depth-2 counted-vmcnt dbuf (64KB LDS -> 2 blocks/CU co-residency).
template<int RESID>
__global__ __launch_bounds__(256) void tb_gemm_sp2(const u16* __restrict__ Ahg,
    const u16* __restrict__ Alg, const u16* __restrict__ Bhg,
    const u16* __restrict__ Blg, const float* __restrict__ bias,
    const float* __restrict__ resid, float* __restrict__ C,
    int M, int N, int K) {
  __shared__ __align__(16) u16 Ah[2][128*32], Al[2][128*32];
  __shared__ __align__(16) u16 Bh[2][128*32], Bl[2][128*32];   // 64KB total
  int tid = threadIdx.x;
  int row0 = blockIdx.y * 128, col0 = blockIdx.x * 128;
  int lane = tid & 63, wave = tid >> 6;
  int wm = wave >> 1, wn = wave & 1;
  int l15 = lane & 15, l4 = lane >> 4;
  int sw = (l15 >> 1) & 3;
  int ci0 = ((wave*2+0)<<6)+lane, ci1 = ((wave*2+1)<<6)+lane;
  int r0 = ci0 >> 2, c0 = ((ci0 & 3) ^ ((r0 >> 1) & 3)) << 3;
  int r1 = ci1 >> 2, c1 = ((ci1 & 3) ^ ((r1 >> 1) & 3)) << 3;
  int lo0 = (wave*2+0) << 9, lo1 = (wave*2+1) << 9;
  f32x4 zero = {0.f,0.f,0.f,0.f};
  f32x4 acc[4][4];
  #pragma unroll
  for (int i=0;i<4;++i) for (int j=0;j<4;++j) acc[i][j] = zero;
  const int nt = K / 32;

  #define SP2_STAGE(b, k0) do { \
    g2l16(Ahg + (size_t)(row0+r0)*K + (k0) + c0, &Ah[b][lo0]); \
    g2l16(Ahg + (size_t)(row0+r1)*K + (k0) + c1, &Ah[b][lo1]); \
    g2l16(Alg + (size_t)(row0+r0)*K + (k0) + c0, &Al[b][lo0]); \
    g2l16(Alg + (size_t)(row0+r1)*K + (k0) + c1, &Al[b][lo1]); \
    g2l16(Bhg + (size_t)(col0+r0)*K + (k0) + c0, &Bh[b][lo0]); \
    g2l16(Bhg + (size_t)(col0+r1)*K + (k0) + c1, &Bh[b][lo1]); \
    g2l16(Blg + (size_t)(col0+r0)*K + (k0) + c0, &Bl[b][lo0]); \
    g2l16(Blg + (size_t)(col0+r1)*K + (k0) + c1, &Bl[b][lo1]); } while(0)

  SP2_STAGE(0, 0);
  SP2_STAGE(1, 32);
  for (int t = 0; t < nt; ++t) {
    int cur = t & 1;
    if (t + 1 < nt) { VMW(8); } else { VMW(0); }
    SBAR(); SCHED0();
    bf16x8 ah[4], al_[4], bh_[4], bl_[4];
    #pragma unroll
    for (int mi = 0; mi < 4; ++mi) {
      int ro = (wm*64 + mi*16 + l15) << 5;
      ah[mi]  = *(const bf16x8*)(&Ah[cur][ro + ((l4 ^ sw) << 3)]);
      al_[mi] = *(const bf16x8*)(&Al[cur][ro + ((l4 ^ sw) << 3)]);
    }
    #pragma unroll
    for (int ni = 0; ni < 4; ++ni) {
      int ro = (wn*64 + ni*16 + l15) << 5;
      bh_[ni] = *(const bf16x8*)(&Bh[cur][ro + ((l4 ^ sw) << 3)]);
      bl_[ni] = *(const bf16x8*)(&Bl[cur][ro + ((l4 ^ sw) << 3)]);
    }
    PRIO(1);
    #pragma unroll
    for (int mi = 0; mi < 4; ++mi)
      #pragma unroll
      for (int ni = 0; ni < 4; ++ni) {
        acc[mi][ni] = __builtin_amdgcn_mfma_f32_16x16x32_bf16(ah[mi], bh_[ni], acc[mi][ni], 0,0,0);
        acc[mi][ni] = __builtin_amdgcn_mfma_f32_16x16x32_bf16(ah[mi], bl_[ni], acc[mi][ni], 0,0,0);
        acc[mi][ni] = __builtin_amdgcn_mfma_f32_16x16x32_bf16(al_[mi], bh_[ni], acc[mi][ni], 0,0,0);
      }
    PRIO(0);
    if (t + 1 < nt) {
      SBAR();
      if (t + 2 < nt) SP2_STAGE(cur, (t+2)*32);
    }
  }
  #undef SP2_STAGE
  #pragma unroll
  for (int mi = 0; mi < 4; ++mi)
    #pragma unroll
    for (int r = 0; r < 4; ++r) {
      int row = row0 + wm*64 + mi*16 + l4*4 + r;
      #pragma unroll
      for (int ni = 0; ni < 4; ++ni) {
        int col = col0 + wn*64 + ni*16 + l15;
        float vv = acc[mi][ni][r] + bias[col];
        if (RESID) vv += resid[(size_t)row*N + col];
        C[(size_t)row*N + col] = vv;
      }
    }
}

// ---------------- RoPE trig table (f64) ------------------------------------
__global__ void tb_trig(float* __restrict__ tab) {
  int t = blockIdx.x, d = threadIdx.x;
  double theta = pow(10000.0, -(double)d / 32.0);
  double ang = (double)t * theta;
  tab[(t*32 + d)*2 + 0] = (float)cos(ang);
  tab[(t*32 + d)*2 + 1] = (float)sin(ang);
}

// ---------------- qkv -> Q f32, K bf16 hi/lo (all [bh][t][d]), V f32 -------
__global__ __launch_bounds__(256) void tb_rope2(const float* __restrict__ qkv,
    const float* __restrict__ tab, float* __restrict__ Qf, u16* __restrict__ Khg,
    u16* __restrict__ Klg, float* __restrict__ Vf) {
  int n = blockIdx.x;
  int b = n >> 10, t = n & 1023;
  const float* src = qkv + (size_t)n * 3072;
  for (int idx = threadIdx.x; idx < 512; idx += 256) {
    int h = idx >> 5, d = idx & 31;
    float ca = tab[(t*32+d)*2], sa = tab[(t*32+d)*2+1];
    size_t base = ((size_t)(b*NHEAD + h) * T_LEN + t) * HDIM;
    { float x1 = src[h*64 + d], x2 = src[h*64 + d + 32];
      Qf[base + d]      = x1*ca - x2*sa;
      Qf[base + d + 32] = x1*sa + x2*ca; }
    { float x1 = src[1024 + h*64 + d], x2 = src[1024 + h*64 + d + 32];
      float k1 = x1*ca - x2*sa, k2 = x1*sa + x2*ca;
      u16 h1 = f2bf(k1), h2 = f2bf(k2);
      Khg[base + d] = h1;      Khg[base + d + 32] = h2;
      Klg[base + d] = f2bf(k1 - bf2f(h1));
      Klg[base + d + 32] = f2bf(k2 - bf2f(h2)); }
  }
  for (int c = threadIdx.x; c < 1024; c += 256) {
    int h = c >> 6, d = c & 63;
    Vf[((size_t)(b*NHEAD + h) * T_LEN + t) * HDIM + d] = src[2048 + c];
  }
}

// ---------------- V transpose+split: [bh][t][d] f32 -> [bh][d][t] bf16 -----
__global__ __launch_bounds__(256) void tb_vt(const float* __restrict__ Vf,
    u16* __restrict__ Vh, u16* __restrict__ Vl) {
  __shared__ float Tf[64*68];
  int t0 = blockIdx.x * 64, bh = blockIdx.y;
  const float* Vb = Vf + (size_t)bh * (T_LEN*HDIM);
  int tid = threadIdx.x, r = tid >> 2, c = tid & 3;
  const float* vp = Vb + (size_t)(t0+r)*HDIM + c*16;
  float vv[16];
  *(float4*)&vv[0]  = ((const float4*)vp)[0];
  *(float4*)&vv[4]  = ((const float4*)vp)[1];
  *(float4*)&vv[8]  = ((const float4*)vp)[2];
  *(float4*)&vv[12] = ((const float4*)vp)[3];
  #pragma unroll
  for (int j = 0; j < 16; ++j) Tf[(c*16+j)*68 + r] = vv[j];
  __syncthreads();
  int d = tid >> 2, tc = tid & 3;
  float tv[16];
  #pragma unroll
  for (int j = 0; j < 16; ++j) tv[j] = Tf[d*68 + tc*16 + j];
  u32 H[8], L[8];
  split16(tv, H, L);
  u16* oh = Vh + (size_t)bh*(HDIM*T_LEN) + (size_t)d*T_LEN + t0 + tc*16;
  u16* ol = Vl + (size_t)bh*(HDIM*T_LEN) + (size_t)d*T_LEN + t0 + tc*16;
  *(uint4*)oh       = make_uint4(H[0],H[1],H[2],H[3]);
  *(uint4*)(oh + 8) = make_uint4(H[4],H[5],H[6],H[7]);
  *(uint4*)ol       = make_uint4(L[0],L[1],L[2],L[3]);
  *(uint4*)(ol + 8) = make_uint4(L[4],L[5],L[6],L[7]);
}

// ---------------- MFMA flash attention; writes O as hi/lo bf16 split -------
__global__ __launch_bounds__(256) void tb_attn_mfma(const float* __restrict__ Qf,
    const u16* __restrict__ Khg, const u16* __restrict__ Klg,
    const u16* __restrict__ Vhg, const u16* __restrict__ Vlg,
    u16* __restrict__ Obh, u16* __restrict__ Obl) {
  __shared__ __align__(16) u16 Kh[64*72], Kl[64*72];
  __shared__ __align__(16) u16 Vh[64*72], Vl[64*72];
  __shared__ __align__(16) u16 Ph[64*72], Pl[64*72];
  int qt = blockIdx.x, bh = blockIdx.y;
  int tid = threadIdx.x, lane = tid & 63, w = tid >> 6;
  int l15 = lane & 15, l4 = lane >> 4;
  int b = bh >> 4, h = bh & 15;
  const float* Qb = Qf + (size_t)bh * (T_LEN*HDIM);
  const u16* Khb = Khg + (size_t)bh * (T_LEN*HDIM);
  const u16* Klb = Klg + (size_t)bh * (T_LEN*HDIM);
  const u16* Vhb = Vhg + (size_t)bh * (HDIM*T_LEN);
  const u16* Vlb = Vlg + (size_t)bh * (HDIM*T_LEN);
  int q0 = qt * 64;
  int qrow = q0 + w*16 + l15;
  bf16x8 qh[2], ql[2];
  #pragma unroll
  for (int ks = 0; ks < 2; ++ks) {
    const float* qp = Qb + (size_t)qrow*HDIM + ks*32 + l4*8;
    float vv[8];
    *(float4*)&vv[0] = ((const float4*)qp)[0];
    *(float4*)&vv[4] = ((const float4*)qp)[1];
    u32 H[4], L[4];
    #pragma unroll
    for (int j = 0; j < 4; ++j) {
      float a = vv[2*j], bb = vv[2*j+1];
      u16 ha = f2bf(a), hb = f2bf(bb);
      u16 la = f2bf(a - bf2f(ha)), lb = f2bf(bb - bf2f(hb));
      H[j] = (u32)ha | ((u32)hb << 16);
      L[j] = (u32)la | ((u32)lb << 16);
    }
    union { uint4 u; bf16x8 b; } th, tl;
    th.u = make_uint4(H[0],H[1],H[2],H[3]);
    tl.u = make_uint4(L[0],L[1],L[2],L[3]);
    qh[ks] = th.b; ql[ks] = tl.b;
  }
  int qg[4];
  #pragma unroll
  for (int r = 0; r < 4; ++r) qg[r] = q0 + w*16 + l4*4 + r;
  float mrow[4], lrow[4];
  f32x4 oacc[4];
  f32x4 zero = {0.f,0.f,0.f,0.f};
  #pragma unroll
  for (int r = 0; r < 4; ++r) { mrow[r] = -1e30f; lrow[r] = 0.f; }
  #pragma unroll
  for (int d = 0; d < 4; ++d) oacc[d] = zero;

  int sr = tid >> 2, sc = tid & 3;
  for (int kt = 0; kt <= qt; ++kt) {
    int k0 = kt * 64;
    __syncthreads();
    {
      const u16* kp = Khb + (size_t)(k0+sr)*HDIM + sc*16;
      *(uint4*)(Kh + sr*72 + sc*16)     = ((const uint4*)kp)[0];
      *(uint4*)(Kh + sr*72 + sc*16 + 8) = ((const uint4*)kp)[1];
      const u16* kl2 = Klb + (size_t)(k0+sr)*HDIM + sc*16;
      *(uint4*)(Kl + sr*72 + sc*16)     = ((const uint4*)kl2)[0];
      *(uint4*)(Kl + sr*72 + sc*16 + 8) = ((const uint4*)kl2)[1];
      const u16* vp = Vhb + (size_t)sr*T_LEN + k0 + sc*16;
      *(uint4*)(Vh + sr*72 + sc*16)     = ((const uint4*)vp)[0];
      *(uint4*)(Vh + sr*72 + sc*16 + 8) = ((const uint4*)vp)[1];
      const u16* vl2 = Vlb + (size_t)sr*T_LEN + k0 + sc*16;
      *(uint4*)(Vl + sr*72 + sc*16)     = ((const uint4*)vl2)[0];
      *(uint4*)(Vl + sr*72 + sc*16 + 8) = ((const uint4*)vl2)[1];
    }
    __syncthreads();
    f32x4 sacc[4];
    #pragma unroll
    for (int ni = 0; ni < 4; ++ni) {
      sacc[ni] = zero;
      #pragma unroll
      for (int ks = 0; ks < 2; ++ks) {
        bf16x8 kh_ = *(const bf16x8*)(Kh + (ni*16 + l15)*72 + ks*32 + l4*8);
        bf16x8 kl_ = *(const bf16x8*)(Kl + (ni*16 + l15)*72 + ks*32 + l4*8);
        sacc[ni] = __builtin_amdgcn_mfma_f32_16x16x32_bf16(qh[ks], kh_, sacc[ni], 0,0,0);
        sacc[ni] = __builtin_amdgcn_mfma_f32_16x16x32_bf16(qh[ks], kl_, sacc[ni], 0,0,0);
        sacc[ni] = __builtin_amdgcn_mfma_f32_16x16x32_bf16(ql[ks], kh_, sacc[ni], 0,0,0);
      }
    }
    bool diag = (kt == qt);
    float sv[4][4];
    #pragma unroll
    for (int ni = 0; ni < 4; ++ni)
      #pragma unroll
      for (int r = 0; r < 4; ++r) {
        float s = sacc[ni][r] * 0.125f;
        if (diag && (k0 + ni*16 + l15 > qg[r])) s = -1e30f;
        sv[ni][r] = s;
      }
    float mt[4];
    #pragma unroll
    for (int r = 0; r < 4; ++r)
      mt[r] = fmaxf(fmaxf(sv[0][r], sv[1][r]), fmaxf(sv[2][r], sv[3][r]));
    #pragma unroll
    for (int off = 1; off < 16; off <<= 1)
      #pragma unroll
      for (int r = 0; r < 4; ++r) mt[r] = fmaxf(mt[r], __shfl_xor(mt[r], off));
    float al[4];
    #pragma unroll
    for (int r = 0; r < 4; ++r) {
      float mn = fmaxf(mrow[r], mt[r]);
      al[r] = expf(mrow[r] - mn);
      mrow[r] = mn;
    }
    float ls[4] = {0.f,0.f,0.f,0.f};
    #pragma unroll
    for (int ni = 0; ni < 4; ++ni)
      #pragma unroll
      for (int r = 0; r < 4; ++r) {
        float p = expf(sv[ni][r] - mrow[r]);
        u16 ph2 = f2bf(p);
        int qrl = w*16 + l4*4 + r;
        Ph[qrl*72 + ni*16 + l15] = ph2;
        Pl[qrl*72 + ni*16 + l15] = f2bf(p - bf2f(ph2));
        ls[r] += p;
      }
    #pragma unroll
    for (int off = 1; off < 16; off <<= 1)
      #pragma unroll
      for (int r = 0; r < 4; ++r) ls[r] += __shfl_xor(ls[r], off);
    #pragma unroll
    for (int r = 0; r < 4; ++r) lrow[r] = lrow[r]*al[r] + ls[r];
    #pragma unroll
    for (int d = 0; d < 4; ++d)
      #pragma unroll
      for (int r = 0; r < 4; ++r) oacc[d][r] *= al[r];
    bf16x8 ph_[2], pl_[2];
    #pragma unroll
    for (int ks = 0; ks < 2; ++ks) {
      ph_[ks] = *(const bf16x8*)(Ph + (w*16 + l15)*72 + ks*32 + l4*8);
      pl_[ks] = *(const bf16x8*)(Pl + (w*16 + l15)*72 + ks*32 + l4*8);
    }
    #pragma unroll
    for (int dblk = 0; dblk < 4; ++dblk)
      #pragma unroll
      for (int ks = 0; ks < 2; ++ks) {
        bf16x8 vh_ = *(const bf16x8*)(Vh + (dblk*16 + l15)*72 + ks*32 + l4*8);
        bf16x8 vl_ = *(const bf16x8*)(Vl + (dblk*16 + l15)*72 + ks*32 + l4*8);
        oacc[dblk] = __builtin_amdgcn_mfma_f32_16x16x32_bf16(ph_[ks], vh_, oacc[dblk], 0,0,0);
        oacc[dblk] = __builtin_amdgcn_mfma_f32_16x16x32_bf16(ph_[ks], vl_, oacc[dblk], 0,0,0);
        oacc[dblk] = __builtin_amdgcn_mfma_f32_16x16x32_bf16(pl_[ks], vh_, oacc[dblk], 0,0,0);
      }
  }
  #pragma unroll
  for (int dblk = 0; dblk < 4; ++dblk)
    #pragma unroll
    for (int r = 0; r < 4; ++r) {
      int q = qg[r];
      int d = dblk*16 + l15;
      float ov = oacc[dblk][r] / lrow[r];
      u16 hh = f2bf(ov);
      size_t oi = ((size_t)b * T_LEN + q) * DMODEL + h * HDIM + d;
      Obh[oi] = hh;
      Obl[oi] = f2bf(ov - bf2f(hh));
    }
}

// ---------------- router: f64 logits, top-2 --------------------------------
__global__ __launch_bounds__(64) void tb_gating(const float* __restrict__ xn2,
    const float* __restrict__ wg, const float* __restrict__ bg,
    int* __restrict__ top_idx, float* __restrict__ gate_w, int* __restrict__ counts) {
  int t = blockIdx.x, lane = threadIdx.x;
  const float* xr = xn2 + (size_t)t * DMODEL;
  double part[8];
  #pragma unroll
  for (int e = 0; e < 8; ++e) part[e] = 0.0;
  for (int i = lane; i < DMODEL; i += 64) {
    double xv = (double)xr[i];
    const float* wr = wg + (size_t)i * 8;
    #pragma unroll
    for (int e = 0; e < 8; ++e) part[e] += xv * (double)wr[e];
  }
  #pragma unroll
  for (int e = 0; e < 8; ++e)
    for (int off = 32; off; off >>= 1) part[e] += __shfl_xor(part[e], off);
  if (lane == 0) {
    double lg[8];
    for (int e = 0; e < 8; ++e) lg[e] = part[e] + (double)bg[e];
    int i1 = 0;
    for (int e = 1; e < 8; ++e) if (lg[e] > lg[i1]) i1 = e;
    int i2 = (i1 == 0) ? 1 : 0;
    for (int e = 0; e < 8; ++e) if (e != i1 && lg[e] > lg[i2]) i2 = e;
    double e2 = exp(lg[i2] - lg[i1]);
    double den = 1.0 + e2;
    top_idx[t*2] = i1; top_idx[t*2+1] = i2;
    gate_w[t*2] = (float)(1.0/den); gate_w[t*2+1] = (float)(e2/den);
    atomicAdd(&counts[i1], 1); atomicAdd(&counts[i2], 1);
  }
}

__global__ void tb_scan(const int* __restrict__ counts, int* __restrict__ offs,
    int* __restrict__ cursor, float* __restrict__ aux_out) {
  if (threadIdx.x == 0) {
    int off = 0; float aux = 0.f;
    for (int e = 0; e < 8; ++e) {
      offs[e] = off; cursor[e] = off; off += counts[e];
      float fr = (float)counts[e] / 4096.0f - 0.125f;
      aux += fr * fr;
    }
    aux_out[0] = aux;
  }
}

__global__ __launch_bounds__(128) void tb_gather(const u16* __restrict__ xn2b,
    const int* __restrict__ top_idx, int* __restrict__ cursor,
    int* __restrict__ slot_of, u16* __restrict__ Xg) {
  int t = blockIdx.x;
  __shared__ int sl[2];
  if (threadIdx.x < 2) {
    int e = top_idx[t*2 + threadIdx.x];
    int s = atomicAdd(&cursor[e], 1);
    sl[threadIdx.x] = s;
    slot_of[t*2 + threadIdx.x] = s;
  }
  __syncthreads();
  uint4 v = *(const uint4*)(xn2b + (size_t)t * DMODEL + threadIdx.x * 8);
  *(uint4*)(Xg + (size_t)sl[0] * DMODEL + threadIdx.x * 8) = v;
  *(uint4*)(Xg + (size_t)sl[1] * DMODEL + threadIdx.x * 8) = v;
}

// --- fused MoE MLP, ring-4 counted-vmcnt, ONE barrier per K32 unit ---------
// Ring distance 3 >= 2 means stage(u+3) targets buf[(u-1)&3], whose readers
// finished (lgkm-complete) before reaching the TOP barrier of unit u — the
// tail barrier is redundant and removed. Loads never drain.
__global__ __launch_bounds__(512, 1) void tb_moe_mlp8(const u16* __restrict__ Ag,
    const u16* __restrict__ B1t, const u16* __restrict__ B2t,
    const float* __restrict__ b1g, const float* __restrict__ b2g,
    u16* __restrict__ Hout, const int* __restrict__ counts,
    const int* __restrict__ offs, int ebase) {
  const int K = DMODEL, N = FFDIM;
  int ez = blockIdx.z, e = ebase + ez;
  int cnt = counts[e];
  if ((int)blockIdx.y * 256 >= cnt) return;
  int row0 = offs[e] + blockIdx.y * 256;
  int rend = offs[e] + cnt;
  int col0 = blockIdx.x * 128;
  const u16* B1 = B1t + (size_t)ez * K * N;
  const u16* B2 = B2t + (size_t)ez * K * N;
  const float* bb1 = b1g + (size_t)e * N;
  const float* bb2 = b2g + (size_t)e * N;
  __shared__ __align__(16) u16 As[4][256*32];    // 64KB
  __shared__ __align__(16) u16 Bs1[4][128*32];   // 32KB
  __shared__ __align__(16) u16 Bs2[4][128*32];   // 32KB
  int tid = threadIdx.x, lane = tid & 63, wave = tid >> 6;  // 8 waves
  int wm = wave >> 1, wn = wave & 1;
  int l15 = lane & 15, l4 = lane >> 4;
  int sw = (l15 >> 1) & 3;
  int ai0 = ((wave*2+0)<<6) + lane, ai1 = ((wave*2+1)<<6) + lane;
  int ar0 = ai0 >> 2, ac0 = ((ai0 & 3) ^ ((ar0 >> 1) & 3)) << 3;
  int ar1 = ai1 >> 2, ac1 = ((ai1 & 3) ^ ((ar1 >> 1) & 3)) << 3;
  int ga0 = row0 + ar0 < rend ? row0 + ar0 : rend - 1;
  int ga1 = row0 + ar1 < rend ? row0 + ar1 : rend - 1;
  int alo0 = (wave*2+0) << 9, alo1 = (wave*2+1) << 9;
  int bi = (wave << 6) + lane;
  int br = bi >> 2, bc = ((bi & 3) ^ ((br >> 1) & 3)) << 3;
  int blo = wave << 9;
  f32x4 zero = {0.f,0.f,0.f,0.f};
  f32x4 acc1[4][4], acc2[4][4];
  #pragma unroll
  for (int i=0;i<4;++i) for (int j=0;j<4;++j) { acc1[i][j] = zero; acc2[i][j] = zero; }

  #define M8_STAGE(b, k0) do { \
    g2l16(Ag + (size_t)ga0*K + (k0) + ac0, &As[b][alo0]); \
    g2l16(Ag + (size_t)ga1*K + (k0) + ac1, &As[b][alo1]); \
    g2l16(B1 + (size_t)(col0+br)*K + (k0) + bc, &Bs1[b][blo]); \
    g2l16(B2 + (size_t)(col0+br)*K + (k0) + bc, &Bs2[b][blo]); } while(0)

  // prologue: units 0,1,2 (4 loads/wave each -> 12 outstanding)
  M8_STAGE(0, 0);
  M8_STAGE(1, 32);
  M8_STAGE(2, 64);
  const int NT = K / 32;   // 32 units
  for (int u = 0; u < NT; ++u) {
    int buf = u & 3;
    if (u + 2 < NT) { VMW(8); } else if (u + 1 < NT) { VMW(4); } else { VMW(0); }
    SBAR(); SCHED0();                       // unit u landed for ALL waves
    bf16x8 af[4], bf1[4], bf2[4];
    #pragma unroll
    for (int mi = 0; mi < 4; ++mi)
      af[mi] = *(const bf16x8*)(&As[buf][((wm*64 + mi*16 + l15) << 5) + ((l4 ^ sw) << 3)]);
    #pragma unroll
    for (int ni = 0; ni < 4; ++ni) {
      bf1[ni] = *(const bf16x8*)(&Bs1[buf][((wn*64 + ni*16 + l15) << 5) + ((l4 ^ sw) << 3)]);
      bf2[ni] = *(const bf16x8*)(&Bs2[buf][((wn*64 + ni*16 + l15) << 5) + ((l4 ^ sw) << 3)]);
    }
    if (u + 3 < NT) M8_STAGE((u+3) & 3, (u+3)*32);   // buf[(u-1)&3]: sealed by THIS unit's top SBAR
    PRIO(1);
    #pragma unroll
    for (int mi = 0; mi < 4; ++mi)
      #pragma unroll
      for (int ni = 0; ni < 4; ++ni)
        acc1[mi][ni] = __builtin_amdgcn_mfma_f32_16x16x32_bf16(af[mi], bf1[ni], acc1[mi][ni], 0,0,0);
    #pragma unroll
    for (int mi = 0; mi < 4; ++mi)
      #pragma unroll
      for (int ni = 0; ni < 4; ++ni)
        acc2[mi][ni] = __builtin_amdgcn_mfma_f32_16x16x32_bf16(af[mi], bf2[ni], acc2[mi][ni], 0,0,0);
    PRIO(0);
    // no tail barrier: ring distance 3 makes the top barrier sufficient
  }
  #undef M8_STAGE
  #pragma unroll
  for (int mi = 0; mi < 4; ++mi) {
    #pragma unroll
    for (int r = 0; r < 4; ++r) {
      int row = row0 + wm*64 + mi*16 + l4*4 + r;
      if (row >= rend) continue;
      #pragma unroll
      for (int ni = 0; ni < 4; ++ni) {
        int col = col0 + wn*64 + ni*16 + l15;
        float v1 = acc1[mi][ni][r] + bb1[col];
        float v2 = acc2[mi][ni][r] + bb2[col];
        float hv = (v1 / (1.f + expf(-v1))) * v2;
        Hout[(size_t)row * N + col] = f2bf(hv);
      }
    }
  }
}

// --- MoE down-proj, split-K=4, in-kernel f32 convert, counted waits --------
__global__ __launch_bounds__(256) void tb_moe_wp(const u16* __restrict__ Ag,
    const float* __restrict__ Wp, float* __restrict__ Pout,
    const int* __restrict__ counts, const int* __restrict__ offs) {
  const int K = FFDIM, N = DMODEL;
  int e = blockIdx.z & 7, ks = blockIdx.z >> 3;
  int cnt = counts[e];
  if ((int)blockIdx.y * 128 >= cnt) return;
  int row0 = offs[e] + blockIdx.y * 128;
  int rend = offs[e] + cnt;
  int col0 = blockIdx.x * 128;
  int kbase = ks * 1024;
  const float* Bw = Wp + (size_t)e * K * N;
  float* out = Pout + (size_t)ks * (4096u*1024u);
  __shared__ __align__(16) u16 As[2][128*32], Bs[2][128*32];
  int tid = threadIdx.x, lane = tid & 63, wave = tid >> 6;
  int wm = wave >> 1, wn = wave & 1;
  int l15 = lane & 15, l4 = lane >> 4;
  int sw = (l15 >> 1) & 3;
  int ci0 = ((wave*2+0)<<6) + lane, ci1 = ((wave*2+1)<<6) + lane;
  int ar0 = ci0 >> 2, ac0 = ((ci0 & 3) ^ ((ar0 >> 1) & 3)) << 3;
  int ar1 = ci1 >> 2, ac1 = ((ci1 & 3) ^ ((ar1 >> 1) & 3)) << 3;
  int ga0 = row0 + ar0 < rend ? row0 + ar0 : rend - 1;
  int ga1 = row0 + ar1 < rend ? row0 + ar1 : rend - 1;
  int lo0 = (wave*2+0) << 9, lo1 = (wave*2+1) << 9;
  int bn = tid & 127;
  int bkg = (tid >> 7) << 4;
  int bsw = (bn >> 1) & 3;
  int bc0 = bkg >> 3;
  int boff0 = bn*32 + (( bc0    ^ bsw) << 3);
  int boff1 = bn*32 + (((bc0+1) ^ bsw) << 3);
  f32x4 zero = {0.f,0.f,0.f,0.f};
  f32x4 acc[4][4];
  #pragma unroll
  for (int i=0;i<4;++i) for (int j=0;j<4;++j) acc[i][j] = zero;
  float r1[16];

  #define WP_LOAD_B(k0) do { \
    const float* p1 = Bw + (size_t)(kbase+(k0)+bkg)*N + col0 + bn; \
    _Pragma("unroll") \
    for (int j = 0; j < 16; ++j) r1[j] = p1[(size_t)j*N]; } while(0)
  #define WP_ISSUE_A(b, k0) do { \
    g2l16(Ag + (size_t)ga0*K + kbase + (k0) + ac0, &As[b][lo0]); \
    g2l16(Ag + (size_t)ga1*K + kbase + (k0) + ac1, &As[b][lo1]); } while(0)
  #define WP_WRITE_B(b) do { \
    u32 P1[8]; \
    _Pragma("unroll") \
    for (int j = 0; j < 8; ++j) \
      asm("v_cvt_pk_bf16_f32 %0, %1, %2" : "=v"(P1[j]) : "v"(r1[2*j]), "v"(r1[2*j+1])); \
    *(uint4*)(&Bs[b][boff0]) = make_uint4(P1[0],P1[1],P1[2],P1[3]); \
    *(uint4*)(&Bs[b][boff1]) = make_uint4(P1[4],P1[5],P1[6],P1[7]); } while(0)

  // prologue: unit 0 (B first, then A -> VMW(2) leaves A in flight)
  WP_LOAD_B(0);
  WP_ISSUE_A(0, 0);
  VMW(2);
  WP_WRITE_B(0);
  const int nt = 1024 / 32;
  for (int t = 0; t < nt; ++t) {
    int cur = t & 1;
    VMW(0);            // A(t) landed (issued ~1 iter ago; cheap)
    LGKM0();           // own B ds_writes retired before barrier
    SBAR(); SCHED0();
    bf16x8 af[4], bfr[4];
    #pragma unroll
    for (int mi = 0; mi < 4; ++mi)
      af[mi] = *(const bf16x8*)(&As[cur][((wm*64 + mi*16 + l15) << 5) + ((l4 ^ sw) << 3)]);
    #pragma unroll
    for (int ni = 0; ni < 4; ++ni)
      bfr[ni] = *(const bf16x8*)(&Bs[cur][((wn*64 + ni*16 + l15) << 5) + ((l4 ^ sw) << 3)]);
    if (t + 1 < nt) { WP_LOAD_B((t+1)*32); WP_ISSUE_A(cur^1, (t+1)*32); }
    PRIO(1);
    #pragma unroll
    for (int mi = 0; mi < 4; ++mi)
      #pragma unroll
      for (int ni = 0; ni < 4; ++ni)
        acc[mi][ni] = __builtin_amdgcn_mfma_f32_16x16x32_bf16(af[mi], bfr[ni], acc[mi][ni], 0,0,0);
    PRIO(0);
    SBAR();            // readers done with buf[cur]; writes below target buf[cur^1]
    if (t + 1 < nt) {
      VMW(2); SCHED0();       // B(t+1) regs landed; A(t+1) stays in flight
      WP_WRITE_B(cur ^ 1);
    }
  }
  #undef WP_LOAD_B
  #undef WP_ISSUE_A
  #undef WP_WRITE_B
  #pragma unroll
  for (int mi = 0; mi < 4; ++mi) {
    #pragma unroll
    for (int r = 0; r < 4; ++r) {
      int row = row0 + wm*64 + mi*16 + l4*4 + r;
      if (row >= rend) continue;
      #pragma unroll
      for (int ni = 0; ni < 4; ++ni) {
        int col = col0 + wn*64 + ni*16 + l15;
        out[(size_t)row * N + col] = acc[mi][ni][r];
      }
    }
  }
}

// --- final: out = x1 + sum_s g_s*(P0..P3[slot_s] + bp[e_s]) -----------------
__global__ __launch_bounds__(256) void tb_combine(const float* __restrict__ x1,
    const float* __restrict__ P, const int* __restrict__ slot_of,
    const int* __restrict__ top_idx, const float* __restrict__ gate_w,
    const float* __restrict__ bp, float* __restrict__ out) {
  const size_t SL = (size_t)4096 * 1024;
  int t = blockIdx.x;
  int c = threadIdx.x * 4;
  float4 a = *(const float4*)(x1 + (size_t)t*DMODEL + c);
  float ox = a.x, oy = a.y, oz = a.z, ow = a.w;
  #pragma unroll
  for (int s = 0; s < 2; ++s) {
    int slot = slot_of[t*2+s], e = top_idx[t*2+s];
    float g = gate_w[t*2+s];
    float4 v = *(const float4*)(bp + (size_t)e*DMODEL + c);
    #pragma unroll
    for (int ks = 0; ks < 4; ++ks) {
      float4 p = *(const float4*)(P + ks*SL + (size_t)slot*DMODEL + c);
      v.x += p.x; v.y += p.y; v.z += p.z; v.w += p.w;
    }
    ox += g*v.x; oy += g*v.y; oz += g*v.z; ow += g*v.w;
  }
  *(float4*)(out + (size_t)t*DMODEL + c) = make_float4(ox,oy,oz,ow);
}

extern "C" void kernel_launch(void* const* d_in, const int* in_sizes, int n_in,
                              void* d_out, int out_size, void* d_ws, size_t ws_size,
                              hipStream_t stream) {
  const float* x      = (const float*)d_in[0];
  const float* w_qkv  = (const float*)d_in[1];
  const float* b_qkv  = (const float*)d_in[2];
  const float* w_out  = (const float*)d_in[3];
  const float* b_out  = (const float*)d_in[4];
  const float* scale1 = (const float*)d_in[5];
  const float* scale2 = (const float*)d_in[6];
  const float* w_gate = (const float*)d_in[7];
  const float* b_gate = (const float*)d_in[8];
  const float* w1     = (const float*)d_in[9];
  const float* b1     = (const float*)d_in[10];
  const float* w2     = (const float*)d_in[11];
  const float* b2     = (const float*)d_in[12];
  const float* wp     = (const float*)d_in[13];
  const float* bp     = (const float*)d_in[14];
  float* out = (float*)d_out;

  char* ws = (char*)d_ws;
  const size_t MB = 1024 * 1024;
  bool full8 = ws_size >= (size_t)198 * MB;   // room for 128MB bf16 w1+w2

  // Residents:
  u16*   XN1h = (u16*)  (ws + 0*MB);    // 4MB  rms1 hi  (dead after QKV gemm)
  u16*   XN1l = (u16*)  (ws + 4*MB);    // 4MB  rms1 lo
  u16*   XG   = (u16*)  (ws + 0*MB);    // 8MB  (overlay XN1h/l; written at gather)
  float* X1   = (float*)(ws + 8*MB);    // 8MB  alive till combine
  float* XN2F = (float*)(ws + 16*MB);   // 8MB  dead after gating
  u16*   XN2B = (u16*)  (ws + 32*MB);   // 4MB
  u16*   HB   = (u16*)  (ws + 36*MB);   // 32MB [36,68)
  float* PPART= (float*)(ws + 68*MB);   // 64MB [68,132) wp partials (after MLP)
  u16*   WT1  = (u16*)  (ws + 68*MB);   // w1 bf16: 64MB full8 / 32MB halves
  u16*   WT2  = (u16*)  (ws + (full8 ? 132 : 100)*MB);  // w2 bf16
  // Attention-phase overlays (dead before MoE):
  float* QKV  = (float*)(ws + 36*MB);   // 24MB (inside HB)
  float* Qf   = (float*)(ws + 60*MB);   // 8MB  (inside HB)
  float* Vf   = (float*)(ws + 68*MB);   // 8MB
  u16*   Khg  = (u16*)  (ws + 76*MB);   // 4MB
  u16*   Klg  = (u16*)  (ws + 80*MB);   // 4MB
  u16*   Vth  = (u16*)  (ws + 84*MB);   // 4MB
  u16*   Vtl  = (u16*)  (ws + 88*MB);   // 4MB
  u16*   Obh  = (u16*)  (ws + 92*MB);   // 4MB attn out hi
  u16*   Obl  = (u16*)  (ws + 96*MB);   // 4MB attn out lo
  u16*   Wqh  = (u16*)  (ws + 100*MB);  // 6MB
  u16*   Wql  = (u16*)  (ws + 106*MB);  // 6MB
  u16*   Woh  = (u16*)  (ws + 112*MB);  // 2MB
  u16*   Wol  = (u16*)  (ws + 114*MB);  // 2MB
  char*  GT   = ws + (full8 ? 196 : 132)*MB;
  int*   top_idx = (int*)  (GT);
  float* gate_w  = (float*)(GT + 16*1024);
  int*   slot_of = (int*)  (GT + 32*1024);
  int*   counts  = (int*)  (GT + 48*1024);
  int*   offs    = (int*)  (GT + 48*1024 + 64);
  int*   cursor  = (int*)  (GT + 48*1024 + 128);
  float* trig    = (float*)(GT + 64*1024);

  const size_t KN = (size_t)1024 * 4096;

  hipMemsetAsync(counts, 0, 32, stream);
  tb_trig<<<1024, 32, 0, stream>>>(trig);
  tb_wsplit<1><<<dim3(48,16,1), 256, 0, stream>>>(w_qkv, Wqh, Wql, 1024, 3072);
  tb_wsplit<1><<<dim3(16,16,1), 256, 0, stream>>>(w_out, Woh, Wol, 1024, 1024);
  tb_rms_hl<<<2048, 256, 0, stream>>>(x, scale1, XN1h, XN1l);
  tb_gemm_sp2<0><<<dim3(24,16), 256, 0, stream>>>(XN1h, XN1l, Wqh, Wql, b_qkv, nullptr, QKV, 2048, 3072, 1024);
  tb_rope2<<<2048, 256, 0, stream>>>(QKV, trig, Qf, Khg, Klg, Vf);
  tb_vt<<<dim3(16,32), 256, 0, stream>>>(Vf, Vth, Vtl);
  tb_attn_mfma<<<dim3(16,32), 256, 0, stream>>>(Qf, Khg, Klg, Vth, Vtl, Obh, Obl);
  tb_gemm_sp2<1><<<dim3(8,16), 256, 0, stream>>>(Obh, Obl, Woh, Wol, b_out, x, X1, 2048, 1024, 1024);
  tb_rms<<<2048, 256, 0, stream>>>(X1, scale2, XN2F, XN2B);
  tb_gating<<<2048, 64, 0, stream>>>(XN2F, w_gate, b_gate, top_idx, gate_w, counts);
  tb_scan<<<1, 64, 0, stream>>>(counts, offs, cursor, out + (size_t)NTOK*DMODEL);
  tb_gather<<<2048, 128, 0, stream>>>(XN2B, top_idx, cursor, slot_of, XG);
  // MoE MLP: pre-convert w1/w2 to [n][k] bf16, then single-barrier ring GEMM.
  if (full8) {
    tb_wsplit<0><<<dim3(64,16,8), 256, 0, stream>>>(w1, WT1, nullptr, 1024, 4096);
    tb_wsplit<0><<<dim3(64,16,8), 256, 0, stream>>>(w2, WT2, nullptr, 1024, 4096);
    tb_moe_mlp8<<<dim3(32,16,8), 512, 0, stream>>>(XG, WT1, WT2, b1, b2, HB, counts, offs, 0);
  } else {
    tb_wsplit<0><<<dim3(64,16,4), 256, 0, stream>>>(w1, WT1, nullptr, 1024, 4096);
    tb_wsplit<0><<<dim3(64,16,4), 256, 0, stream>>>(w2, WT2, nullptr, 1024, 4096);
    tb_moe_mlp8<<<dim3(32,16,4), 512, 0, stream>>>(XG, WT1, WT2, b1, b2, HB, counts, offs, 0);
    tb_wsplit<0><<<dim3(64,16,4), 256, 0, stream>>>(w1 + 4*KN, WT1, nullptr, 1024, 4096);
    tb_wsplit<0><<<dim3(64,16,4), 256, 0, stream>>>(w2 + 4*KN, WT2, nullptr, 1024, 4096);
    tb_moe_mlp8<<<dim3(32,16,4), 512, 0, stream>>>(XG, WT1, WT2, b1, b2, HB, counts, offs, 4);
  }
  // Down-projection: split-K=4 partials (f32 weights read directly).
  tb_moe_wp<<<dim3(8,16,32), 256, 0, stream>>>(HB, wp, PPART, counts, offs);
  tb_combine<<<2048, 256, 0, stream>>>(X1, PPART, slot_of, top_idx, gate_w, bp, out);
}